// Round 1
// baseline (1643.398 us; speedup 1.0000x reference)
//
#include <hip/hip_runtime.h>
#include <hip/hip_bf16.h>
#include <math.h>

// Problem constants (from reference)
#define B_  8
#define N_  32
#define M_  16
#define LX  32
#define D_  64
#define IN_DIM_ 17
#define TT_ 63
#define H_  4
#define DH_ 16
#define P_TOT 4096          // B*N*M
#define BN_ 256             // B*N
#define FF_ 2048

// -------------------------------------------------------------------------
// Kernel 1: fused TTCN. One block per patch p. Computes
//   h1 = relu(x@w1.T+b1); h2 = relu(h1@w2.T+b2)
//   filt[l,c] = h2[l]·w3[c] + b3[c]  (c = t*17+i), masked, softmax over l
//   h_t[t]    = relu(sum_{l,i} x[l,i]*softmax_l(filt)[l,t,i] + t_bias[t])
//   xp[p] = concat(h_t, mask_patch); pm[p] = mask_patch
// -------------------------------------------------------------------------
__global__ __launch_bounds__(256) void ttcn_kernel(
    const float* __restrict__ x, const int* __restrict__ mask,
    const float* __restrict__ w1, const float* __restrict__ b1,
    const float* __restrict__ w2, const float* __restrict__ b2,
    const float* __restrict__ w3, const float* __restrict__ b3,
    const float* __restrict__ tb,
    float* __restrict__ xp, float* __restrict__ pm)
{
  const int p = blockIdx.x;
  const int tid = threadIdx.x;
  __shared__ float xs[LX * IN_DIM_];     // 544
  __shared__ float ms[LX];               // 32
  __shared__ float h1[LX * TT_];         // 2016
  __shared__ float h2[LX * TT_];         // 2016
  __shared__ float colres[TT_ * IN_DIM_];// 1071

  for (int i = tid; i < LX * IN_DIM_; i += 256) xs[i] = x[p * (LX * IN_DIM_) + i];
  if (tid < LX) ms[tid] = (float)mask[p * LX + tid];
  __syncthreads();

  // h1 = relu(x @ w1.T + b1)   (32 x 63)
  for (int o = tid; o < LX * TT_; o += 256) {
    int l = o / TT_, t = o % TT_;
    float acc = b1[t];
    const float* wr = w1 + t * IN_DIM_;
    const float* xr = xs + l * IN_DIM_;
    #pragma unroll
    for (int k = 0; k < IN_DIM_; ++k) acc += xr[k] * wr[k];
    h1[o] = fmaxf(acc, 0.f);
  }
  __syncthreads();

  // h2 = relu(h1 @ w2.T + b2)  (32 x 63)
  for (int o = tid; o < LX * TT_; o += 256) {
    int l = o / TT_, t = o % TT_;
    float acc = b2[t];
    const float* wr = w2 + t * TT_;
    const float* hr = h1 + l * TT_;
    for (int k = 0; k < TT_; ++k) acc += hr[k] * wr[k];
    h2[o] = fmaxf(acc, 0.f);
  }
  __syncthreads();

  // per-column filt -> masked softmax over l -> contract with x[:, i]
  for (int c = tid; c < TT_ * IN_DIM_; c += 256) {
    const int ii = c % IN_DIM_;
    const float* wr = w3 + c * TT_;
    const float bb = b3[c];
    float f[LX];
    #pragma unroll
    for (int l = 0; l < LX; ++l) f[l] = bb;
    for (int k = 0; k < TT_; ++k) {
      float wv = wr[k];
      #pragma unroll
      for (int l = 0; l < LX; ++l) f[l] += h2[l * TT_ + k] * wv;
    }
    float mx = -1e30f;
    #pragma unroll
    for (int l = 0; l < LX; ++l) {
      f[l] = (ms[l] != 0.f) ? f[l] : -1e8f;
      mx = fmaxf(mx, f[l]);
    }
    float se = 0.f, acc = 0.f;
    #pragma unroll
    for (int l = 0; l < LX; ++l) {
      float e = __expf(f[l] - mx);
      se += e;
      acc += e * xs[l * IN_DIM_ + ii];
    }
    colres[c] = acc / se;
  }
  __syncthreads();

  if (tid < TT_) {
    float acc = 0.f;
    #pragma unroll
    for (int i2 = 0; i2 < IN_DIM_; ++i2) acc += colres[tid * IN_DIM_ + i2];
    xp[p * D_ + tid] = fmaxf(acc + tb[tid], 0.f);
  }
  if (tid == 0) {
    float s = 0.f;
    #pragma unroll
    for (int l = 0; l < LX; ++l) s += ms[l];
    float mp = (s > 0.f) ? 1.f : 0.f;
    xp[p * D_ + TT_] = mp;
    pm[p] = mp;
  }
}

// -------------------------------------------------------------------------
// Kernel 2: one full transformer layer. One block per (b,n); M=16 tokens.
//   xb += gattn(xb); xb += pe; xb = ln1(xb + mha(xb)); xb = ln2(xb + ff(xb));
//   xout = xb (+ xin if add_residual)
// -------------------------------------------------------------------------
__global__ __launch_bounds__(256) void layer_kernel(
    const float* __restrict__ xin, const float* __restrict__ pm,
    const float* __restrict__ qw, const float* __restrict__ qb,
    const float* __restrict__ kw, const float* __restrict__ kb,
    const float* __restrict__ vw, const float* __restrict__ vb,
    const float* __restrict__ ow, const float* __restrict__ ob,
    const float* __restrict__ in_w, const float* __restrict__ in_b,
    const float* __restrict__ out_w, const float* __restrict__ out_b,
    const float* __restrict__ ln1g, const float* __restrict__ ln1b,
    const float* __restrict__ ln2g, const float* __restrict__ ln2b,
    const float* __restrict__ fw1, const float* __restrict__ fb1,
    const float* __restrict__ fw2, const float* __restrict__ fb2,
    float* __restrict__ xout, int add_residual)
{
  const int bn = blockIdx.x;
  const int tid = threadIdx.x;
  __shared__ float xb[M_ * D_];          // 1024
  __shared__ float qs[M_ * D_];          // 1024 (also attn-out)
  __shared__ float ks[M_ * D_];          // 1024
  __shared__ float vs[M_ * D_];          // 1024
  __shared__ float ss[H_ * M_ * M_];     // 1024 scores
  __shared__ float hidden[4 * FF_];      // 8192
  __shared__ float red[4 * 4 * D_];      // 1024
  __shared__ float pmv[M_], mur[M_], rvr[M_];

  const float* xin_p = xin + bn * (M_ * D_);
  for (int o = tid; o < M_ * D_; o += 256) xb[o] = xin_p[o];
  if (tid < M_) pmv[tid] = pm[bn * M_ + tid];
  __syncthreads();

  // ======== patch gattn ========
  for (int o = tid; o < 3 * M_ * D_; o += 256) {
    int sel = o >> 10, r = o & 1023, m = r >> 6, d = r & 63;
    const float* W = (sel == 0) ? qw : (sel == 1) ? kw : vw;
    const float* Bv = (sel == 0) ? qb : (sel == 1) ? kb : vb;
    float acc = Bv[d];
    const float* wr = W + d * D_;
    const float* xr = xb + m * D_;
    #pragma unroll
    for (int kk = 0; kk < D_; ++kk) acc += xr[kk] * wr[kk];
    ((sel == 0) ? qs : (sel == 1) ? ks : vs)[r] = acc;
  }
  __syncthreads();
  for (int o = tid; o < H_ * M_ * M_; o += 256) {
    int h = o >> 8, r = o & 255, qm = r >> 4, km = r & 15;
    float acc = 0.f;
    #pragma unroll
    for (int dd = 0; dd < DH_; ++dd)
      acc += qs[qm * D_ + h * DH_ + dd] * ks[km * D_ + h * DH_ + dd];
    float dist = 5.0f * fabsf((float)(qm - km));         // |i-j|*DELTA/TAU
    float tbv = logf(expf(-dist) + 1e-12f);
    acc = acc * 0.25f + tbv;
    if (pmv[km] == 0.f) acc = -1e9f;
    ss[o] = acc;
  }
  __syncthreads();
  if (tid < H_ * M_) {
    float* row = ss + tid * M_;
    float mx = -1e30f;
    #pragma unroll
    for (int j = 0; j < M_; ++j) mx = fmaxf(mx, row[j]);
    float se = 0.f;
    #pragma unroll
    for (int j = 0; j < M_; ++j) { float e = __expf(row[j] - mx); row[j] = e; se += e; }
    float inv = 1.f / se;
    #pragma unroll
    for (int j = 0; j < M_; ++j) row[j] *= inv;
  }
  __syncthreads();
  for (int o = tid; o < M_ * D_; o += 256) {   // attn out -> qs (q dead)
    int m = o >> 6, d = o & 63, h = d >> 4;
    float acc = 0.f;
    #pragma unroll
    for (int km = 0; km < M_; ++km) acc += ss[h * 256 + m * M_ + km] * vs[km * D_ + d];
    qs[o] = acc;
  }
  __syncthreads();
  for (int o = tid; o < M_ * D_; o += 256) {   // proj*pm + residual + pos-enc
    int m = o >> 6, d = o & 63;
    float acc = ob[d];
    const float* ar = qs + m * D_;
    const float* wr = ow + d * D_;
    #pragma unroll
    for (int kk = 0; kk < D_; ++kk) acc += ar[kk] * wr[kk];
    acc *= pmv[m];
    int kp = d >> 1;
    float div = expf((float)(2 * kp) * (-9.210340371976184f / 64.f));
    float arg = (float)m * div;
    float pev = (d & 1) ? cosf(arg) : sinf(arg);
    xb[o] = xb[o] + acc + pev;
  }
  __syncthreads();

  // ======== tf MHA ========
  for (int o = tid; o < 3 * M_ * D_; o += 256) {
    int sel = o >> 10, r = o & 1023, m = r >> 6, d = r & 63;
    const float* wr = in_w + (sel * D_ + d) * D_;
    float acc = in_b[sel * D_ + d];
    const float* xr = xb + m * D_;
    #pragma unroll
    for (int kk = 0; kk < D_; ++kk) acc += xr[kk] * wr[kk];
    ((sel == 0) ? qs : (sel == 1) ? ks : vs)[r] = acc;
  }
  __syncthreads();
  for (int o = tid; o < H_ * M_ * M_; o += 256) {
    int h = o >> 8, r = o & 255, qm = r >> 4, km = r & 15;
    float acc = 0.f;
    #pragma unroll
    for (int dd = 0; dd < DH_; ++dd)
      acc += qs[qm * D_ + h * DH_ + dd] * ks[km * D_ + h * DH_ + dd];
    ss[o] = acc * 0.25f;
  }
  __syncthreads();
  if (tid < H_ * M_) {
    float* row = ss + tid * M_;
    float mx = -1e30f;
    #pragma unroll
    for (int j = 0; j < M_; ++j) mx = fmaxf(mx, row[j]);
    float se = 0.f;
    #pragma unroll
    for (int j = 0; j < M_; ++j) { float e = __expf(row[j] - mx); row[j] = e; se += e; }
    float inv = 1.f / se;
    #pragma unroll
    for (int j = 0; j < M_; ++j) row[j] *= inv;
  }
  __syncthreads();
  for (int o = tid; o < M_ * D_; o += 256) {
    int m = o >> 6, d = o & 63, h = d >> 4;
    float acc = 0.f;
    #pragma unroll
    for (int km = 0; km < M_; ++km) acc += ss[h * 256 + m * M_ + km] * vs[km * D_ + d];
    qs[o] = acc;
  }
  __syncthreads();
  for (int o = tid; o < M_ * D_; o += 256) {   // out proj, add into xb
    int m = o >> 6, d = o & 63;
    float acc = out_b[d];
    const float* ar = qs + m * D_;
    const float* wr = out_w + d * D_;
    #pragma unroll
    for (int kk = 0; kk < D_; ++kk) acc += ar[kk] * wr[kk];
    xb[o] += acc;
  }
  __syncthreads();

  // ======== LN1 ========
  if (tid < M_) {
    const float* row = xb + tid * D_;
    float mu = 0.f;
    #pragma unroll
    for (int d = 0; d < D_; ++d) mu += row[d];
    mu *= (1.f / 64.f);
    float var = 0.f;
    #pragma unroll
    for (int d = 0; d < D_; ++d) { float t = row[d] - mu; var += t * t; }
    var *= (1.f / 64.f);
    mur[tid] = mu; rvr[tid] = rsqrtf(var + 1e-5f);
  }
  __syncthreads();
  for (int o = tid; o < M_ * D_; o += 256) {
    int m = o >> 6, d = o & 63;
    xb[o] = (xb[o] - mur[m]) * rvr[m] * ln1g[d] + ln1b[d];
  }
  __syncthreads();

  // ======== FF (2048 hidden), 4 tokens per chunk ========
  for (int chunk = 0; chunk < 4; ++chunk) {
    const int t0 = chunk * 4;
    for (int j = tid; j < FF_; j += 256) {
      const float* wr = fw1 + j * D_;
      float a0 = fb1[j], a1 = a0, a2 = a0, a3 = a0;
      #pragma unroll 16
      for (int kk = 0; kk < D_; ++kk) {
        float wv = wr[kk];
        a0 += xb[(t0 + 0) * D_ + kk] * wv;
        a1 += xb[(t0 + 1) * D_ + kk] * wv;
        a2 += xb[(t0 + 2) * D_ + kk] * wv;
        a3 += xb[(t0 + 3) * D_ + kk] * wv;
      }
      hidden[0 * FF_ + j] = fmaxf(a0, 0.f);
      hidden[1 * FF_ + j] = fmaxf(a1, 0.f);
      hidden[2 * FF_ + j] = fmaxf(a2, 0.f);
      hidden[3 * FF_ + j] = fmaxf(a3, 0.f);
    }
    __syncthreads();
    {
      int d = tid & 63, qq = tid >> 6;        // qq in [0,4): j-quarter
      const float* wr = fw2 + d * FF_ + qq * 512;
      const float* h0 = hidden + 0 * FF_ + qq * 512;
      const float* h1p = hidden + 1 * FF_ + qq * 512;
      const float* h2p = hidden + 2 * FF_ + qq * 512;
      const float* h3p = hidden + 3 * FF_ + qq * 512;
      float p0 = 0.f, p1 = 0.f, p2 = 0.f, p3 = 0.f;
      #pragma unroll 8
      for (int j = 0; j < 512; ++j) {
        float wv = wr[j];
        p0 += h0[j] * wv; p1 += h1p[j] * wv; p2 += h2p[j] * wv; p3 += h3p[j] * wv;
      }
      red[(qq * 4 + 0) * D_ + d] = p0;
      red[(qq * 4 + 1) * D_ + d] = p1;
      red[(qq * 4 + 2) * D_ + d] = p2;
      red[(qq * 4 + 3) * D_ + d] = p3;
    }
    __syncthreads();
    {
      int tt = tid >> 6, d = tid & 63;
      float acc = fb2[d];
      #pragma unroll
      for (int qq = 0; qq < 4; ++qq) acc += red[(qq * 4 + tt) * D_ + d];
      xb[(t0 + tt) * D_ + d] += acc;           // residual: xb(ln1) + ff
    }
    __syncthreads();
  }

  // ======== LN2 ========
  if (tid < M_) {
    const float* row = xb + tid * D_;
    float mu = 0.f;
    #pragma unroll
    for (int d = 0; d < D_; ++d) mu += row[d];
    mu *= (1.f / 64.f);
    float var = 0.f;
    #pragma unroll
    for (int d = 0; d < D_; ++d) { float t = row[d] - mu; var += t * t; }
    var *= (1.f / 64.f);
    mur[tid] = mu; rvr[tid] = rsqrtf(var + 1e-5f);
  }
  __syncthreads();
  float* xo = xout + bn * (M_ * D_);
  for (int o = tid; o < M_ * D_; o += 256) {
    int m = o >> 6, d = o & 63;
    float v = (xb[o] - mur[m]) * rvr[m] * ln2g[d] + ln2b[d];
    xo[o] = v + (add_residual ? xin_p[o] : 0.f);
  }
}

// -------------------------------------------------------------------------
// Kernel 3: classifier head. One block per b.
// -------------------------------------------------------------------------
__global__ __launch_bounds__(256) void final_kernel(
    const float* __restrict__ xc, const float* __restrict__ pm,
    const float* __restrict__ q_embed,
    const float* __restrict__ cin_w, const float* __restrict__ cin_b,
    const float* __restrict__ cout_w, const float* __restrict__ cout_b,
    const float* __restrict__ logit_w, const float* __restrict__ logit_b,
    float* __restrict__ out)
{
  const int b = blockIdx.x;
  const int tid = threadIdx.x;
  __shared__ float xs[M_ * D_];
  __shared__ float kpmv[M_];
  __shared__ float qv[5 * D_], kv[M_ * D_], vv[M_ * D_];
  __shared__ float sv[H_ * 5 * M_];   // 320
  __shared__ float ao[5 * D_], zv[5 * D_];

  for (int o = tid; o < M_ * D_; o += 256) {
    int m = o >> 6, d = o & 63;
    float acc = 0.f;
    #pragma unroll
    for (int n = 0; n < N_; ++n) acc += xc[(((b * N_ + n) * M_ + m) * D_) + d];
    xs[o] = acc * (1.f / 32.f);
  }
  if (tid < M_) {
    float any = 0.f;
    #pragma unroll
    for (int n = 0; n < N_; ++n) any += (pm[(b * N_ + n) * M_ + tid] > 0.f) ? 1.f : 0.f;
    kpmv[tid] = (any > 0.f) ? 0.f : 1.f;   // 1 => masked key
  }
  __syncthreads();

  for (int o = tid; o < 5 * D_; o += 256) {
    int qi = o >> 6, d = o & 63;
    float acc = cin_b[d];
    const float* wr = cin_w + d * D_;
    #pragma unroll
    for (int kk = 0; kk < D_; ++kk) acc += q_embed[qi * D_ + kk] * wr[kk];
    qv[o] = acc;
  }
  for (int o = tid; o < 2 * M_ * D_; o += 256) {
    int sel = o >> 10, r = o & 1023, m = r >> 6, d = r & 63;
    const float* wr = cin_w + (D_ + sel * D_ + d) * D_;
    float acc = cin_b[D_ + sel * D_ + d];
    const float* xr = xs + m * D_;
    #pragma unroll
    for (int kk = 0; kk < D_; ++kk) acc += xr[kk] * wr[kk];
    ((sel == 0) ? kv : vv)[r] = acc;
  }
  __syncthreads();

  for (int o = tid; o < H_ * 5 * M_; o += 256) {
    int h = o / 80, r = o % 80, qi = r >> 4, km = r & 15;
    float acc = 0.f;
    #pragma unroll
    for (int dd = 0; dd < DH_; ++dd)
      acc += qv[qi * D_ + h * DH_ + dd] * kv[km * D_ + h * DH_ + dd];
    acc *= 0.25f;
    if (kpmv[km] != 0.f) acc = -1e9f;
    sv[o] = acc;
  }
  __syncthreads();
  if (tid < H_ * 5) {
    int h = tid / 5, qi = tid % 5;
    float* row = sv + h * 80 + qi * M_;
    float mx = -1e30f;
    #pragma unroll
    for (int km = 0; km < M_; ++km) mx = fmaxf(mx, row[km]);
    float se = 0.f;
    #pragma unroll
    for (int km = 0; km < M_; ++km) { float e = __expf(row[km] - mx); row[km] = e; se += e; }
    float inv = 1.f / se;
    #pragma unroll
    for (int km = 0; km < M_; ++km) row[km] *= inv;
  }
  __syncthreads();
  for (int o = tid; o < 5 * D_; o += 256) {
    int qi = o >> 6, d = o & 63, h = d >> 4;
    float acc = 0.f;
    #pragma unroll
    for (int km = 0; km < M_; ++km) acc += sv[h * 80 + qi * M_ + km] * vv[km * D_ + d];
    ao[o] = acc;
  }
  __syncthreads();
  for (int o = tid; o < 5 * D_; o += 256) {
    int qi = o >> 6, d = o & 63;
    float acc = cout_b[d];
    const float* wr = cout_w + d * D_;
    #pragma unroll
    for (int kk = 0; kk < D_; ++kk) acc += ao[qi * D_ + kk] * wr[kk];
    zv[o] = acc;
  }
  __syncthreads();
  if (tid < 5) {
    float acc = logit_b[0];
    #pragma unroll
    for (int d = 0; d < D_; ++d) acc += zv[tid * D_ + d] * logit_w[d];
    out[b * 5 + tid] = acc;
  }
}

// -------------------------------------------------------------------------
extern "C" void kernel_launch(void* const* d_in, const int* in_sizes, int n_in,
                              void* d_out, int out_size, void* d_ws, size_t ws_size,
                              hipStream_t stream) {
  const float* x       = (const float*)d_in[0];
  const int*   mask    = (const int*)  d_in[1];
  const float* ttcn_w1 = (const float*)d_in[2];
  const float* ttcn_b1 = (const float*)d_in[3];
  const float* ttcn_w2 = (const float*)d_in[4];
  const float* ttcn_b2 = (const float*)d_in[5];
  const float* ttcn_w3 = (const float*)d_in[6];
  const float* ttcn_b3 = (const float*)d_in[7];
  const float* t_bias  = (const float*)d_in[8];
  const float* ga_qw   = (const float*)d_in[9];
  const float* ga_qb   = (const float*)d_in[10];
  const float* ga_kw   = (const float*)d_in[11];
  const float* ga_kb   = (const float*)d_in[12];
  const float* ga_vw   = (const float*)d_in[13];
  const float* ga_vb   = (const float*)d_in[14];
  const float* ga_ow   = (const float*)d_in[15];
  const float* ga_ob   = (const float*)d_in[16];
  const float* tf_in_w = (const float*)d_in[17];
  const float* tf_in_b = (const float*)d_in[18];
  const float* tf_out_w= (const float*)d_in[19];
  const float* tf_out_b= (const float*)d_in[20];
  const float* tf_ln1g = (const float*)d_in[21];
  const float* tf_ln1b = (const float*)d_in[22];
  const float* tf_ln2g = (const float*)d_in[23];
  const float* tf_ln2b = (const float*)d_in[24];
  const float* tf_fw1  = (const float*)d_in[25];
  const float* tf_fb1  = (const float*)d_in[26];
  const float* tf_fw2  = (const float*)d_in[27];
  const float* tf_fb2  = (const float*)d_in[28];
  const float* q_embed = (const float*)d_in[29];
  const float* cls_in_w  = (const float*)d_in[30];
  const float* cls_in_b  = (const float*)d_in[31];
  const float* cls_out_w = (const float*)d_in[32];
  const float* cls_out_b = (const float*)d_in[33];
  const float* logit_w = (const float*)d_in[34];
  const float* logit_b = (const float*)d_in[35];

  float* wsf = (float*)d_ws;
  float* xp  = wsf;                       // P*64
  float* pmb = wsf + P_TOT * D_;          // P
  float* xa  = pmb + P_TOT;               // P*64
  float* xbuf= xa  + P_TOT * D_;          // P*64

  ttcn_kernel<<<P_TOT, 256, 0, stream>>>(x, mask, ttcn_w1, ttcn_b1, ttcn_w2,
                                         ttcn_b2, ttcn_w3, ttcn_b3, t_bias,
                                         xp, pmb);

  // layer 0: xa = layer(xp)
  layer_kernel<<<BN_, 256, 0, stream>>>(
      xp, pmb,
      ga_qw, ga_qb, ga_kw, ga_kb, ga_vw, ga_vb, ga_ow, ga_ob,
      tf_in_w, tf_in_b, tf_out_w, tf_out_b,
      tf_ln1g, tf_ln1b, tf_ln2g, tf_ln2b,
      tf_fw1, tf_fb1, tf_fw2, tf_fb2,
      xa, 0);

  // layer 1: xbuf = xa + layer(xa)
  layer_kernel<<<BN_, 256, 0, stream>>>(
      xa, pmb,
      ga_qw + D_*D_, ga_qb + D_, ga_kw + D_*D_, ga_kb + D_,
      ga_vw + D_*D_, ga_vb + D_, ga_ow + D_*D_, ga_ob + D_,
      tf_in_w + 3*D_*D_, tf_in_b + 3*D_, tf_out_w + D_*D_, tf_out_b + D_,
      tf_ln1g + D_, tf_ln1b + D_, tf_ln2g + D_, tf_ln2b + D_,
      tf_fw1 + FF_*D_, tf_fb1 + FF_, tf_fw2 + D_*FF_, tf_fb2 + D_,
      xbuf, 1);

  final_kernel<<<B_, 256, 0, stream>>>(xbuf, pmb, q_embed,
                                       cls_in_w, cls_in_b, cls_out_w, cls_out_b,
                                       logit_w, logit_b, (float*)d_out);
}

// Round 2
// 603.401 us; speedup vs baseline: 2.7236x; 2.7236x over previous
//
#include <hip/hip_runtime.h>
#include <hip/hip_bf16.h>
#include <math.h>

// Problem constants
#define B_  8
#define N_  32
#define M_  16
#define LX  32
#define D_  64
#define IN_DIM_ 17
#define TT_ 63
#define H_  4
#define DH_ 16
#define P_TOT 4096          // B*N*M
#define BN_ 256             // B*N
#define FF_ 2048

typedef unsigned short ushort_t;
typedef __attribute__((ext_vector_type(8))) short short8;   // 8 bf16 (4 VGPRs)
typedef __attribute__((ext_vector_type(4))) float floatx4;  // MFMA C/D

#define MFMA16(a,b,c) __builtin_amdgcn_mfma_f32_16x16x32_bf16((a),(b),(c),0,0,0)

__device__ __forceinline__ ushort_t f2bf(float f){          // RNE float->bf16
  unsigned u = __float_as_uint(f);
  u += 0x7FFFu + ((u >> 16) & 1u);
  return (ushort_t)(u >> 16);
}
__device__ __forceinline__ float bf2f(ushort_t h){ return __uint_as_float(((unsigned)h) << 16); }

__device__ __forceinline__ uint4 pack8(const ushort_t* h){
  uint4 u;
  u.x = (unsigned)h[0] | ((unsigned)h[1] << 16);
  u.y = (unsigned)h[2] | ((unsigned)h[3] << 16);
  u.z = (unsigned)h[4] | ((unsigned)h[5] << 16);
  u.w = (unsigned)h[6] | ((unsigned)h[7] << 16);
  return u;
}

__device__ __forceinline__ float dot64(const float* __restrict__ a, const float* __restrict__ w){
  const float4* a4 = (const float4*)a;
  const float4* w4 = (const float4*)w;
  float acc = 0.f;
  #pragma unroll
  for (int k = 0; k < 16; ++k){ float4 x = a4[k], y = w4[k];
    acc += x.x*y.x + x.y*y.y + x.z*y.z + x.w*y.w; }
  return acc;
}
__device__ __forceinline__ float dot16(const float* __restrict__ a, const float* __restrict__ b){
  const float4* a4 = (const float4*)a; const float4* b4 = (const float4*)b;
  float acc = 0.f;
  #pragma unroll
  for (int k = 0; k < 4; ++k){ float4 x = a4[k], y = b4[k];
    acc += x.x*y.x + x.y*y.y + x.z*y.z + x.w*y.w; }
  return acc;
}

// -------------------------------------------------------------------------
// Prep: split w1/w2/w3 into bf16 hi/lo, laid out as MFMA B-fragments.
// B[k][n] fragment: n = lane&15, k = ks*32 + (lane>>4)*8 + j  (j=0..7).
// slots: w3: 68 tiles x 2 ks x 64 lanes = 8704; w1: 4x1x64=256; w2: 4x2x64=512.
// -------------------------------------------------------------------------
__global__ __launch_bounds__(256) void prep_kernel(
    const float* __restrict__ w1, const float* __restrict__ w2, const float* __restrict__ w3,
    uint4* __restrict__ w1bhi, uint4* __restrict__ w1blo,
    uint4* __restrict__ w2bhi, uint4* __restrict__ w2blo,
    uint4* __restrict__ w3bhi, uint4* __restrict__ w3blo)
{
  int s = blockIdx.x * 256 + threadIdx.x;     // 0..9471
  int lane = s & 63, n = lane & 15, quad = (lane >> 4) & 3;
  float v[8];
  uint4 *dh, *dl; int idx;
  if (s < 8704){
    int tile = s >> 7, ks = (s >> 6) & 1;
    int c = tile * 16 + n;                    // column of w3 (0..1087, valid <1071)
    #pragma unroll
    for (int j = 0; j < 8; ++j){ int k = ks*32 + quad*8 + j;
      v[j] = (c < 1071 && k < TT_) ? w3[c*TT_ + k] : 0.f; }
    dh = w3bhi; dl = w3blo; idx = s;
  } else if (s < 8960){
    int s1 = s - 8704; int tile = s1 >> 6;
    int t = tile * 16 + n;                    // output t of h1 (valid <63)
    #pragma unroll
    for (int j = 0; j < 8; ++j){ int k = quad*8 + j;
      v[j] = (t < TT_ && k < IN_DIM_) ? w1[t*IN_DIM_ + k] : 0.f; }
    dh = w1bhi; dl = w1blo; idx = s1;
  } else {
    int s2 = s - 8960; int tile = s2 >> 7, ks = (s2 >> 6) & 1;
    int tp = tile * 16 + n;                   // output t' of h2 (valid <63)
    #pragma unroll
    for (int j = 0; j < 8; ++j){ int k = ks*32 + quad*8 + j;
      v[j] = (tp < TT_ && k < TT_) ? w2[tp*TT_ + k] : 0.f; }
    dh = w2bhi; dl = w2blo; idx = s2;
  }
  ushort_t hh[8], ll[8];
  #pragma unroll
  for (int j = 0; j < 8; ++j){ hh[j] = f2bf(v[j]); ll[j] = f2bf(v[j] - bf2f(hh[j])); }
  dh[idx] = pack8(hh); dl[idx] = pack8(ll);
}

// -------------------------------------------------------------------------
// Fused TTCN, all three GEMMs on MFMA with split-bf16 (hi/lo) operands.
// One block per patch. LDS pool aliased across phases (36032 B -> 4 blk/CU).
// -------------------------------------------------------------------------
__global__ __launch_bounds__(256) void ttcn_kernel(
    const float* __restrict__ x, const int* __restrict__ mask,
    const float* __restrict__ b1, const float* __restrict__ b2,
    const float* __restrict__ b3, const float* __restrict__ tb,
    const short8* __restrict__ w1bhi, const short8* __restrict__ w1blo,
    const short8* __restrict__ w2bhi, const short8* __restrict__ w2blo,
    const short8* __restrict__ w3bhi, const short8* __restrict__ w3blo,
    float* __restrict__ xp, float* __restrict__ pm)
{
  __shared__ __align__(16) char pool[36032];
  float*  xs    = (float*)(pool + 0);        // 544 f, x row-major [l][i]
  float*  msv   = (float*)(pool + 2176);     // 32 f
  float*  b3s   = (float*)(pool + 2304);     // 1072 f
  float*  h1t   = (float*)(pool + 6592);     // [k][l] stride 33, 64x33 f  (aliased by h2frag)
  short8* h2fhi = (short8*)(pool + 6592);
  short8* h2flo = (short8*)(pool + 10688);
  float*  h2t   = (float*)(pool + 15040);    // [k][l] stride 33
  short8* xfhi  = (short8*)(pool + 23488);
  short8* xflo  = (short8*)(pool + 25536);
  short8* h1fhi = (short8*)(pool + 27584);   // aliased by colres
  short8* h1flo = (short8*)(pool + 31680);
  float*  colres= (float*)(pool + 27584);    // 1071 f

  const int p = blockIdx.x, tid = threadIdx.x;
  const int lane = tid & 63, wvi = tid >> 6;
  const int nidx = lane & 15, quad = lane >> 4;

  // P0: stage x, mask, b3
  for (int i = tid; i < LX*IN_DIM_; i += 256) xs[i] = x[p*(LX*IN_DIM_) + i];
  if (tid < LX) msv[tid] = (float)mask[p*LX + tid];
  for (int i = tid; i < 1071; i += 256) b3s[i] = b3[i];
  __syncthreads();

  // P1: x A-fragments (hi/lo). slot = mt*64+lane, K=32 (k>=17 zero-padded)
  if (tid < 128){
    int mt = tid >> 6;
    int l = mt*16 + nidx;
    ushort_t hh[8], ll[8];
    #pragma unroll
    for (int j = 0; j < 8; ++j){
      int k = quad*8 + j;
      float vv = (k < IN_DIM_) ? xs[l*IN_DIM_ + k] : 0.f;
      hh[j] = f2bf(vv); ll[j] = f2bf(vv - bf2f(hh[j]));
    }
    ((uint4*)xfhi)[tid] = pack8(hh); ((uint4*)xflo)[tid] = pack8(ll);
  }
  __syncthreads();

  // P2: GEMM1  h1 = relu(x @ w1^T + b1). wave wvi -> n-tile wvi (t range)
  {
    short8 axh0 = xfhi[lane],      axl0 = xflo[lane];
    short8 axh1 = xfhi[64 + lane], axl1 = xflo[64 + lane];
    short8 bh = w1bhi[wvi*64 + lane];
    short8 bl = w1blo[wvi*64 + lane];
    floatx4 a0 = {0.f,0.f,0.f,0.f}, a1 = {0.f,0.f,0.f,0.f};
    a0 = MFMA16(axh0, bh, a0); a0 = MFMA16(axh0, bl, a0); a0 = MFMA16(axl0, bh, a0);
    a1 = MFMA16(axh1, bh, a1); a1 = MFMA16(axh1, bl, a1); a1 = MFMA16(axl1, bh, a1);
    int t = wvi*16 + nidx;
    float bb = (t < TT_) ? b1[t] : 0.f;      // t=63 pad: B zeros -> acc 0 -> stores 0
    #pragma unroll
    for (int r = 0; r < 4; ++r){
      h1t[t*33 + quad*4 + r]      = fmaxf(a0[r] + bb, 0.f);
      h1t[t*33 + 16 + quad*4 + r] = fmaxf(a1[r] + bb, 0.f);
    }
  }
  __syncthreads();

  // P3: h1 A-fragments. slot = (mt*2+ks)*64+lane = tid
  {
    int mt = tid >> 7, ks = (tid >> 6) & 1;
    int l = mt*16 + nidx;
    ushort_t hh[8], ll[8];
    #pragma unroll
    for (int j = 0; j < 8; ++j){
      int k = ks*32 + quad*8 + j;
      float vv = h1t[k*33 + l];
      hh[j] = f2bf(vv); ll[j] = f2bf(vv - bf2f(hh[j]));
    }
    ((uint4*)h1fhi)[tid] = pack8(hh); ((uint4*)h1flo)[tid] = pack8(ll);
  }
  __syncthreads();

  // P4: GEMM2  h2 = relu(h1 @ w2^T + b2). wave wvi -> n-tile wvi
  {
    short8 ah[2][2], al[2][2];
    #pragma unroll
    for (int mt = 0; mt < 2; ++mt)
      #pragma unroll
      for (int ks = 0; ks < 2; ++ks){
        ah[mt][ks] = h1fhi[(mt*2+ks)*64 + lane];
        al[mt][ks] = h1flo[(mt*2+ks)*64 + lane];
      }
    short8 bh0 = w2bhi[(wvi*2+0)*64 + lane], bl0 = w2blo[(wvi*2+0)*64 + lane];
    short8 bh1 = w2bhi[(wvi*2+1)*64 + lane], bl1 = w2blo[(wvi*2+1)*64 + lane];
    floatx4 a0 = {0.f,0.f,0.f,0.f}, a1 = {0.f,0.f,0.f,0.f};
    a0 = MFMA16(ah[0][0], bh0, a0); a0 = MFMA16(ah[0][0], bl0, a0); a0 = MFMA16(al[0][0], bh0, a0);
    a0 = MFMA16(ah[0][1], bh1, a0); a0 = MFMA16(ah[0][1], bl1, a0); a0 = MFMA16(al[0][1], bh1, a0);
    a1 = MFMA16(ah[1][0], bh0, a1); a1 = MFMA16(ah[1][0], bl0, a1); a1 = MFMA16(al[1][0], bh0, a1);
    a1 = MFMA16(ah[1][1], bh1, a1); a1 = MFMA16(ah[1][1], bl1, a1); a1 = MFMA16(al[1][1], bh1, a1);
    int t = wvi*16 + nidx;
    float bb = (t < TT_) ? b2[t] : 0.f;
    #pragma unroll
    for (int r = 0; r < 4; ++r){
      h2t[t*33 + quad*4 + r]      = fmaxf(a0[r] + bb, 0.f);
      h2t[t*33 + 16 + quad*4 + r] = fmaxf(a1[r] + bb, 0.f);
    }
  }
  __syncthreads();

  // P5: h2 A-fragments (into region aliasing dead h1t)
  {
    int mt = tid >> 7, ks = (tid >> 6) & 1;
    int l = mt*16 + nidx;
    ushort_t hh[8], ll[8];
    #pragma unroll
    for (int j = 0; j < 8; ++j){
      int k = ks*32 + quad*8 + j;
      float vv = h2t[k*33 + l];
      hh[j] = f2bf(vv); ll[j] = f2bf(vv - bf2f(hh[j]));
    }
    ((uint4*)h2fhi)[tid] = pack8(hh); ((uint4*)h2flo)[tid] = pack8(ll);
  }
  __syncthreads();

  // P6: GEMM3  filt = h2 @ w3^T + b3, masked softmax over l, contract with x
  {
    short8 ah[2][2], al[2][2];
    #pragma unroll
    for (int mt = 0; mt < 2; ++mt)
      #pragma unroll
      for (int ks = 0; ks < 2; ++ks){
        ah[mt][ks] = h2fhi[(mt*2+ks)*64 + lane];
        al[mt][ks] = h2flo[(mt*2+ks)*64 + lane];
      }
    // prefetch first tile's B frags
    short8 nbh0 = w3bhi[(wvi*2+0)*64 + lane], nbl0 = w3blo[(wvi*2+0)*64 + lane];
    short8 nbh1 = w3bhi[(wvi*2+1)*64 + lane], nbl1 = w3blo[(wvi*2+1)*64 + lane];
    for (int it = 0; it < 17; ++it){
      int tile = wvi + it*4;                 // waves cover tiles 0..67
      short8 bh0 = nbh0, bl0 = nbl0, bh1 = nbh1, bl1 = nbl1;
      if (it < 16){
        int nt = tile + 4;
        nbh0 = w3bhi[(nt*2+0)*64 + lane]; nbl0 = w3blo[(nt*2+0)*64 + lane];
        nbh1 = w3bhi[(nt*2+1)*64 + lane]; nbl1 = w3blo[(nt*2+1)*64 + lane];
      }
      floatx4 a0 = {0.f,0.f,0.f,0.f}, a1 = {0.f,0.f,0.f,0.f};
      a0 = MFMA16(ah[0][0], bh0, a0); a0 = MFMA16(ah[0][0], bl0, a0); a0 = MFMA16(al[0][0], bh0, a0);
      a0 = MFMA16(ah[0][1], bh1, a0); a0 = MFMA16(ah[0][1], bl1, a0); a0 = MFMA16(al[0][1], bh1, a0);
      a1 = MFMA16(ah[1][0], bh0, a1); a1 = MFMA16(ah[1][0], bl0, a1); a1 = MFMA16(al[1][0], bh0, a1);
      a1 = MFMA16(ah[1][1], bh1, a1); a1 = MFMA16(ah[1][1], bl1, a1); a1 = MFMA16(al[1][1], bh1, a1);

      int c = tile*16 + nidx;
      bool valid = c < 1071;
      int t = (c * 3856) >> 16;              // c/17 (exact for c<1088)
      int ii = c - t*17;
      float bb = valid ? b3s[c] : 0.f;
      float f[8];
      #pragma unroll
      for (int r = 0; r < 4; ++r){
        int l0 = quad*4 + r;
        f[r]     = (msv[l0]      != 0.f) ? (a0[r] + bb) : -1e8f;
        f[r + 4] = (msv[l0 + 16] != 0.f) ? (a1[r] + bb) : -1e8f;
      }
      float mx = f[0];
      #pragma unroll
      for (int r = 1; r < 8; ++r) mx = fmaxf(mx, f[r]);
      mx = fmaxf(mx, __shfl_xor(mx, 16, 64));
      mx = fmaxf(mx, __shfl_xor(mx, 32, 64));
      float den = 0.f, num = 0.f;
      #pragma unroll
      for (int r = 0; r < 4; ++r){
        int l0 = quad*4 + r;
        float e0 = __expf(f[r] - mx);     den += e0; num += e0 * xs[l0*IN_DIM_ + ii];
        float e1 = __expf(f[r+4] - mx);   den += e1; num += e1 * xs[(l0+16)*IN_DIM_ + ii];
      }
      den += __shfl_xor(den, 16, 64); den += __shfl_xor(den, 32, 64);
      num += __shfl_xor(num, 16, 64); num += __shfl_xor(num, 32, 64);
      if (quad == 0 && valid) colres[c] = num / den;
    }
  }
  __syncthreads();

  // P7: h_t[t] = relu(sum_i colres[t*17+i] + tb[t]); append mask_patch
  if (tid < TT_){
    float acc = 0.f;
    #pragma unroll
    for (int i2 = 0; i2 < IN_DIM_; ++i2) acc += colres[tid*IN_DIM_ + i2];
    xp[p*D_ + tid] = fmaxf(acc + tb[tid], 0.f);
  }
  if (tid == TT_){
    float s = 0.f;
    #pragma unroll
    for (int l = 0; l < LX; ++l) s += msv[l];
    float mp = (s > 0.f) ? 1.f : 0.f;
    xp[p*D_ + TT_] = mp;
    pm[p] = mp;
  }
}

// -------------------------------------------------------------------------
// One full transformer layer. One block per (b,n); M=16 tokens.
// -------------------------------------------------------------------------
__global__ __launch_bounds__(256) void layer_kernel(
    const float* __restrict__ xin, const float* __restrict__ pm,
    const float* __restrict__ qw, const float* __restrict__ qb,
    const float* __restrict__ kw, const float* __restrict__ kb,
    const float* __restrict__ vw, const float* __restrict__ vb,
    const float* __restrict__ ow, const float* __restrict__ ob,
    const float* __restrict__ in_w, const float* __restrict__ in_b,
    const float* __restrict__ out_w, const float* __restrict__ out_b,
    const float* __restrict__ ln1g, const float* __restrict__ ln1b,
    const float* __restrict__ ln2g, const float* __restrict__ ln2b,
    const float* __restrict__ fw1, const float* __restrict__ fb1,
    const float* __restrict__ fw2, const float* __restrict__ fb2,
    float* __restrict__ xout, int add_residual)
{
  const int bn = blockIdx.x;
  const int tid = threadIdx.x;
  __shared__ __align__(16) float xb[M_ * D_];
  __shared__ __align__(16) float qs[M_ * D_];
  __shared__ __align__(16) float ks[M_ * D_];
  __shared__ __align__(16) float vs[M_ * D_];
  __shared__ __align__(16) float ss[H_ * M_ * M_];
  __shared__ __align__(16) float hidden[4 * FF_];
  __shared__ __align__(16) float red[4 * 4 * D_];
  __shared__ float pmv[M_], mur[M_], rvr[M_];

  const float* xin_p = xin + bn * (M_ * D_);
  for (int o = tid; o < M_ * D_; o += 256) xb[o] = xin_p[o];
  if (tid < M_) pmv[tid] = pm[bn * M_ + tid];
  __syncthreads();

  // ======== patch gattn ========
  for (int o = tid; o < 3 * M_ * D_; o += 256) {
    int sel = o >> 10, r = o & 1023, m = r >> 6, d = r & 63;
    const float* W = (sel == 0) ? qw : (sel == 1) ? kw : vw;
    const float* Bv = (sel == 0) ? qb : (sel == 1) ? kb : vb;
    float acc = Bv[d] + dot64(xb + m * D_, W + d * D_);
    ((sel == 0) ? qs : (sel == 1) ? ks : vs)[r] = acc;
  }
  __syncthreads();
  for (int o = tid; o < H_ * M_ * M_; o += 256) {
    int h = o >> 8, r = o & 255, qm = r >> 4, km = r & 15;
    float acc = dot16(qs + qm * D_ + h * DH_, ks + km * D_ + h * DH_);
    float dist = 5.0f * fabsf((float)(qm - km));         // |i-j|*DELTA/TAU
    float tbv = logf(expf(-dist) + 1e-12f);
    acc = acc * 0.25f + tbv;
    if (pmv[km] == 0.f) acc = -1e9f;
    ss[o] = acc;
  }
  __syncthreads();
  if (tid < H_ * M_) {
    float* row = ss + tid * M_;
    float mx = -1e30f;
    #pragma unroll
    for (int j = 0; j < M_; ++j) mx = fmaxf(mx, row[j]);
    float se = 0.f;
    #pragma unroll
    for (int j = 0; j < M_; ++j) { float e = __expf(row[j] - mx); row[j] = e; se += e; }
    float inv = 1.f / se;
    #pragma unroll
    for (int j = 0; j < M_; ++j) row[j] *= inv;
  }
  __syncthreads();
  for (int o = tid; o < M_ * D_; o += 256) {
    int m = o >> 6, d = o & 63, h = d >> 4;
    float acc = 0.f;
    #pragma unroll
    for (int km = 0; km < M_; ++km) acc += ss[h * 256 + m * M_ + km] * vs[km * D_ + d];
    qs[o] = acc;
  }
  __syncthreads();
  for (int o = tid; o < M_ * D_; o += 256) {   // proj*pm + residual + pos-enc
    int m = o >> 6, d = o & 63;
    float acc = ob[d] + dot64(qs + m * D_, ow + d * D_);
    acc *= pmv[m];
    int kp = d >> 1;
    float div = expf((float)(2 * kp) * (-9.210340371976184f / 64.f));
    float arg = (float)m * div;
    float pev = (d & 1) ? cosf(arg) : sinf(arg);
    xb[o] = xb[o] + acc + pev;
  }
  __syncthreads();

  // ======== tf MHA ========
  for (int o = tid; o < 3 * M_ * D_; o += 256) {
    int sel = o >> 10, r = o & 1023, m = r >> 6, d = r & 63;
    float acc = in_b[sel * D_ + d] + dot64(xb + m * D_, in_w + (sel * D_ + d) * D_);
    ((sel == 0) ? qs : (sel == 1) ? ks : vs)[r] = acc;
  }
  __syncthreads();
  for (int o = tid; o < H_ * M_ * M_; o += 256) {
    int h = o >> 8, r = o & 255, qm = r >> 4, km = r & 15;
    ss[o] = 0.25f * dot16(qs + qm * D_ + h * DH_, ks + km * D_ + h * DH_);
  }
  __syncthreads();
  if (tid < H_ * M_) {
    float* row = ss + tid * M_;
    float mx = -1e30f;
    #pragma unroll
    for (int j = 0; j < M_; ++j) mx = fmaxf(mx, row[j]);
    float se = 0.f;
    #pragma unroll
    for (int j = 0; j < M_; ++j) { float e = __expf(row[j] - mx); row[j] = e; se += e; }
    float inv = 1.f / se;
    #pragma unroll
    for (int j = 0; j < M_; ++j) row[j] *= inv;
  }
  __syncthreads();
  for (int o = tid; o < M_ * D_; o += 256) {
    int m = o >> 6, d = o & 63, h = d >> 4;
    float acc = 0.f;
    #pragma unroll
    for (int km = 0; km < M_; ++km) acc += ss[h * 256 + m * M_ + km] * vs[km * D_ + d];
    qs[o] = acc;
  }
  __syncthreads();
  for (int o = tid; o < M_ * D_; o += 256) {
    int m = o >> 6, d = o & 63;
    xb[o] += out_b[d] + dot64(qs + m * D_, out_w + d * D_);
  }
  __syncthreads();

  // ======== LN1 ========
  if (tid < M_) {
    const float* row = xb + tid * D_;
    float mu = 0.f;
    #pragma unroll
    for (int d = 0; d < D_; ++d) mu += row[d];
    mu *= (1.f / 64.f);
    float var = 0.f;
    #pragma unroll
    for (int d = 0; d < D_; ++d) { float t = row[d] - mu; var += t * t; }
    var *= (1.f / 64.f);
    mur[tid] = mu; rvr[tid] = rsqrtf(var + 1e-5f);
  }
  __syncthreads();
  for (int o = tid; o < M_ * D_; o += 256) {
    int m = o >> 6, d = o & 63;
    xb[o] = (xb[o] - mur[m]) * rvr[m] * ln1g[d] + ln1b[d];
  }
  __syncthreads();

  // ======== FF (2048 hidden), 4 tokens per chunk ========
  for (int chunk = 0; chunk < 4; ++chunk) {
    const int t0 = chunk * 4;
    for (int j = tid; j < FF_; j += 256) {
      const float4* wr4 = (const float4*)(fw1 + j * D_);
      const float4* x0 = (const float4*)(xb + (t0 + 0) * D_);
      const float4* x1 = (const float4*)(xb + (t0 + 1) * D_);
      const float4* x2 = (const float4*)(xb + (t0 + 2) * D_);
      const float4* x3 = (const float4*)(xb + (t0 + 3) * D_);
      float a0 = fb1[j], a1 = a0, a2 = a0, a3 = a0;
      #pragma unroll
      for (int kk = 0; kk < 16; ++kk) {
        float4 wvv = wr4[kk];
        float4 v0 = x0[kk], v1 = x1[kk], v2 = x2[kk], v3 = x3[kk];
        a0 += wvv.x*v0.x + wvv.y*v0.y + wvv.z*v0.z + wvv.w*v0.w;
        a1 += wvv.x*v1.x + wvv.y*v1.y + wvv.z*v1.z + wvv.w*v1.w;
        a2 += wvv.x*v2.x + wvv.y*v2.y + wvv.z*v2.z + wvv.w*v2.w;
        a3 += wvv.x*v3.x + wvv.y*v3.y + wvv.z*v3.z + wvv.w*v3.w;
      }
      hidden[0 * FF_ + j] = fmaxf(a0, 0.f);
      hidden[1 * FF_ + j] = fmaxf(a1, 0.f);
      hidden[2 * FF_ + j] = fmaxf(a2, 0.f);
      hidden[3 * FF_ + j] = fmaxf(a3, 0.f);
    }
    __syncthreads();
    {
      int d = tid & 63, qq = tid >> 6;        // qq in [0,4): j-quarter
      const float4* wr4 = (const float4*)(fw2 + d * FF_ + qq * 512);
      const float4* h04 = (const float4*)(hidden + 0 * FF_ + qq * 512);
      const float4* h14 = (const float4*)(hidden + 1 * FF_ + qq * 512);
      const float4* h24 = (const float4*)(hidden + 2 * FF_ + qq * 512);
      const float4* h34 = (const float4*)(hidden + 3 * FF_ + qq * 512);
      float p0 = 0.f, p1 = 0.f, p2 = 0.f, p3 = 0.f;
      #pragma unroll 4
      for (int j = 0; j < 128; ++j) {
        float4 wvv = wr4[j];
        float4 a0 = h04[j], a1 = h14[j], a2 = h24[j], a3 = h34[j];
        p0 += wvv.x*a0.x + wvv.y*a0.y + wvv.z*a0.z + wvv.w*a0.w;
        p1 += wvv.x*a1.x + wvv.y*a1.y + wvv.z*a1.z + wvv.w*a1.w;
        p2 += wvv.x*a2.x + wvv.y*a2.y + wvv.z*a2.z + wvv.w*a2.w;
        p3 += wvv.x*a3.x + wvv.y*a3.y + wvv.z*a3.z + wvv.w*a3.w;
      }
      red[(qq * 4 + 0) * D_ + d] = p0;
      red[(qq * 4 + 1) * D_ + d] = p1;
      red[(qq * 4 + 2) * D_ + d] = p2;
      red[(qq * 4 + 3) * D_ + d] = p3;
    }
    __syncthreads();
    {
      int tt = tid >> 6, d = tid & 63;
      float acc = fb2[d];
      #pragma unroll
      for (int qq = 0; qq < 4; ++qq) acc += red[(qq * 4 + tt) * D_ + d];
      xb[(t0 + tt) * D_ + d] += acc;
    }
    __syncthreads();
  }

  // ======== LN2 ========
  if (tid < M_) {
    const float* row = xb + tid * D_;
    float mu = 0.f;
    #pragma unroll
    for (int d = 0; d < D_; ++d) mu += row[d];
    mu *= (1.f / 64.f);
    float var = 0.f;
    #pragma unroll
    for (int d = 0; d < D_; ++d) { float t = row[d] - mu; var += t * t; }
    var *= (1.f / 64.f);
    mur[tid] = mu; rvr[tid] = rsqrtf(var + 1e-5f);
  }
  __syncthreads();
  float* xo = xout + bn * (M_ * D_);
  for (int o = tid; o < M_ * D_; o += 256) {
    int m = o >> 6, d = o & 63;
    float v = (xb[o] - mur[m]) * rvr[m] * ln2g[d] + ln2b[d];
    xo[o] = v + (add_residual ? xin_p[o] : 0.f);
  }
}

// -------------------------------------------------------------------------
// Classifier head. One block per b.
// -------------------------------------------------------------------------
__global__ __launch_bounds__(256) void final_kernel(
    const float* __restrict__ xc, const float* __restrict__ pm,
    const float* __restrict__ q_embed,
    const float* __restrict__ cin_w, const float* __restrict__ cin_b,
    const float* __restrict__ cout_w, const float* __restrict__ cout_b,
    const float* __restrict__ logit_w, const float* __restrict__ logit_b,
    float* __restrict__ out)
{
  const int b = blockIdx.x;
  const int tid = threadIdx.x;
  __shared__ __align__(16) float xs[M_ * D_];
  __shared__ float kpmv[M_];
  __shared__ __align__(16) float qv[5 * D_], kv[M_ * D_], vv[M_ * D_];
  __shared__ float sv[H_ * 5 * M_];
  __shared__ __align__(16) float ao[5 * D_], zv[5 * D_];

  for (int o = tid; o < M_ * D_; o += 256) {
    int m = o >> 6, d = o & 63;
    float acc = 0.f;
    #pragma unroll
    for (int n = 0; n < N_; ++n) acc += xc[(((b * N_ + n) * M_ + m) * D_) + d];
    xs[o] = acc * (1.f / 32.f);
  }
  if (tid < M_) {
    float any = 0.f;
    #pragma unroll
    for (int n = 0; n < N_; ++n) any += (pm[(b * N_ + n) * M_ + tid] > 0.f) ? 1.f : 0.f;
    kpmv[tid] = (any > 0.f) ? 0.f : 1.f;   // 1 => masked key
  }
  __syncthreads();

  for (int o = tid; o < 5 * D_; o += 256) {
    int qi = o >> 6, d = o & 63;
    qv[o] = cin_b[d] + dot64(q_embed + qi * D_, cin_w + d * D_);
  }
  for (int o = tid; o < 2 * M_ * D_; o += 256) {
    int sel = o >> 10, r = o & 1023, m = r >> 6, d = r & 63;
    float acc = cin_b[D_ + sel * D_ + d] + dot64(xs + m * D_, cin_w + (D_ + sel * D_ + d) * D_);
    ((sel == 0) ? kv : vv)[r] = acc;
  }
  __syncthreads();

  for (int o = tid; o < H_ * 5 * M_; o += 256) {
    int h = o / 80, r = o % 80, qi = r >> 4, km = r & 15;
    float acc = 0.25f * dot16(qv + qi * D_ + h * DH_, kv + km * D_ + h * DH_);
    if (kpmv[km] != 0.f) acc = -1e9f;
    sv[o] = acc;
  }
  __syncthreads();
  if (tid < H_ * 5) {
    int h = tid / 5, qi = tid % 5;
    float* row = sv + h * 80 + qi * M_;
    float mx = -1e30f;
    #pragma unroll
    for (int km = 0; km < M_; ++km) mx = fmaxf(mx, row[km]);
    float se = 0.f;
    #pragma unroll
    for (int km = 0; km < M_; ++km) { float e = __expf(row[km] - mx); row[km] = e; se += e; }
    float inv = 1.f / se;
    #pragma unroll
    for (int km = 0; km < M_; ++km) row[km] *= inv;
  }
  __syncthreads();
  for (int o = tid; o < 5 * D_; o += 256) {
    int qi = o >> 6, d = o & 63, h = d >> 4;
    float acc = 0.f;
    #pragma unroll
    for (int km = 0; km < M_; ++km) acc += sv[h * 80 + qi * M_ + km] * vv[km * D_ + d];
    ao[o] = acc;
  }
  __syncthreads();
  for (int o = tid; o < 5 * D_; o += 256) {
    int qi = o >> 6, d = o & 63;
    zv[o] = cout_b[d] + dot64(ao + qi * D_, cout_w + d * D_);
  }
  __syncthreads();
  if (tid < 5) {
    float acc = logit_b[0] + dot64(zv + tid * D_, logit_w);
    out[b * 5 + tid] = acc;
  }
}

// -------------------------------------------------------------------------
extern "C" void kernel_launch(void* const* d_in, const int* in_sizes, int n_in,
                              void* d_out, int out_size, void* d_ws, size_t ws_size,
                              hipStream_t stream) {
  const float* x       = (const float*)d_in[0];
  const int*   mask    = (const int*)  d_in[1];
  const float* ttcn_w1 = (const float*)d_in[2];
  const float* ttcn_b1 = (const float*)d_in[3];
  const float* ttcn_w2 = (const float*)d_in[4];
  const float* ttcn_b2 = (const float*)d_in[5];
  const float* ttcn_w3 = (const float*)d_in[6];
  const float* ttcn_b3 = (const float*)d_in[7];
  const float* t_bias  = (const float*)d_in[8];
  const float* ga_qw   = (const float*)d_in[9];
  const float* ga_qb   = (const float*)d_in[10];
  const float* ga_kw   = (const float*)d_in[11];
  const float* ga_kb   = (const float*)d_in[12];
  const float* ga_vw   = (const float*)d_in[13];
  const float* ga_vb   = (const float*)d_in[14];
  const float* ga_ow   = (const float*)d_in[15];
  const float* ga_ob   = (const float*)d_in[16];
  const float* tf_in_w = (const float*)d_in[17];
  const float* tf_in_b = (const float*)d_in[18];
  const float* tf_out_w= (const float*)d_in[19];
  const float* tf_out_b= (const float*)d_in[20];
  const float* tf_ln1g = (const float*)d_in[21];
  const float* tf_ln1b = (const float*)d_in[22];
  const float* tf_ln2g = (const float*)d_in[23];
  const float* tf_ln2b = (const float*)d_in[24];
  const float* tf_fw1  = (const float*)d_in[25];
  const float* tf_fb1  = (const float*)d_in[26];
  const float* tf_fw2  = (const float*)d_in[27];
  const float* tf_fb2  = (const float*)d_in[28];
  const float* q_embed = (const float*)d_in[29];
  const float* cls_in_w  = (const float*)d_in[30];
  const float* cls_in_b  = (const float*)d_in[31];
  const float* cls_out_w = (const float*)d_in[32];
  const float* cls_out_b = (const float*)d_in[33];
  const float* logit_w = (const float*)d_in[34];
  const float* logit_b = (const float*)d_in[35];

  float* wsf = (float*)d_ws;
  float* xp   = wsf;                        // 262144 f
  float* pmb  = wsf + P_TOT * D_;           // 4096 f
  float* xa   = pmb + P_TOT;                // 262144 f
  float* xbuf = xa  + P_TOT * D_;           // 262144 f
  unsigned short* w3bhi = (unsigned short*)(xbuf + P_TOT * D_);  // 69632 bf16
  unsigned short* w3blo = w3bhi + 69632;
  unsigned short* w1bhi = w3blo + 69632;    // 2048 bf16
  unsigned short* w1blo = w1bhi + 2048;
  unsigned short* w2bhi = w1blo + 2048;     // 4096 bf16
  unsigned short* w2blo = w2bhi + 4096;

  prep_kernel<<<37, 256, 0, stream>>>(ttcn_w1, ttcn_w2, ttcn_w3,
      (uint4*)w1bhi, (uint4*)w1blo, (uint4*)w2bhi, (uint4*)w2blo,
      (uint4*)w3bhi, (uint4*)w3blo);

  ttcn_kernel<<<P_TOT, 256, 0, stream>>>(x, mask, ttcn_b1, ttcn_b2, ttcn_b3, t_bias,
      (const short8*)w1bhi, (const short8*)w1blo,
      (const short8*)w2bhi, (const short8*)w2blo,
      (const short8*)w3bhi, (const short8*)w3blo,
      xp, pmb);

  layer_kernel<<<BN_, 256, 0, stream>>>(
      xp, pmb,
      ga_qw, ga_qb, ga_kw, ga_kb, ga_vw, ga_vb, ga_ow, ga_ob,
      tf_in_w, tf_in_b, tf_out_w, tf_out_b,
      tf_ln1g, tf_ln1b, tf_ln2g, tf_ln2b,
      tf_fw1, tf_fb1, tf_fw2, tf_fb2,
      xa, 0);

  layer_kernel<<<BN_, 256, 0, stream>>>(
      xa, pmb,
      ga_qw + D_*D_, ga_qb + D_, ga_kw + D_*D_, ga_kb + D_,
      ga_vw + D_*D_, ga_vb + D_, ga_ow + D_*D_, ga_ob + D_,
      tf_in_w + 3*D_*D_, tf_in_b + 3*D_, tf_out_w + D_*D_, tf_out_b + D_,
      tf_ln1g + D_, tf_ln1b + D_, tf_ln2g + D_, tf_ln2b + D_,
      tf_fw1 + FF_*D_, tf_fb1 + FF_, tf_fw2 + D_*FF_, tf_fb2 + D_,
      xbuf, 1);

  final_kernel<<<B_, 256, 0, stream>>>(xbuf, pmb, q_embed,
                                       cls_in_w, cls_in_b, cls_out_w, cls_out_b,
                                       logit_w, logit_b, (float*)d_out);
}

// Round 3
// 316.344 us; speedup vs baseline: 5.1950x; 1.9074x over previous
//
#include <hip/hip_runtime.h>
#include <hip/hip_bf16.h>
#include <math.h>

// Problem constants
#define B_  8
#define N_  32
#define M_  16
#define LX  32
#define D_  64
#define IN_DIM_ 17
#define TT_ 63
#define H_  4
#define DH_ 16
#define P_TOT 4096          // B*N*M
#define BN_ 256             // B*N
#define FF_ 2048

// Fragment pool layout (slot = one short8/uint4 per lane-group entry)
#define FRAG_TOT 83200
#define LBASE(l) (9472 + (l)*36864)
#define OFF_INW  2048
#define OFF_OUTW 3584
#define OFF_FW1  4096
#define OFF_FW2  20480
#define XF_LO    32768      // lo offset in xfrag (short8 units)

typedef unsigned short ushort_t;
typedef __attribute__((ext_vector_type(8))) short short8;   // 8 bf16 (4 VGPRs)
typedef __attribute__((ext_vector_type(4))) float floatx4;  // MFMA C/D

#define MFMA16(a,b,c) __builtin_amdgcn_mfma_f32_16x16x32_bf16((a),(b),(c),0,0,0)

__device__ __forceinline__ ushort_t f2bf(float f){          // RNE float->bf16
  unsigned u = __float_as_uint(f);
  u += 0x7FFFu + ((u >> 16) & 1u);
  return (ushort_t)(u >> 16);
}
__device__ __forceinline__ float bf2f(ushort_t h){ return __uint_as_float(((unsigned)h) << 16); }

__device__ __forceinline__ uint4 pack8(const ushort_t* h){
  uint4 u;
  u.x = (unsigned)h[0] | ((unsigned)h[1] << 16);
  u.y = (unsigned)h[2] | ((unsigned)h[3] << 16);
  u.z = (unsigned)h[4] | ((unsigned)h[5] << 16);
  u.w = (unsigned)h[6] | ((unsigned)h[7] << 16);
  return u;
}

// split 8 consecutive floats into hi/lo bf16 short8
__device__ __forceinline__ void split8(const float* r, short8& hi, short8& lo){
  #pragma unroll
  for (int j = 0; j < 8; ++j){
    float v = r[j];
    ushort_t h = f2bf(v);
    ushort_t l2 = f2bf(v - bf2f(h));
    hi[j] = (short)h; lo[j] = (short)l2;
  }
}

// 3-term split product: (ah+al)(bh+bl) ~= ah*bh + ah*bl + al*bh
__device__ __forceinline__ floatx4 mm3(short8 ah, short8 al, short8 bh, short8 bl, floatx4 c){
  c = MFMA16(ah, bh, c); c = MFMA16(ah, bl, c); c = MFMA16(al, bh, c); return c;
}

__device__ __forceinline__ float dot64(const float* __restrict__ a, const float* __restrict__ w){
  const float4* a4 = (const float4*)a;
  const float4* w4 = (const float4*)w;
  float acc = 0.f;
  #pragma unroll
  for (int k = 0; k < 16; ++k){ float4 x = a4[k], y = w4[k];
    acc += x.x*y.x + x.y*y.y + x.z*y.z + x.w*y.w; }
  return acc;
}
__device__ __forceinline__ float dot16(const float* __restrict__ a, const float* __restrict__ b){
  const float4* a4 = (const float4*)a; const float4* b4 = (const float4*)b;
  float acc = 0.f;
  #pragma unroll
  for (int k = 0; k < 4; ++k){ float4 x = a4[k], y = b4[k];
    acc += x.x*y.x + x.y*y.y + x.z*y.z + x.w*y.w; }
  return acc;
}

// pack A-frags (16 tokens x 64 k) from stride-68 LDS buffer into fragA (hi[128], lo[128])
__device__ __forceinline__ void packA68(const float* buf, short8* fA, int tid){
  if (tid < 128){
    int ln = tid & 63, ks = tid >> 6;
    const float* r = buf + (ln & 15)*68 + ks*32 + ((ln >> 4) & 3)*8;
    short8 hi, lo; split8(r, hi, lo);
    fA[tid] = hi; fA[128 + tid] = lo;
  }
}

// -------------------------------------------------------------------------
// Prep: convert ALL weight matrices to MFMA B-fragment pool (hi at [s], lo at
// [FRAG_TOT+s]). B[k][n]: n = nt*16 + (lane&15), k = ks*32 + quad*8 + j.
// -------------------------------------------------------------------------
__global__ __launch_bounds__(256) void prep_kernel(
    const float* __restrict__ w1, const float* __restrict__ w2, const float* __restrict__ w3,
    const float* __restrict__ gqw, const float* __restrict__ gkw,
    const float* __restrict__ gvw, const float* __restrict__ gow,
    const float* __restrict__ inw, const float* __restrict__ outw,
    const float* __restrict__ fw1, const float* __restrict__ fw2,
    uint4* __restrict__ fr)
{
  int s = blockIdx.x*256 + threadIdx.x;
  if (s >= FRAG_TOT) return;
  const float* src; int Nr, Kr, KS, rel;
  if (s < 256)      { src = w1; Nr=63;  Kr=17; KS=1; rel = s; }
  else if (s < 768) { src = w2; Nr=63;  Kr=63; KS=2; rel = s-256; }
  else if (s < 9472){ src = w3; Nr=1071;Kr=63; KS=2; rel = s-768; }
  else {
    int t = s - 9472, l = t / 36864, r2 = t - l*36864;
    if (r2 < 512)        { src = gqw + l*4096;   Nr=64;  Kr=64;   KS=2;  rel = r2; }
    else if (r2 < 1024)  { src = gkw + l*4096;   Nr=64;  Kr=64;   KS=2;  rel = r2-512; }
    else if (r2 < 1536)  { src = gvw + l*4096;   Nr=64;  Kr=64;   KS=2;  rel = r2-1024; }
    else if (r2 < 2048)  { src = gow + l*4096;   Nr=64;  Kr=64;   KS=2;  rel = r2-1536; }
    else if (r2 < 3584)  { src = inw + l*12288;  Nr=192; Kr=64;   KS=2;  rel = r2-2048; }
    else if (r2 < 4096)  { src = outw + l*4096;  Nr=64;  Kr=64;   KS=2;  rel = r2-3584; }
    else if (r2 < 20480) { src = fw1 + l*131072; Nr=2048;Kr=64;   KS=2;  rel = r2-4096; }
    else                 { src = fw2 + l*131072; Nr=64;  Kr=2048; KS=64; rel = r2-20480; }
  }
  int lane = rel & 63, tmp = rel >> 6;
  int ks = tmp % KS, nt = tmp / KS;
  int n = nt*16 + (lane & 15), kb = ks*32 + ((lane >> 4) & 3)*8;
  float v[8];
  #pragma unroll
  for (int j = 0; j < 8; ++j) v[j] = (n < Nr && (kb + j) < Kr) ? src[n*Kr + kb + j] : 0.f;
  ushort_t hh[8], ll[8];
  #pragma unroll
  for (int j = 0; j < 8; ++j){ hh[j] = f2bf(v[j]); ll[j] = f2bf(v[j] - bf2f(hh[j])); }
  fr[s] = pack8(hh); fr[FRAG_TOT + s] = pack8(ll);
}

// -------------------------------------------------------------------------
// Fused TTCN (unchanged from R2 pass). One block per patch.
// -------------------------------------------------------------------------
__global__ __launch_bounds__(256) void ttcn_kernel(
    const float* __restrict__ x, const int* __restrict__ mask,
    const float* __restrict__ b1, const float* __restrict__ b2,
    const float* __restrict__ b3, const float* __restrict__ tb,
    const short8* __restrict__ w1bhi, const short8* __restrict__ w1blo,
    const short8* __restrict__ w2bhi, const short8* __restrict__ w2blo,
    const short8* __restrict__ w3bhi, const short8* __restrict__ w3blo,
    float* __restrict__ xp, float* __restrict__ pm)
{
  __shared__ __align__(16) char pool[36032];
  float*  xs    = (float*)(pool + 0);
  float*  msv   = (float*)(pool + 2176);
  float*  b3s   = (float*)(pool + 2304);
  float*  h1t   = (float*)(pool + 6592);
  short8* h2fhi = (short8*)(pool + 6592);
  short8* h2flo = (short8*)(pool + 10688);
  float*  h2t   = (float*)(pool + 15040);
  short8* xfhi  = (short8*)(pool + 23488);
  short8* xflo  = (short8*)(pool + 25536);
  short8* h1fhi = (short8*)(pool + 27584);
  short8* h1flo = (short8*)(pool + 31680);
  float*  colres= (float*)(pool + 27584);

  const int p = blockIdx.x, tid = threadIdx.x;
  const int lane = tid & 63, wvi = tid >> 6;
  const int nidx = lane & 15, quad = lane >> 4;

  for (int i = tid; i < LX*IN_DIM_; i += 256) xs[i] = x[p*(LX*IN_DIM_) + i];
  if (tid < LX) msv[tid] = (float)mask[p*LX + tid];
  for (int i = tid; i < 1071; i += 256) b3s[i] = b3[i];
  __syncthreads();

  if (tid < 128){
    int mt = tid >> 6;
    int l = mt*16 + nidx;
    ushort_t hh[8], ll[8];
    #pragma unroll
    for (int j = 0; j < 8; ++j){
      int k = quad*8 + j;
      float vv = (k < IN_DIM_) ? xs[l*IN_DIM_ + k] : 0.f;
      hh[j] = f2bf(vv); ll[j] = f2bf(vv - bf2f(hh[j]));
    }
    ((uint4*)xfhi)[tid] = pack8(hh); ((uint4*)xflo)[tid] = pack8(ll);
  }
  __syncthreads();

  {
    short8 axh0 = xfhi[lane],      axl0 = xflo[lane];
    short8 axh1 = xfhi[64 + lane], axl1 = xflo[64 + lane];
    short8 bh = w1bhi[wvi*64 + lane];
    short8 bl = w1blo[wvi*64 + lane];
    floatx4 a0 = {0.f,0.f,0.f,0.f}, a1 = {0.f,0.f,0.f,0.f};
    a0 = MFMA16(axh0, bh, a0); a0 = MFMA16(axh0, bl, a0); a0 = MFMA16(axl0, bh, a0);
    a1 = MFMA16(axh1, bh, a1); a1 = MFMA16(axh1, bl, a1); a1 = MFMA16(axl1, bh, a1);
    int t = wvi*16 + nidx;
    float bb = (t < TT_) ? b1[t] : 0.f;
    #pragma unroll
    for (int r = 0; r < 4; ++r){
      h1t[t*33 + quad*4 + r]      = fmaxf(a0[r] + bb, 0.f);
      h1t[t*33 + 16 + quad*4 + r] = fmaxf(a1[r] + bb, 0.f);
    }
  }
  __syncthreads();

  {
    int mt = tid >> 7, ks = (tid >> 6) & 1;
    int l = mt*16 + nidx;
    ushort_t hh[8], ll[8];
    #pragma unroll
    for (int j = 0; j < 8; ++j){
      int k = ks*32 + quad*8 + j;
      float vv = h1t[k*33 + l];
      hh[j] = f2bf(vv); ll[j] = f2bf(vv - bf2f(hh[j]));
    }
    ((uint4*)h1fhi)[tid] = pack8(hh); ((uint4*)h1flo)[tid] = pack8(ll);
  }
  __syncthreads();

  {
    short8 ah[2][2], al[2][2];
    #pragma unroll
    for (int mt = 0; mt < 2; ++mt)
      #pragma unroll
      for (int ks = 0; ks < 2; ++ks){
        ah[mt][ks] = h1fhi[(mt*2+ks)*64 + lane];
        al[mt][ks] = h1flo[(mt*2+ks)*64 + lane];
      }
    short8 bh0 = w2bhi[(wvi*2+0)*64 + lane], bl0 = w2blo[(wvi*2+0)*64 + lane];
    short8 bh1 = w2bhi[(wvi*2+1)*64 + lane], bl1 = w2blo[(wvi*2+1)*64 + lane];
    floatx4 a0 = {0.f,0.f,0.f,0.f}, a1 = {0.f,0.f,0.f,0.f};
    a0 = MFMA16(ah[0][0], bh0, a0); a0 = MFMA16(ah[0][0], bl0, a0); a0 = MFMA16(al[0][0], bh0, a0);
    a0 = MFMA16(ah[0][1], bh1, a0); a0 = MFMA16(ah[0][1], bl1, a0); a0 = MFMA16(al[0][1], bh1, a0);
    a1 = MFMA16(ah[1][0], bh0, a1); a1 = MFMA16(ah[1][0], bl0, a1); a1 = MFMA16(al[1][0], bh0, a1);
    a1 = MFMA16(ah[1][1], bh1, a1); a1 = MFMA16(ah[1][1], bl1, a1); a1 = MFMA16(al[1][1], bh1, a1);
    int t = wvi*16 + nidx;
    float bb = (t < TT_) ? b2[t] : 0.f;
    #pragma unroll
    for (int r = 0; r < 4; ++r){
      h2t[t*33 + quad*4 + r]      = fmaxf(a0[r] + bb, 0.f);
      h2t[t*33 + 16 + quad*4 + r] = fmaxf(a1[r] + bb, 0.f);
    }
  }
  __syncthreads();

  {
    int mt = tid >> 7, ks = (tid >> 6) & 1;
    int l = mt*16 + nidx;
    ushort_t hh[8], ll[8];
    #pragma unroll
    for (int j = 0; j < 8; ++j){
      int k = ks*32 + quad*8 + j;
      float vv = h2t[k*33 + l];
      hh[j] = f2bf(vv); ll[j] = f2bf(vv - bf2f(hh[j]));
    }
    ((uint4*)h2fhi)[tid] = pack8(hh); ((uint4*)h2flo)[tid] = pack8(ll);
  }
  __syncthreads();

  {
    short8 ah[2][2], al[2][2];
    #pragma unroll
    for (int mt = 0; mt < 2; ++mt)
      #pragma unroll
      for (int ks = 0; ks < 2; ++ks){
        ah[mt][ks] = h2fhi[(mt*2+ks)*64 + lane];
        al[mt][ks] = h2flo[(mt*2+ks)*64 + lane];
      }
    short8 nbh0 = w3bhi[(wvi*2+0)*64 + lane], nbl0 = w3blo[(wvi*2+0)*64 + lane];
    short8 nbh1 = w3bhi[(wvi*2+1)*64 + lane], nbl1 = w3blo[(wvi*2+1)*64 + lane];
    for (int it = 0; it < 17; ++it){
      int tile = wvi + it*4;
      short8 bh0 = nbh0, bl0 = nbl0, bh1 = nbh1, bl1 = nbl1;
      if (it < 16){
        int nt = tile + 4;
        nbh0 = w3bhi[(nt*2+0)*64 + lane]; nbl0 = w3blo[(nt*2+0)*64 + lane];
        nbh1 = w3bhi[(nt*2+1)*64 + lane]; nbl1 = w3blo[(nt*2+1)*64 + lane];
      }
      floatx4 a0 = {0.f,0.f,0.f,0.f}, a1 = {0.f,0.f,0.f,0.f};
      a0 = MFMA16(ah[0][0], bh0, a0); a0 = MFMA16(ah[0][0], bl0, a0); a0 = MFMA16(al[0][0], bh0, a0);
      a0 = MFMA16(ah[0][1], bh1, a0); a0 = MFMA16(ah[0][1], bl1, a0); a0 = MFMA16(al[0][1], bh1, a0);
      a1 = MFMA16(ah[1][0], bh0, a1); a1 = MFMA16(ah[1][0], bl0, a1); a1 = MFMA16(al[1][0], bh0, a1);
      a1 = MFMA16(ah[1][1], bh1, a1); a1 = MFMA16(ah[1][1], bl1, a1); a1 = MFMA16(al[1][1], bh1, a1);

      int c = tile*16 + nidx;
      bool valid = c < 1071;
      int t = (c * 3856) >> 16;
      int ii = c - t*17;
      float bb = valid ? b3s[c] : 0.f;
      float f[8];
      #pragma unroll
      for (int r = 0; r < 4; ++r){
        int l0 = quad*4 + r;
        f[r]     = (msv[l0]      != 0.f) ? (a0[r] + bb) : -1e8f;
        f[r + 4] = (msv[l0 + 16] != 0.f) ? (a1[r] + bb) : -1e8f;
      }
      float mx = f[0];
      #pragma unroll
      for (int r = 1; r < 8; ++r) mx = fmaxf(mx, f[r]);
      mx = fmaxf(mx, __shfl_xor(mx, 16, 64));
      mx = fmaxf(mx, __shfl_xor(mx, 32, 64));
      float den = 0.f, num = 0.f;
      #pragma unroll
      for (int r = 0; r < 4; ++r){
        int l0 = quad*4 + r;
        float e0 = __expf(f[r] - mx);     den += e0; num += e0 * xs[l0*IN_DIM_ + ii];
        float e1 = __expf(f[r+4] - mx);   den += e1; num += e1 * xs[(l0+16)*IN_DIM_ + ii];
      }
      den += __shfl_xor(den, 16, 64); den += __shfl_xor(den, 32, 64);
      num += __shfl_xor(num, 16, 64); num += __shfl_xor(num, 32, 64);
      if (quad == 0 && valid) colres[c] = num / den;
    }
  }
  __syncthreads();

  if (tid < TT_){
    float acc = 0.f;
    #pragma unroll
    for (int i2 = 0; i2 < IN_DIM_; ++i2) acc += colres[tid*IN_DIM_ + i2];
    xp[p*D_ + tid] = fmaxf(acc + tb[tid], 0.f);
  }
  if (tid == TT_){
    float s = 0.f;
    #pragma unroll
    for (int l = 0; l < LX; ++l) s += msv[l];
    float mp = (s > 0.f) ? 1.f : 0.f;
    xp[p*D_ + TT_] = mp;
    pm[p] = mp;
  }
}

// -------------------------------------------------------------------------
// Attention half of a layer: gattn + pe + MHA + LN1. One block per bn.
// All projections via split-bf16 MFMA. Emits xb2 (fp32) + its A-frags.
// LDS rows stride 68 (16B-aligned, conflict-free: 17*tok mod 32 distinct).
// -------------------------------------------------------------------------
__global__ __launch_bounds__(256) void attn_kernel(
    const float* __restrict__ xin, const float* __restrict__ pm,
    const short8* __restrict__ frS, int lbase,
    const float* __restrict__ gqb, const float* __restrict__ gkb,
    const float* __restrict__ gvb, const float* __restrict__ gob,
    const float* __restrict__ inb, const float* __restrict__ outb,
    const float* __restrict__ ln1g, const float* __restrict__ ln1b,
    float* __restrict__ xb2g, short8* __restrict__ xfG)
{
  __shared__ __align__(16) float xb[16*68];
  __shared__ __align__(16) float q_[16*68];
  __shared__ __align__(16) float k_[16*68];
  __shared__ __align__(16) float v_[16*68];
  __shared__ __align__(16) float ao[16*68];
  __shared__ __align__(16) float ss[1024];
  __shared__ __align__(16) short8 fragA[256];
  __shared__ float pmv[16], mur[16], rvr[16];

  const int bn = blockIdx.x, tid = threadIdx.x;
  const int lane = tid & 63, wvi = tid >> 6;
  const int nidx = lane & 15, quad = lane >> 4;
  const float* xin_p = xin + bn*1024;

  for (int o = tid; o < 1024; o += 256) xb[(o>>6)*68 + (o&63)] = xin_p[o];
  if (tid < 16) pmv[tid] = pm[bn*16 + tid];
  __syncthreads();

  // ---- gattn QKV ----
  packA68(xb, fragA, tid);
  __syncthreads();
  {
    short8 axh0 = fragA[lane], axh1 = fragA[64+lane];
    short8 axl0 = fragA[128+lane], axl1 = fragA[192+lane];
    #pragma unroll
    for (int mat = 0; mat < 3; ++mat){
      int base = lbase + mat*512;
      short8 bh0 = frS[base + (wvi*2+0)*64 + lane];
      short8 bl0 = frS[FRAG_TOT + base + (wvi*2+0)*64 + lane];
      short8 bh1 = frS[base + (wvi*2+1)*64 + lane];
      short8 bl1 = frS[FRAG_TOT + base + (wvi*2+1)*64 + lane];
      floatx4 c = {0.f,0.f,0.f,0.f};
      c = mm3(axh0, axl0, bh0, bl0, c);
      c = mm3(axh1, axl1, bh1, bl1, c);
      int d = wvi*16 + nidx;
      float bb = (mat == 0 ? gqb : mat == 1 ? gkb : gvb)[d];
      float* dst = (mat == 0 ? q_ : mat == 1 ? k_ : v_);
      #pragma unroll
      for (int r = 0; r < 4; ++r) dst[(quad*4+r)*68 + d] = c[r] + bb;
    }
  }
  __syncthreads();
  // scores + tbias + mask
  for (int o = tid; o < 1024; o += 256){
    int h = o >> 8, r = o & 255, qm = r >> 4, km = r & 15;
    float acc = dot16(q_ + qm*68 + h*16, k_ + km*68 + h*16);
    float dist = 5.0f * fabsf((float)(qm - km));
    float tbv = logf(expf(-dist) + 1e-12f);
    acc = acc * 0.25f + tbv;
    if (pmv[km] == 0.f) acc = -1e9f;
    ss[o] = acc;
  }
  __syncthreads();
  if (tid < 64){
    float* row = ss + tid*16;
    float mx = -1e30f;
    #pragma unroll
    for (int j = 0; j < 16; ++j) mx = fmaxf(mx, row[j]);
    float se = 0.f;
    #pragma unroll
    for (int j = 0; j < 16; ++j){ float e = __expf(row[j]-mx); row[j] = e; se += e; }
    float inv = 1.f/se;
    #pragma unroll
    for (int j = 0; j < 16; ++j) row[j] *= inv;
  }
  __syncthreads();
  for (int o = tid; o < 1024; o += 256){
    int m = o >> 6, d = o & 63, h = d >> 4;
    float acc = 0.f;
    #pragma unroll
    for (int km = 0; km < 16; ++km) acc += ss[h*256 + m*16 + km] * v_[km*68 + d];
    ao[m*68 + d] = acc;
  }
  __syncthreads();
  // gattn out proj: xb += proj(ao)*pm + pe
  packA68(ao, fragA, tid);
  __syncthreads();
  {
    short8 axh0 = fragA[lane], axh1 = fragA[64+lane];
    short8 axl0 = fragA[128+lane], axl1 = fragA[192+lane];
    int base = lbase + 1536;   // gow
    short8 bh0 = frS[base + (wvi*2+0)*64 + lane];
    short8 bl0 = frS[FRAG_TOT + base + (wvi*2+0)*64 + lane];
    short8 bh1 = frS[base + (wvi*2+1)*64 + lane];
    short8 bl1 = frS[FRAG_TOT + base + (wvi*2+1)*64 + lane];
    floatx4 c = {0.f,0.f,0.f,0.f};
    c = mm3(axh0, axl0, bh0, bl0, c);
    c = mm3(axh1, axl1, bh1, bl1, c);
    int d = wvi*16 + nidx;
    float bb = gob[d];
    float div = __expf((float)(d & ~1) * (-0.14391156831212793f)); // -ln(1e4)/64
    #pragma unroll
    for (int r = 0; r < 4; ++r){
      int tok = quad*4 + r;
      float arg = (float)tok * div;
      float pev = (d & 1) ? cosf(arg) : sinf(arg);
      xb[tok*68 + d] += (c[r] + bb) * pmv[tok] + pev;
    }
  }
  __syncthreads();

  // ---- MHA ----
  packA68(xb, fragA, tid);
  __syncthreads();
  {
    short8 axh0 = fragA[lane], axh1 = fragA[64+lane];
    short8 axl0 = fragA[128+lane], axl1 = fragA[192+lane];
    #pragma unroll
    for (int sel = 0; sel < 3; ++sel){
      int nt = sel*4 + wvi;
      int base = lbase + OFF_INW + nt*128;
      short8 bh0 = frS[base + lane];
      short8 bl0 = frS[FRAG_TOT + base + lane];
      short8 bh1 = frS[base + 64 + lane];
      short8 bl1 = frS[FRAG_TOT + base + 64 + lane];
      floatx4 c = {0.f,0.f,0.f,0.f};
      c = mm3(axh0, axl0, bh0, bl0, c);
      c = mm3(axh1, axl1, bh1, bl1, c);
      int d = wvi*16 + nidx;
      float bb = inb[nt*16 + nidx];
      float* dst = (sel == 0 ? q_ : sel == 1 ? k_ : v_);
      #pragma unroll
      for (int r = 0; r < 4; ++r) dst[(quad*4+r)*68 + d] = c[r] + bb;
    }
  }
  __syncthreads();
  for (int o = tid; o < 1024; o += 256){
    int h = o >> 8, r = o & 255, qm = r >> 4, km = r & 15;
    ss[o] = 0.25f * dot16(q_ + qm*68 + h*16, k_ + km*68 + h*16);
  }
  __syncthreads();
  if (tid < 64){
    float* row = ss + tid*16;
    float mx = -1e30f;
    #pragma unroll
    for (int j = 0; j < 16; ++j) mx = fmaxf(mx, row[j]);
    float se = 0.f;
    #pragma unroll
    for (int j = 0; j < 16; ++j){ float e = __expf(row[j]-mx); row[j] = e; se += e; }
    float inv = 1.f/se;
    #pragma unroll
    for (int j = 0; j < 16; ++j) row[j] *= inv;
  }
  __syncthreads();
  for (int o = tid; o < 1024; o += 256){
    int m = o >> 6, d = o & 63, h = d >> 4;
    float acc = 0.f;
    #pragma unroll
    for (int km = 0; km < 16; ++km) acc += ss[h*256 + m*16 + km] * v_[km*68 + d];
    ao[m*68 + d] = acc;
  }
  __syncthreads();
  packA68(ao, fragA, tid);
  __syncthreads();
  {
    short8 axh0 = fragA[lane], axh1 = fragA[64+lane];
    short8 axl0 = fragA[128+lane], axl1 = fragA[192+lane];
    int base = lbase + OFF_OUTW;
    short8 bh0 = frS[base + (wvi*2+0)*64 + lane];
    short8 bl0 = frS[FRAG_TOT + base + (wvi*2+0)*64 + lane];
    short8 bh1 = frS[base + (wvi*2+1)*64 + lane];
    short8 bl1 = frS[FRAG_TOT + base + (wvi*2+1)*64 + lane];
    floatx4 c = {0.f,0.f,0.f,0.f};
    c = mm3(axh0, axl0, bh0, bl0, c);
    c = mm3(axh1, axl1, bh1, bl1, c);
    int d = wvi*16 + nidx;
    float bb = outb[d];
    #pragma unroll
    for (int r = 0; r < 4; ++r) xb[(quad*4+r)*68 + d] += c[r] + bb;
  }
  __syncthreads();

  // ---- LN1 ----
  if (tid < 16){
    const float* row = xb + tid*68;
    float mu = 0.f;
    #pragma unroll
    for (int d = 0; d < 64; ++d) mu += row[d];
    mu *= (1.f/64.f);
    float var = 0.f;
    #pragma unroll
    for (int d = 0; d < 64; ++d){ float t = row[d]-mu; var += t*t; }
    var *= (1.f/64.f);
    mur[tid] = mu; rvr[tid] = rsqrtf(var + 1e-5f);
  }
  __syncthreads();
  for (int o = tid; o < 1024; o += 256){
    int m = o >> 6, d = o & 63;
    xb[m*68 + d] = (xb[m*68 + d] - mur[m]) * rvr[m] * ln1g[d] + ln1b[d];
  }
  __syncthreads();
  // write xb2 + its A-frags
  for (int o = tid; o < 1024; o += 256) xb2g[bn*1024 + o] = xb[(o>>6)*68 + (o&63)];
  if (tid < 128){
    int ln = tid & 63, ks = tid >> 6;
    const float* r = xb + (ln & 15)*68 + ks*32 + ((ln >> 4) & 3)*8;
    short8 hi, lo; split8(r, hi, lo);
    xfG[bn*128 + tid] = hi; xfG[XF_LO + bn*128 + tid] = lo;
  }
}

// -------------------------------------------------------------------------
// FF half of a layer: xout = ln2(xb2 + ff(xb2)) (+xin). One block per bn.
// Per wave: 512 hidden j's, 16 iters of fw1-MFMA -> wave-private LDS
// transpose -> fw2-MFMA accumulate. One block barrier before reduce+LN2.
// -------------------------------------------------------------------------
__global__ __launch_bounds__(256) void ffln_kernel(
    const float* __restrict__ xb2g, const short8* __restrict__ xfS,
    const short8* __restrict__ frS, int lbase,
    const float* __restrict__ fb1, const float* __restrict__ fb2,
    const float* __restrict__ ln2g, const float* __restrict__ ln2b,
    const float* __restrict__ xin_res, float* __restrict__ xout, int add_residual)
{
  __shared__ __align__(16) float hbuf[4*16*36];   // per-wave hidden kstep tile
  __shared__ __align__(16) float part[4*16*68];   // per-wave partial y
  __shared__ __align__(16) float xb3[16*68];
  __shared__ float mur[16], rvr[16];

  const int bn = blockIdx.x, tid = threadIdx.x;
  const int lane = tid & 63, w = tid >> 6;
  const int nidx = lane & 15, quad = lane >> 4;
  const int f1base = lbase + OFF_FW1, f2base = lbase + OFF_FW2;

  short8 axh0 = xfS[bn*128 + lane],          axh1 = xfS[bn*128 + 64 + lane];
  short8 axl0 = xfS[XF_LO + bn*128 + lane],  axl1 = xfS[XF_LO + bn*128 + 64 + lane];

  floatx4 y0 = {0.f,0.f,0.f,0.f}, y1 = y0, y2 = y0, y3 = y0;
  float* hw = hbuf + w*576;

  // prefetch fw1 frags for it=0
  short8 f1c[8], f1n[8];
  {
    int ntA = w*32;
    #pragma unroll
    for (int t2 = 0; t2 < 2; ++t2){
      int sb = f1base + ((ntA+t2)*2)*64 + lane;
      f1c[t2*4+0] = frS[sb];            f1c[t2*4+1] = frS[FRAG_TOT + sb];
      f1c[t2*4+2] = frS[sb + 64];       f1c[t2*4+3] = frS[FRAG_TOT + sb + 64];
    }
  }
  for (int it = 0; it < 16; ++it){
    int ntA = w*32 + it*2;
    // stage1: hidden tiles ntA, ntA+1
    floatx4 hA = {0.f,0.f,0.f,0.f}, hB = hA;
    hA = mm3(axh0, axl0, f1c[0], f1c[1], hA);
    hA = mm3(axh1, axl1, f1c[2], f1c[3], hA);
    hB = mm3(axh0, axl0, f1c[4], f1c[5], hB);
    hB = mm3(axh1, axl1, f1c[6], f1c[7], hB);
    float bbA = fb1[ntA*16 + nidx], bbB = fb1[ntA*16 + 16 + nidx];
    #pragma unroll
    for (int r = 0; r < 4; ++r){
      hw[(quad*4+r)*36 + nidx]      = fmaxf(hA[r] + bbA, 0.f);
      hw[(quad*4+r)*36 + 16 + nidx] = fmaxf(hB[r] + bbB, 0.f);
    }
    // issue fw2 loads for this kstep
    int kst = w*16 + it;
    short8 f2[8];
    #pragma unroll
    for (int ntd = 0; ntd < 4; ++ntd){
      int sb = f2base + (ntd*64 + kst)*64 + lane;
      f2[ntd*2]   = frS[sb];
      f2[ntd*2+1] = frS[FRAG_TOT + sb];
    }
    // prefetch next iter's fw1
    if (it < 15){
      int ntN = ntA + 2;
      #pragma unroll
      for (int t2 = 0; t2 < 2; ++t2){
        int sb = f1base + ((ntN+t2)*2)*64 + lane;
        f1n[t2*4+0] = frS[sb];            f1n[t2*4+1] = frS[FRAG_TOT + sb];
        f1n[t2*4+2] = frS[sb + 64];       f1n[t2*4+3] = frS[FRAG_TOT + sb + 64];
      }
    }
    // wave-private transpose: read hidden as A-frag (lane=token, k=j)
    short8 ah, al;
    split8(hw + (lane & 15)*36 + quad*8, ah, al);
    // stage2: accumulate y over this kstep
    y0 = mm3(ah, al, f2[0], f2[1], y0);
    y1 = mm3(ah, al, f2[2], f2[3], y1);
    y2 = mm3(ah, al, f2[4], f2[5], y2);
    y3 = mm3(ah, al, f2[6], f2[7], y3);
    #pragma unroll
    for (int j = 0; j < 8; ++j){
      f1c[j] = f1n[j];
    }
  }
  // write partials
  #pragma unroll
  for (int r = 0; r < 4; ++r){
    int row = (quad*4 + r)*68;
    part[w*1088 + row + nidx]      = y0[r];
    part[w*1088 + row + 16 + nidx] = y1[r];
    part[w*1088 + row + 32 + nidx] = y2[r];
    part[w*1088 + row + 48 + nidx] = y3[r];
  }
  __syncthreads();
  // combine + residual
  for (int o = tid; o < 1024; o += 256){
    int tok = o >> 6, d = o & 63;
    float s = xb2g[bn*1024 + o] + fb2[d];
    #pragma unroll
    for (int ww = 0; ww < 4; ++ww) s += part[ww*1088 + tok*68 + d];
    xb3[tok*68 + d] = s;
  }
  __syncthreads();
  if (tid < 16){
    const float* row = xb3 + tid*68;
    float mu = 0.f;
    #pragma unroll
    for (int d = 0; d < 64; ++d) mu += row[d];
    mu *= (1.f/64.f);
    float var = 0.f;
    #pragma unroll
    for (int d = 0; d < 64; ++d){ float t = row[d]-mu; var += t*t; }
    var *= (1.f/64.f);
    mur[tid] = mu; rvr[tid] = rsqrtf(var + 1e-5f);
  }
  __syncthreads();
  for (int o = tid; o < 1024; o += 256){
    int tok = o >> 6, d = o & 63;
    float vv = (xb3[tok*68 + d] - mur[tok]) * rvr[tok] * ln2g[d] + ln2b[d];
    xout[bn*1024 + o] = vv + (add_residual ? xin_res[bn*1024 + o] : 0.f);
  }
}

// -------------------------------------------------------------------------
// Classifier head. One block per b. (small; fp32)
// -------------------------------------------------------------------------
__global__ __launch_bounds__(256) void final_kernel(
    const float* __restrict__ xc, const float* __restrict__ pm,
    const float* __restrict__ q_embed,
    const float* __restrict__ cin_w, const float* __restrict__ cin_b,
    const float* __restrict__ cout_w, const float* __restrict__ cout_b,
    const float* __restrict__ logit_w, const float* __restrict__ logit_b,
    float* __restrict__ out)
{
  const int b = blockIdx.x;
  const int tid = threadIdx.x;
  __shared__ __align__(16) float xs[M_ * D_];
  __shared__ float kpmv[M_];
  __shared__ __align__(16) float qv[5 * D_], kv[M_ * D_], vv[M_ * D_];
  __shared__ float sv[H_ * 5 * M_];
  __shared__ __align__(16) float ao[5 * D_], zv[5 * D_];

  for (int o = tid; o < M_ * D_; o += 256) {
    int m = o >> 6, d = o & 63;
    float acc = 0.f;
    #pragma unroll
    for (int n = 0; n < N_; ++n) acc += xc[(((b * N_ + n) * M_ + m) * D_) + d];
    xs[o] = acc * (1.f / 32.f);
  }
  if (tid < M_) {
    float any = 0.f;
    #pragma unroll
    for (int n = 0; n < N_; ++n) any += (pm[(b * N_ + n) * M_ + tid] > 0.f) ? 1.f : 0.f;
    kpmv[tid] = (any > 0.f) ? 0.f : 1.f;
  }
  __syncthreads();

  for (int o = tid; o < 5 * D_; o += 256) {
    int qi = o >> 6, d = o & 63;
    qv[o] = cin_b[d] + dot64(q_embed + qi * D_, cin_w + d * D_);
  }
  for (int o = tid; o < 2 * M_ * D_; o += 256) {
    int sel = o >> 10, r = o & 1023, m = r >> 6, d = r & 63;
    float acc = cin_b[D_ + sel * D_ + d] + dot64(xs + m * D_, cin_w + (D_ + sel * D_ + d) * D_);
    ((sel == 0) ? kv : vv)[r] = acc;
  }
  __syncthreads();

  for (int o = tid; o < H_ * 5 * M_; o += 256) {
    int h = o / 80, r = o % 80, qi = r >> 4, km = r & 15;
    float acc = 0.25f * dot16(qv + qi * D_ + h * DH_, kv + km * D_ + h * DH_);
    if (kpmv[km] != 0.f) acc = -1e9f;
    sv[o] = acc;
  }
  __syncthreads();
  if (tid < H_ * 5) {
    int h = tid / 5, qi = tid % 5;
    float* row = sv + h * 80 + qi * M_;
    float mx = -1e30f;
    #pragma unroll
    for (int km = 0; km < M_; ++km) mx = fmaxf(mx, row[km]);
    float se = 0.f;
    #pragma unroll
    for (int km = 0; km < M_; ++km) { float e = __expf(row[km] - mx); row[km] = e; se += e; }
    float inv = 1.f / se;
    #pragma unroll
    for (int km = 0; km < M_; ++km) row[km] *= inv;
  }
  __syncthreads();
  for (int o = tid; o < 5 * D_; o += 256) {
    int qi = o >> 6, d = o & 63, h = d >> 4;
    float acc = 0.f;
    #pragma unroll
    for (int km = 0; km < M_; ++km) acc += sv[h * 80 + qi * M_ + km] * vv[km * D_ + d];
    ao[o] = acc;
  }
  __syncthreads();
  for (int o = tid; o < 5 * D_; o += 256) {
    int qi = o >> 6, d = o & 63;
    zv[o] = cout_b[d] + dot64(ao + qi * D_, cout_w + d * D_);
  }
  __syncthreads();
  if (tid < 5) {
    float acc = logit_b[0] + dot64(zv + tid * D_, logit_w);
    out[b * 5 + tid] = acc;
  }
}

// -------------------------------------------------------------------------
extern "C" void kernel_launch(void* const* d_in, const int* in_sizes, int n_in,
                              void* d_out, int out_size, void* d_ws, size_t ws_size,
                              hipStream_t stream) {
  const float* x       = (const float*)d_in[0];
  const int*   mask    = (const int*)  d_in[1];
  const float* ttcn_w1 = (const float*)d_in[2];
  const float* ttcn_b1 = (const float*)d_in[3];
  const float* ttcn_w2 = (const float*)d_in[4];
  const float* ttcn_b2 = (const float*)d_in[5];
  const float* ttcn_w3 = (const float*)d_in[6];
  const float* ttcn_b3 = (const float*)d_in[7];
  const float* t_bias  = (const float*)d_in[8];
  const float* ga_qw   = (const float*)d_in[9];
  const float* ga_qb   = (const float*)d_in[10];
  const float* ga_kw   = (const float*)d_in[11];
  const float* ga_kb   = (const float*)d_in[12];
  const float* ga_vw   = (const float*)d_in[13];
  const float* ga_vb   = (const float*)d_in[14];
  const float* ga_ow   = (const float*)d_in[15];
  const float* ga_ob   = (const float*)d_in[16];
  const float* tf_in_w = (const float*)d_in[17];
  const float* tf_in_b = (const float*)d_in[18];
  const float* tf_out_w= (const float*)d_in[19];
  const float* tf_out_b= (const float*)d_in[20];
  const float* tf_ln1g = (const float*)d_in[21];
  const float* tf_ln1b = (const float*)d_in[22];
  const float* tf_ln2g = (const float*)d_in[23];
  const float* tf_ln2b = (const float*)d_in[24];
  const float* tf_fw1  = (const float*)d_in[25];
  const float* tf_fb1  = (const float*)d_in[26];
  const float* tf_fw2  = (const float*)d_in[27];
  const float* tf_fb2  = (const float*)d_in[28];
  const float* q_embed = (const float*)d_in[29];
  const float* cls_in_w  = (const float*)d_in[30];
  const float* cls_in_b  = (const float*)d_in[31];
  const float* cls_out_w = (const float*)d_in[32];
  const float* cls_out_b = (const float*)d_in[33];
  const float* logit_w = (const float*)d_in[34];
  const float* logit_b = (const float*)d_in[35];

  float* wsf  = (float*)d_ws;
  float* xp   = wsf;                        // 262144 f
  float* pmb  = wsf + P_TOT * D_;           // 4096 f
  float* xa   = pmb + P_TOT;                // 262144 f
  float* xbuf = xa  + P_TOT * D_;           // 262144 f
  float* xb2  = xbuf + P_TOT * D_;          // 262144 f
  short8* xf  = (short8*)(xb2 + BN_*1024);  // 65536 short8 = 1 MB
  uint4*  fr  = (uint4*)((char*)xf + 65536*16);   // 2*FRAG_TOT uint4
  const short8* frS = (const short8*)fr;

  prep_kernel<<<325, 256, 0, stream>>>(ttcn_w1, ttcn_w2, ttcn_w3,
      ga_qw, ga_kw, ga_vw, ga_ow, tf_in_w, tf_out_w, tf_fw1, tf_fw2, fr);

  ttcn_kernel<<<P_TOT, 256, 0, stream>>>(x, mask, ttcn_b1, ttcn_b2, ttcn_b3, t_bias,
      frS + 0,   frS + FRAG_TOT,
      frS + 256, frS + FRAG_TOT + 256,
      frS + 768, frS + FRAG_TOT + 768,
      xp, pmb);

  // layer 0
  attn_kernel<<<BN_, 256, 0, stream>>>(xp, pmb, frS, LBASE(0),
      ga_qb, ga_kb, ga_vb, ga_ob, tf_in_b, tf_out_b, tf_ln1g, tf_ln1b,
      xb2, xf);
  ffln_kernel<<<BN_, 256, 0, stream>>>(xb2, xf, frS, LBASE(0),
      tf_fb1, tf_fb2, tf_ln2g, tf_ln2b, xp, xa, 0);

  // layer 1 (with layer residual)
  attn_kernel<<<BN_, 256, 0, stream>>>(xa, pmb, frS, LBASE(1),
      ga_qb + 64, ga_kb + 64, ga_vb + 64, ga_ob + 64,
      tf_in_b + 192, tf_out_b + 64, tf_ln1g + 64, tf_ln1b + 64,
      xb2, xf);
  ffln_kernel<<<BN_, 256, 0, stream>>>(xb2, xf, frS, LBASE(1),
      tf_fb1 + FF_, tf_fb2 + 64, tf_ln2g + 64, tf_ln2b + 64, xa, xbuf, 1);

  final_kernel<<<B_, 256, 0, stream>>>(xbuf, pmb, q_embed,
                                       cls_in_w, cls_in_b, cls_out_w, cls_out_b,
                                       logit_w, logit_b, (float*)d_out);
}

// Round 4
// 283.583 us; speedup vs baseline: 5.7951x; 1.1155x over previous
//
#include <hip/hip_runtime.h>
#include <hip/hip_bf16.h>
#include <math.h>

// Problem constants
#define B_  8
#define N_  32
#define M_  16
#define LX  32
#define D_  64
#define IN_DIM_ 17
#define TT_ 63
#define H_  4
#define DH_ 16
#define P_TOT 4096          // B*N*M
#define BN_ 256             // B*N
#define FF_ 2048

// Fragment pool layout (slot = one short8/uint4 per lane-group entry)
#define FRAG_TOT 83200
#define LBASE(l) (9472 + (l)*36864)
#define OFF_INW  2048
#define OFF_OUTW 3584
#define OFF_FW1  4096
#define OFF_FW2  20480

typedef unsigned short ushort_t;
typedef __attribute__((ext_vector_type(8))) short short8;   // 8 bf16 (4 VGPRs)
typedef __attribute__((ext_vector_type(4))) float floatx4;  // MFMA C/D

#define MFMA16(a,b,c) __builtin_amdgcn_mfma_f32_16x16x32_bf16((a),(b),(c),0,0,0)

__device__ __forceinline__ ushort_t f2bf(float f){          // RNE float->bf16
  unsigned u = __float_as_uint(f);
  u += 0x7FFFu + ((u >> 16) & 1u);
  return (ushort_t)(u >> 16);
}
__device__ __forceinline__ float bf2f(ushort_t h){ return __uint_as_float(((unsigned)h) << 16); }

__device__ __forceinline__ uint4 pack8(const ushort_t* h){
  uint4 u;
  u.x = (unsigned)h[0] | ((unsigned)h[1] << 16);
  u.y = (unsigned)h[2] | ((unsigned)h[3] << 16);
  u.z = (unsigned)h[4] | ((unsigned)h[5] << 16);
  u.w = (unsigned)h[6] | ((unsigned)h[7] << 16);
  return u;
}

// split 8 consecutive floats into hi/lo bf16 short8
__device__ __forceinline__ void split8(const float* r, short8& hi, short8& lo){
  #pragma unroll
  for (int j = 0; j < 8; ++j){
    float v = r[j];
    ushort_t h = f2bf(v);
    ushort_t l2 = f2bf(v - bf2f(h));
    hi[j] = (short)h; lo[j] = (short)l2;
  }
}
// hi-only conversion
__device__ __forceinline__ uint4 cvt8(const float* r){
  ushort_t hh[8];
  #pragma unroll
  for (int j = 0; j < 8; ++j) hh[j] = f2bf(r[j]);
  return pack8(hh);
}

// 3-term split product: (ah+al)(bh+bl) ~= ah*bh + ah*bl + al*bh
__device__ __forceinline__ floatx4 mm3(short8 ah, short8 al, short8 bh, short8 bl, floatx4 c){
  c = MFMA16(ah, bh, c); c = MFMA16(ah, bl, c); c = MFMA16(al, bh, c); return c;
}

__device__ __forceinline__ float dot64(const float* __restrict__ a, const float* __restrict__ w){
  const float4* a4 = (const float4*)a;
  const float4* w4 = (const float4*)w;
  float acc = 0.f;
  #pragma unroll
  for (int k = 0; k < 16; ++k){ float4 x = a4[k], y = w4[k];
    acc += x.x*y.x + x.y*y.y + x.z*y.z + x.w*y.w; }
  return acc;
}
__device__ __forceinline__ float dot16(const float* __restrict__ a, const float* __restrict__ b){
  const float4* a4 = (const float4*)a; const float4* b4 = (const float4*)b;
  float acc = 0.f;
  #pragma unroll
  for (int k = 0; k < 4; ++k){ float4 x = a4[k], y = b4[k];
    acc += x.x*y.x + x.y*y.y + x.z*y.z + x.w*y.w; }
  return acc;
}

// pack A-frags (16 tokens x 64 k) from stride-68 LDS buffer into fragA (hi[128], lo[128])
__device__ __forceinline__ void packA68(const float* buf, short8* fA, int tid){
  if (tid < 128){
    int ln = tid & 63, ks = tid >> 6;
    const float* r = buf + (ln & 15)*68 + ks*32 + ((ln >> 4) & 3)*8;
    short8 hi, lo; split8(r, hi, lo);
    fA[tid] = hi; fA[128 + tid] = lo;
  }
}

// -------------------------------------------------------------------------
// Prep: convert ALL weight matrices to MFMA B-fragment pool (hi at [s], lo at
// [FRAG_TOT+s]). B[k][n]: n = nt*16 + (lane&15), k = ks*32 + quad*8 + j.
// -------------------------------------------------------------------------
__global__ __launch_bounds__(256) void prep_kernel(
    const float* __restrict__ w1, const float* __restrict__ w2, const float* __restrict__ w3,
    const float* __restrict__ gqw, const float* __restrict__ gkw,
    const float* __restrict__ gvw, const float* __restrict__ gow,
    const float* __restrict__ inw, const float* __restrict__ outw,
    const float* __restrict__ fw1, const float* __restrict__ fw2,
    uint4* __restrict__ fr)
{
  int s = blockIdx.x*256 + threadIdx.x;
  if (s >= FRAG_TOT) return;
  const float* src; int Nr, Kr, KS, rel;
  if (s < 256)      { src = w1; Nr=63;  Kr=17; KS=1; rel = s; }
  else if (s < 768) { src = w2; Nr=63;  Kr=63; KS=2; rel = s-256; }
  else if (s < 9472){ src = w3; Nr=1071;Kr=63; KS=2; rel = s-768; }
  else {
    int t = s - 9472, l = t / 36864, r2 = t - l*36864;
    if (r2 < 512)        { src = gqw + l*4096;   Nr=64;  Kr=64;   KS=2;  rel = r2; }
    else if (r2 < 1024)  { src = gkw + l*4096;   Nr=64;  Kr=64;   KS=2;  rel = r2-512; }
    else if (r2 < 1536)  { src = gvw + l*4096;   Nr=64;  Kr=64;   KS=2;  rel = r2-1024; }
    else if (r2 < 2048)  { src = gow + l*4096;   Nr=64;  Kr=64;   KS=2;  rel = r2-1536; }
    else if (r2 < 3584)  { src = inw + l*12288;  Nr=192; Kr=64;   KS=2;  rel = r2-2048; }
    else if (r2 < 4096)  { src = outw + l*4096;  Nr=64;  Kr=64;   KS=2;  rel = r2-3584; }
    else if (r2 < 20480) { src = fw1 + l*131072; Nr=2048;Kr=64;   KS=2;  rel = r2-4096; }
    else                 { src = fw2 + l*131072; Nr=64;  Kr=2048; KS=64; rel = r2-20480; }
  }
  int lane = rel & 63, tmp = rel >> 6;
  int ks = tmp % KS, nt = tmp / KS;
  int n = nt*16 + (lane & 15), kb = ks*32 + ((lane >> 4) & 3)*8;
  float v[8];
  #pragma unroll
  for (int j = 0; j < 8; ++j) v[j] = (n < Nr && (kb + j) < Kr) ? src[n*Kr + kb + j] : 0.f;
  ushort_t hh[8], ll[8];
  #pragma unroll
  for (int j = 0; j < 8; ++j){ hh[j] = f2bf(v[j]); ll[j] = f2bf(v[j] - bf2f(hh[j])); }
  fr[s] = pack8(hh); fr[FRAG_TOT + s] = pack8(ll);
}

// -------------------------------------------------------------------------
// Fused TTCN — pure bf16 1-term MFMA (threshold is bf16-grade; softmax+LN
// downstream smooth the rounding). One block per patch; LDS 29.8 KB.
// -------------------------------------------------------------------------
__global__ __launch_bounds__(256) void ttcn_kernel(
    const float* __restrict__ x, const int* __restrict__ mask,
    const float* __restrict__ b1, const float* __restrict__ b2,
    const float* __restrict__ b3, const float* __restrict__ tb,
    const short8* __restrict__ w1bhi,
    const short8* __restrict__ w2bhi,
    const short8* __restrict__ w3bhi,
    float* __restrict__ xp, float* __restrict__ pm)
{
  __shared__ __align__(16) char pool[29824];
  float*  xs    = (float*)(pool + 0);        // 544 f, x row-major [l][i]
  float*  msv   = (float*)(pool + 2176);     // 32 f
  float*  b3s   = (float*)(pool + 2304);     // 1072 f
  float*  h1t   = (float*)(pool + 6592);     // [k][l] stride 33 (dead after P3)
  short8* h2fhi = (short8*)(pool + 6592);    // alias h1t (written P5)
  float*  h2t   = (float*)(pool + 15040);    // [k][l] stride 33
  short8* xfhi  = (short8*)(pool + 23488);   // 128 slots
  short8* h1fhi = (short8*)(pool + 25536);   // 256 slots (dead after P4)
  float*  colres= (float*)(pool + 25536);    // alias h1fhi (written P6)

  const int p = blockIdx.x, tid = threadIdx.x;
  const int lane = tid & 63, wvi = tid >> 6;
  const int nidx = lane & 15, quad = lane >> 4;

  // P0: stage x, mask, b3
  for (int i = tid; i < LX*IN_DIM_; i += 256) xs[i] = x[p*(LX*IN_DIM_) + i];
  if (tid < LX) msv[tid] = (float)mask[p*LX + tid];
  for (int i = tid; i < 1071; i += 256) b3s[i] = b3[i];
  __syncthreads();

  // P1: x A-fragments (hi only), K=32 (k>=17 zero-padded)
  if (tid < 128){
    int mt = tid >> 6;
    int l = mt*16 + nidx;
    float r[8];
    #pragma unroll
    for (int j = 0; j < 8; ++j){
      int k = quad*8 + j;
      r[j] = (k < IN_DIM_) ? xs[l*IN_DIM_ + k] : 0.f;
    }
    ((uint4*)xfhi)[tid] = cvt8(r);
  }
  __syncthreads();

  // P2: GEMM1  h1 = relu(x @ w1^T + b1)
  {
    short8 axh0 = xfhi[lane], axh1 = xfhi[64 + lane];
    short8 bh = w1bhi[wvi*64 + lane];
    floatx4 a0 = {0.f,0.f,0.f,0.f}, a1 = {0.f,0.f,0.f,0.f};
    a0 = MFMA16(axh0, bh, a0);
    a1 = MFMA16(axh1, bh, a1);
    int t = wvi*16 + nidx;
    float bb = (t < TT_) ? b1[t] : 0.f;
    #pragma unroll
    for (int r = 0; r < 4; ++r){
      h1t[t*33 + quad*4 + r]      = fmaxf(a0[r] + bb, 0.f);
      h1t[t*33 + 16 + quad*4 + r] = fmaxf(a1[r] + bb, 0.f);
    }
  }
  __syncthreads();

  // P3: h1 A-fragments (hi only). slot = (mt*2+ks)*64+lane = tid
  {
    int mt = tid >> 7, ks = (tid >> 6) & 1;
    int l = mt*16 + nidx;
    float r[8];
    #pragma unroll
    for (int j = 0; j < 8; ++j) r[j] = h1t[(ks*32 + quad*8 + j)*33 + l];
    ((uint4*)h1fhi)[tid] = cvt8(r);
  }
  __syncthreads();

  // P4: GEMM2  h2 = relu(h1 @ w2^T + b2)
  {
    short8 ah00 = h1fhi[lane],       ah01 = h1fhi[64 + lane];
    short8 ah10 = h1fhi[128 + lane], ah11 = h1fhi[192 + lane];
    short8 bh0 = w2bhi[(wvi*2+0)*64 + lane];
    short8 bh1 = w2bhi[(wvi*2+1)*64 + lane];
    floatx4 a0 = {0.f,0.f,0.f,0.f}, a1 = {0.f,0.f,0.f,0.f};
    a0 = MFMA16(ah00, bh0, a0); a0 = MFMA16(ah01, bh1, a0);
    a1 = MFMA16(ah10, bh0, a1); a1 = MFMA16(ah11, bh1, a1);
    int t = wvi*16 + nidx;
    float bb = (t < TT_) ? b2[t] : 0.f;
    #pragma unroll
    for (int r = 0; r < 4; ++r){
      h2t[t*33 + quad*4 + r]      = fmaxf(a0[r] + bb, 0.f);
      h2t[t*33 + 16 + quad*4 + r] = fmaxf(a1[r] + bb, 0.f);
    }
  }
  __syncthreads();

  // P5: h2 A-fragments (hi only), into region aliasing dead h1t
  {
    int mt = tid >> 7, ks = (tid >> 6) & 1;
    int l = mt*16 + nidx;
    float r[8];
    #pragma unroll
    for (int j = 0; j < 8; ++j) r[j] = h2t[(ks*32 + quad*8 + j)*33 + l];
    ((uint4*)h2fhi)[tid] = cvt8(r);
  }
  __syncthreads();

  // P6: GEMM3  filt = h2 @ w3^T + b3, masked softmax over l, contract with x
  {
    short8 ah00 = h2fhi[lane],       ah01 = h2fhi[64 + lane];
    short8 ah10 = h2fhi[128 + lane], ah11 = h2fhi[192 + lane];
    short8 nbh0 = w3bhi[(wvi*2+0)*64 + lane];
    short8 nbh1 = w3bhi[(wvi*2+1)*64 + lane];
    for (int it = 0; it < 17; ++it){
      int tile = wvi + it*4;                 // waves cover tiles 0..67
      short8 bh0 = nbh0, bh1 = nbh1;
      if (it < 16){
        int nt = tile + 4;
        nbh0 = w3bhi[(nt*2+0)*64 + lane];
        nbh1 = w3bhi[(nt*2+1)*64 + lane];
      }
      floatx4 a0 = {0.f,0.f,0.f,0.f}, a1 = {0.f,0.f,0.f,0.f};
      a0 = MFMA16(ah00, bh0, a0); a0 = MFMA16(ah01, bh1, a0);
      a1 = MFMA16(ah10, bh0, a1); a1 = MFMA16(ah11, bh1, a1);

      int c = tile*16 + nidx;
      bool valid = c < 1071;
      int t = (c * 3856) >> 16;              // c/17 (exact for c<1088)
      int ii = c - t*17;
      float bb = valid ? b3s[c] : 0.f;
      float f[8];
      #pragma unroll
      for (int r = 0; r < 4; ++r){
        int l0 = quad*4 + r;
        f[r]     = (msv[l0]      != 0.f) ? (a0[r] + bb) : -1e8f;
        f[r + 4] = (msv[l0 + 16] != 0.f) ? (a1[r] + bb) : -1e8f;
      }
      float mx = f[0];
      #pragma unroll
      for (int r = 1; r < 8; ++r) mx = fmaxf(mx, f[r]);
      mx = fmaxf(mx, __shfl_xor(mx, 16, 64));
      mx = fmaxf(mx, __shfl_xor(mx, 32, 64));
      float den = 0.f, num = 0.f;
      #pragma unroll
      for (int r = 0; r < 4; ++r){
        int l0 = quad*4 + r;
        float e0 = __expf(f[r] - mx);     den += e0; num += e0 * xs[l0*IN_DIM_ + ii];
        float e1 = __expf(f[r+4] - mx);   den += e1; num += e1 * xs[(l0+16)*IN_DIM_ + ii];
      }
      den += __shfl_xor(den, 16, 64); den += __shfl_xor(den, 32, 64);
      num += __shfl_xor(num, 16, 64); num += __shfl_xor(num, 32, 64);
      if (quad == 0 && valid) colres[c] = num / den;
    }
  }
  __syncthreads();

  // P7: h_t[t] = relu(sum_i colres[t*17+i] + tb[t]); append mask_patch
  if (tid < TT_){
    float acc = 0.f;
    #pragma unroll
    for (int i2 = 0; i2 < IN_DIM_; ++i2) acc += colres[tid*IN_DIM_ + i2];
    xp[p*D_ + tid] = fmaxf(acc + tb[tid], 0.f);
  }
  if (tid == TT_){
    float s = 0.f;
    #pragma unroll
    for (int l = 0; l < LX; ++l) s += msv[l];
    float mp = (s > 0.f) ? 1.f : 0.f;
    xp[p*D_ + TT_] = mp;
    pm[p] = mp;
  }
}

// -------------------------------------------------------------------------
// Full transformer layer (attn + FF merged). One block per bn, 1 block/CU.
// All projections via split-bf16 MFMA (3-term). Post-LN1 state + A-frags
// stay in LDS — no global round-trip between halves.
// -------------------------------------------------------------------------
__global__ __launch_bounds__(256) void layer_kernel(
    const float* __restrict__ xin, const float* __restrict__ pm,
    const short8* __restrict__ frS, int lbase,
    const float* __restrict__ gqb, const float* __restrict__ gkb,
    const float* __restrict__ gvb, const float* __restrict__ gob,
    const float* __restrict__ inb, const float* __restrict__ outb,
    const float* __restrict__ ln1g, const float* __restrict__ ln1b,
    const float* __restrict__ fb1, const float* __restrict__ fb2,
    const float* __restrict__ ln2g, const float* __restrict__ ln2b,
    float* __restrict__ xout, int add_residual)
{
  __shared__ __align__(16) float xb[16*68];
  __shared__ __align__(16) float xb2[16*68];
  __shared__ __align__(16) float q_[16*68];
  __shared__ __align__(16) float k_[16*68];
  __shared__ __align__(16) float v_[16*68];
  __shared__ __align__(16) float ao[16*68];
  __shared__ __align__(16) float ss[1024];
  __shared__ __align__(16) short8 fragA[256];
  __shared__ __align__(16) float hbuf[4*16*36];   // per-wave hidden kstep tile
  __shared__ __align__(16) float part[4*16*68];   // per-wave partial y
  __shared__ float pmv[16], mur[16], rvr[16];

  const int bn = blockIdx.x, tid = threadIdx.x;
  const int lane = tid & 63, wvi = tid >> 6;
  const int nidx = lane & 15, quad = lane >> 4;
  const float* xin_p = xin + bn*1024;

  for (int o = tid; o < 1024; o += 256) xb[(o>>6)*68 + (o&63)] = xin_p[o];
  if (tid < 16) pmv[tid] = pm[bn*16 + tid];
  __syncthreads();

  // ---- gattn QKV ----
  packA68(xb, fragA, tid);
  __syncthreads();
  {
    short8 axh0 = fragA[lane], axh1 = fragA[64+lane];
    short8 axl0 = fragA[128+lane], axl1 = fragA[192+lane];
    #pragma unroll
    for (int mat = 0; mat < 3; ++mat){
      int base = lbase + mat*512;
      short8 bh0 = frS[base + (wvi*2+0)*64 + lane];
      short8 bl0 = frS[FRAG_TOT + base + (wvi*2+0)*64 + lane];
      short8 bh1 = frS[base + (wvi*2+1)*64 + lane];
      short8 bl1 = frS[FRAG_TOT + base + (wvi*2+1)*64 + lane];
      floatx4 c = {0.f,0.f,0.f,0.f};
      c = mm3(axh0, axl0, bh0, bl0, c);
      c = mm3(axh1, axl1, bh1, bl1, c);
      int d = wvi*16 + nidx;
      float bb = (mat == 0 ? gqb : mat == 1 ? gkb : gvb)[d];
      float* dst = (mat == 0 ? q_ : mat == 1 ? k_ : v_);
      #pragma unroll
      for (int r = 0; r < 4; ++r) dst[(quad*4+r)*68 + d] = c[r] + bb;
    }
  }
  __syncthreads();
  // scores + tbias + mask
  for (int o = tid; o < 1024; o += 256){
    int h = o >> 8, r = o & 255, qm = r >> 4, km = r & 15;
    float acc = dot16(q_ + qm*68 + h*16, k_ + km*68 + h*16);
    float dist = 5.0f * fabsf((float)(qm - km));
    float tbv = logf(expf(-dist) + 1e-12f);
    acc = acc * 0.25f + tbv;
    if (pmv[km] == 0.f) acc = -1e9f;
    ss[o] = acc;
  }
  __syncthreads();
  if (tid < 64){
    float* row = ss + tid*16;
    float mx = -1e30f;
    #pragma unroll
    for (int j = 0; j < 16; ++j) mx = fmaxf(mx, row[j]);
    float se = 0.f;
    #pragma unroll
    for (int j = 0; j < 16; ++j){ float e = __expf(row[j]-mx); row[j] = e; se += e; }
    float inv = 1.f/se;
    #pragma unroll
    for (int j = 0; j < 16; ++j) row[j] *= inv;
  }
  __syncthreads();
  for (int o = tid; o < 1024; o += 256){
    int m = o >> 6, d = o & 63, h = d >> 4;
    float acc = 0.f;
    #pragma unroll
    for (int km = 0; km < 16; ++km) acc += ss[h*256 + m*16 + km] * v_[km*68 + d];
    ao[m*68 + d] = acc;
  }
  __syncthreads();
  // gattn out proj: xb += proj(ao)*pm + pe
  packA68(ao, fragA, tid);
  __syncthreads();
  {
    short8 axh0 = fragA[lane], axh1 = fragA[64+lane];
    short8 axl0 = fragA[128+lane], axl1 = fragA[192+lane];
    int base = lbase + 1536;   // gow
    short8 bh0 = frS[base + (wvi*2+0)*64 + lane];
    short8 bl0 = frS[FRAG_TOT + base + (wvi*2+0)*64 + lane];
    short8 bh1 = frS[base + (wvi*2+1)*64 + lane];
    short8 bl1 = frS[FRAG_TOT + base + (wvi*2+1)*64 + lane];
    floatx4 c = {0.f,0.f,0.f,0.f};
    c = mm3(axh0, axl0, bh0, bl0, c);
    c = mm3(axh1, axl1, bh1, bl1, c);
    int d = wvi*16 + nidx;
    float bb = gob[d];
    float div = __expf((float)(d & ~1) * (-0.14391156831212793f)); // -ln(1e4)/64
    #pragma unroll
    for (int r = 0; r < 4; ++r){
      int tok = quad*4 + r;
      float arg = (float)tok * div;
      float pev = (d & 1) ? cosf(arg) : sinf(arg);
      xb[tok*68 + d] += (c[r] + bb) * pmv[tok] + pev;
    }
  }
  __syncthreads();

  // ---- MHA ----
  packA68(xb, fragA, tid);
  __syncthreads();
  {
    short8 axh0 = fragA[lane], axh1 = fragA[64+lane];
    short8 axl0 = fragA[128+lane], axl1 = fragA[192+lane];
    #pragma unroll
    for (int sel = 0; sel < 3; ++sel){
      int nt = sel*4 + wvi;
      int base = lbase + OFF_INW + nt*128;
      short8 bh0 = frS[base + lane];
      short8 bl0 = frS[FRAG_TOT + base + lane];
      short8 bh1 = frS[base + 64 + lane];
      short8 bl1 = frS[FRAG_TOT + base + 64 + lane];
      floatx4 c = {0.f,0.f,0.f,0.f};
      c = mm3(axh0, axl0, bh0, bl0, c);
      c = mm3(axh1, axl1, bh1, bl1, c);
      int d = wvi*16 + nidx;
      float bb = inb[nt*16 + nidx];
      float* dst = (sel == 0 ? q_ : sel == 1 ? k_ : v_);
      #pragma unroll
      for (int r = 0; r < 4; ++r) dst[(quad*4+r)*68 + d] = c[r] + bb;
    }
  }
  __syncthreads();
  for (int o = tid; o < 1024; o += 256){
    int h = o >> 8, r = o & 255, qm = r >> 4, km = r & 15;
    ss[o] = 0.25f * dot16(q_ + qm*68 + h*16, k_ + km*68 + h*16);
  }
  __syncthreads();
  if (tid < 64){
    float* row = ss + tid*16;
    float mx = -1e30f;
    #pragma unroll
    for (int j = 0; j < 16; ++j) mx = fmaxf(mx, row[j]);
    float se = 0.f;
    #pragma unroll
    for (int j = 0; j < 16; ++j){ float e = __expf(row[j]-mx); row[j] = e; se += e; }
    float inv = 1.f/se;
    #pragma unroll
    for (int j = 0; j < 16; ++j) row[j] *= inv;
  }
  __syncthreads();
  for (int o = tid; o < 1024; o += 256){
    int m = o >> 6, d = o & 63, h = d >> 4;
    float acc = 0.f;
    #pragma unroll
    for (int km = 0; km < 16; ++km) acc += ss[h*256 + m*16 + km] * v_[km*68 + d];
    ao[m*68 + d] = acc;
  }
  __syncthreads();
  packA68(ao, fragA, tid);
  __syncthreads();
  {
    short8 axh0 = fragA[lane], axh1 = fragA[64+lane];
    short8 axl0 = fragA[128+lane], axl1 = fragA[192+lane];
    int base = lbase + OFF_OUTW;
    short8 bh0 = frS[base + (wvi*2+0)*64 + lane];
    short8 bl0 = frS[FRAG_TOT + base + (wvi*2+0)*64 + lane];
    short8 bh1 = frS[base + (wvi*2+1)*64 + lane];
    short8 bl1 = frS[FRAG_TOT + base + (wvi*2+1)*64 + lane];
    floatx4 c = {0.f,0.f,0.f,0.f};
    c = mm3(axh0, axl0, bh0, bl0, c);
    c = mm3(axh1, axl1, bh1, bl1, c);
    int d = wvi*16 + nidx;
    float bb = outb[d];
    #pragma unroll
    for (int r = 0; r < 4; ++r) xb[(quad*4+r)*68 + d] += c[r] + bb;
  }
  __syncthreads();

  // ---- LN1 -> xb2 ----
  if (tid < 16){
    const float* row = xb + tid*68;
    float mu = 0.f;
    #pragma unroll
    for (int d = 0; d < 64; ++d) mu += row[d];
    mu *= (1.f/64.f);
    float var = 0.f;
    #pragma unroll
    for (int d = 0; d < 64; ++d){ float t = row[d]-mu; var += t*t; }
    var *= (1.f/64.f);
    mur[tid] = mu; rvr[tid] = rsqrtf(var + 1e-5f);
  }
  __syncthreads();
  for (int o = tid; o < 1024; o += 256){
    int m = o >> 6, d = o & 63;
    xb2[m*68 + d] = (xb[m*68 + d] - mur[m]) * rvr[m] * ln1g[d] + ln1b[d];
  }
  __syncthreads();
  packA68(xb2, fragA, tid);
  __syncthreads();

  // ---- FF (2048 hidden): per wave 512 j's, 16 ksteps ----
  {
    const int w = wvi;
    const int f1base = lbase + OFF_FW1, f2base = lbase + OFF_FW2;
    short8 axh0 = fragA[lane],     axh1 = fragA[64 + lane];
    short8 axl0 = fragA[128+lane], axl1 = fragA[192 + lane];
    floatx4 y0 = {0.f,0.f,0.f,0.f}, y1 = y0, y2 = y0, y3 = y0;
    float* hw = hbuf + w*576;

    short8 f1c[8], f1n[8];
    {
      int ntA = w*32;
      #pragma unroll
      for (int t2 = 0; t2 < 2; ++t2){
        int sb = f1base + ((ntA+t2)*2)*64 + lane;
        f1c[t2*4+0] = frS[sb];            f1c[t2*4+1] = frS[FRAG_TOT + sb];
        f1c[t2*4+2] = frS[sb + 64];       f1c[t2*4+3] = frS[FRAG_TOT + sb + 64];
      }
    }
    for (int it = 0; it < 16; ++it){
      int ntA = w*32 + it*2;
      floatx4 hA = {0.f,0.f,0.f,0.f}, hB = hA;
      hA = mm3(axh0, axl0, f1c[0], f1c[1], hA);
      hA = mm3(axh1, axl1, f1c[2], f1c[3], hA);
      hB = mm3(axh0, axl0, f1c[4], f1c[5], hB);
      hB = mm3(axh1, axl1, f1c[6], f1c[7], hB);
      float bbA = fb1[ntA*16 + nidx], bbB = fb1[ntA*16 + 16 + nidx];
      #pragma unroll
      for (int r = 0; r < 4; ++r){
        hw[(quad*4+r)*36 + nidx]      = fmaxf(hA[r] + bbA, 0.f);
        hw[(quad*4+r)*36 + 16 + nidx] = fmaxf(hB[r] + bbB, 0.f);
      }
      int kst = w*16 + it;
      short8 f2[8];
      #pragma unroll
      for (int ntd = 0; ntd < 4; ++ntd){
        int sb = f2base + (ntd*64 + kst)*64 + lane;
        f2[ntd*2]   = frS[sb];
        f2[ntd*2+1] = frS[FRAG_TOT + sb];
      }
      if (it < 15){
        int ntN = ntA + 2;
        #pragma unroll
        for (int t2 = 0; t2 < 2; ++t2){
          int sb = f1base + ((ntN+t2)*2)*64 + lane;
          f1n[t2*4+0] = frS[sb];            f1n[t2*4+1] = frS[FRAG_TOT + sb];
          f1n[t2*4+2] = frS[sb + 64];       f1n[t2*4+3] = frS[FRAG_TOT + sb + 64];
        }
      }
      short8 ah, al;
      split8(hw + (lane & 15)*36 + quad*8, ah, al);
      y0 = mm3(ah, al, f2[0], f2[1], y0);
      y1 = mm3(ah, al, f2[2], f2[3], y1);
      y2 = mm3(ah, al, f2[4], f2[5], y2);
      y3 = mm3(ah, al, f2[6], f2[7], y3);
      #pragma unroll
      for (int j = 0; j < 8; ++j) f1c[j] = f1n[j];
    }
    #pragma unroll
    for (int r = 0; r < 4; ++r){
      int row = (quad*4 + r)*68;
      part[w*1088 + row + nidx]      = y0[r];
      part[w*1088 + row + 16 + nidx] = y1[r];
      part[w*1088 + row + 32 + nidx] = y2[r];
      part[w*1088 + row + 48 + nidx] = y3[r];
    }
  }
  __syncthreads();
  // combine partials + residual (into xb, dead since LN1)
  for (int o = tid; o < 1024; o += 256){
    int tok = o >> 6, d = o & 63;
    float s = xb2[tok*68 + d] + fb2[d];
    #pragma unroll
    for (int ww = 0; ww < 4; ++ww) s += part[ww*1088 + tok*68 + d];
    xb[tok*68 + d] = s;
  }
  __syncthreads();
  // ---- LN2 + optional layer residual + store ----
  if (tid < 16){
    const float* row = xb + tid*68;
    float mu = 0.f;
    #pragma unroll
    for (int d = 0; d < 64; ++d) mu += row[d];
    mu *= (1.f/64.f);
    float var = 0.f;
    #pragma unroll
    for (int d = 0; d < 64; ++d){ float t = row[d]-mu; var += t*t; }
    var *= (1.f/64.f);
    mur[tid] = mu; rvr[tid] = rsqrtf(var + 1e-5f);
  }
  __syncthreads();
  for (int o = tid; o < 1024; o += 256){
    int tok = o >> 6, d = o & 63;
    float vv = (xb[tok*68 + d] - mur[tok]) * rvr[tok] * ln2g[d] + ln2b[d];
    xout[bn*1024 + o] = vv + (add_residual ? xin_p[o] : 0.f);
  }
}

// -------------------------------------------------------------------------
// Classifier head. One block per b. (small; fp32)
// -------------------------------------------------------------------------
__global__ __launch_bounds__(256) void final_kernel(
    const float* __restrict__ xc, const float* __restrict__ pm,
    const float* __restrict__ q_embed,
    const float* __restrict__ cin_w, const float* __restrict__ cin_b,
    const float* __restrict__ cout_w, const float* __restrict__ cout_b,
    const float* __restrict__ logit_w, const float* __restrict__ logit_b,
    float* __restrict__ out)
{
  const int b = blockIdx.x;
  const int tid = threadIdx.x;
  __shared__ __align__(16) float xs[M_ * D_];
  __shared__ float kpmv[M_];
  __shared__ __align__(16) float qv[5 * D_], kv[M_ * D_], vv[M_ * D_];
  __shared__ float sv[H_ * 5 * M_];
  __shared__ __align__(16) float ao[5 * D_], zv[5 * D_];

  for (int o = tid; o < M_ * D_; o += 256) {
    int m = o >> 6, d = o & 63;
    float acc = 0.f;
    #pragma unroll
    for (int n = 0; n < N_; ++n) acc += xc[(((b * N_ + n) * M_ + m) * D_) + d];
    xs[o] = acc * (1.f / 32.f);
  }
  if (tid < M_) {
    float any = 0.f;
    #pragma unroll
    for (int n = 0; n < N_; ++n) any += (pm[(b * N_ + n) * M_ + tid] > 0.f) ? 1.f : 0.f;
    kpmv[tid] = (any > 0.f) ? 0.f : 1.f;
  }
  __syncthreads();

  for (int o = tid; o < 5 * D_; o += 256) {
    int qi = o >> 6, d = o & 63;
    qv[o] = cin_b[d] + dot64(q_embed + qi * D_, cin_w + d * D_);
  }
  for (int o = tid; o < 2 * M_ * D_; o += 256) {
    int sel = o >> 10, r = o & 1023, m = r >> 6, d = r & 63;
    float acc = cin_b[D_ + sel * D_ + d] + dot64(xs + m * D_, cin_w + (D_ + sel * D_ + d) * D_);
    ((sel == 0) ? kv : vv)[r] = acc;
  }
  __syncthreads();

  for (int o = tid; o < H_ * 5 * M_; o += 256) {
    int h = o / 80, r = o % 80, qi = r >> 4, km = r & 15;
    float acc = 0.25f * dot16(qv + qi * D_ + h * DH_, kv + km * D_ + h * DH_);
    if (kpmv[km] != 0.f) acc = -1e9f;
    sv[o] = acc;
  }
  __syncthreads();
  if (tid < H_ * 5) {
    int h = tid / 5, qi = tid % 5;
    float* row = sv + h * 80 + qi * M_;
    float mx = -1e30f;
    #pragma unroll
    for (int km = 0; km < M_; ++km) mx = fmaxf(mx, row[km]);
    float se = 0.f;
    #pragma unroll
    for (int km = 0; km < M_; ++km) { float e = __expf(row[km] - mx); row[km] = e; se += e; }
    float inv = 1.f / se;
    #pragma unroll
    for (int km = 0; km < M_; ++km) row[km] *= inv;
  }
  __syncthreads();
  for (int o = tid; o < 5 * D_; o += 256) {
    int qi = o >> 6, d = o & 63, h = d >> 4;
    float acc = 0.f;
    #pragma unroll
    for (int km = 0; km < M_; ++km) acc += sv[h * 80 + qi * M_ + km] * vv[km * D_ + d];
    ao[o] = acc;
  }
  __syncthreads();
  for (int o = tid; o < 5 * D_; o += 256) {
    int qi = o >> 6, d = o & 63;
    zv[o] = cout_b[d] + dot64(ao + qi * D_, cout_w + d * D_);
  }
  __syncthreads();
  if (tid < 5) {
    float acc = logit_b[0] + dot64(zv + tid * D_, logit_w);
    out[b * 5 + tid] = acc;
  }
}

// -------------------------------------------------------------------------
extern "C" void kernel_launch(void* const* d_in, const int* in_sizes, int n_in,
                              void* d_out, int out_size, void* d_ws, size_t ws_size,
                              hipStream_t stream) {
  const float* x       = (const float*)d_in[0];
  const int*   mask    = (const int*)  d_in[1];
  const float* ttcn_w1 = (const float*)d_in[2];
  const float* ttcn_b1 = (const float*)d_in[3];
  const float* ttcn_w2 = (const float*)d_in[4];
  const float* ttcn_b2 = (const float*)d_in[5];
  const float* ttcn_w3 = (const float*)d_in[6];
  const float* ttcn_b3 = (const float*)d_in[7];
  const float* t_bias  = (const float*)d_in[8];
  const float* ga_qw   = (const float*)d_in[9];
  const float* ga_qb   = (const float*)d_in[10];
  const float* ga_kw   = (const float*)d_in[11];
  const float* ga_kb   = (const float*)d_in[12];
  const float* ga_vw   = (const float*)d_in[13];
  const float* ga_vb   = (const float*)d_in[14];
  const float* ga_ow   = (const float*)d_in[15];
  const float* ga_ob   = (const float*)d_in[16];
  const float* tf_in_w = (const float*)d_in[17];
  const float* tf_in_b = (const float*)d_in[18];
  const float* tf_out_w= (const float*)d_in[19];
  const float* tf_out_b= (const float*)d_in[20];
  const float* tf_ln1g = (const float*)d_in[21];
  const float* tf_ln1b = (const float*)d_in[22];
  const float* tf_ln2g = (const float*)d_in[23];
  const float* tf_ln2b = (const float*)d_in[24];
  const float* tf_fw1  = (const float*)d_in[25];
  const float* tf_fb1  = (const float*)d_in[26];
  const float* tf_fw2  = (const float*)d_in[27];
  const float* tf_fb2  = (const float*)d_in[28];
  const float* q_embed = (const float*)d_in[29];
  const float* cls_in_w  = (const float*)d_in[30];
  const float* cls_in_b  = (const float*)d_in[31];
  const float* cls_out_w = (const float*)d_in[32];
  const float* cls_out_b = (const float*)d_in[33];
  const float* logit_w = (const float*)d_in[34];
  const float* logit_b = (const float*)d_in[35];

  float* wsf  = (float*)d_ws;
  float* xp   = wsf;                        // 262144 f
  float* pmb  = wsf + P_TOT * D_;           // 4096 f
  float* xa   = pmb + P_TOT;                // 262144 f
  float* xbuf = xa  + P_TOT * D_;           // 262144 f
  uint4* fr   = (uint4*)(xbuf + P_TOT * D_);// 2*FRAG_TOT uint4
  const short8* frS = (const short8*)fr;

  prep_kernel<<<325, 256, 0, stream>>>(ttcn_w1, ttcn_w2, ttcn_w3,
      ga_qw, ga_kw, ga_vw, ga_ow, tf_in_w, tf_out_w, tf_fw1, tf_fw2, fr);

  ttcn_kernel<<<P_TOT, 256, 0, stream>>>(x, mask, ttcn_b1, ttcn_b2, ttcn_b3, t_bias,
      frS + 0, frS + 256, frS + 768,
      xp, pmb);

  // layer 0
  layer_kernel<<<BN_, 256, 0, stream>>>(xp, pmb, frS, LBASE(0),
      ga_qb, ga_kb, ga_vb, ga_ob, tf_in_b, tf_out_b, tf_ln1g, tf_ln1b,
      tf_fb1, tf_fb2, tf_ln2g, tf_ln2b, xa, 0);

  // layer 1 (with layer residual)
  layer_kernel<<<BN_, 256, 0, stream>>>(xa, pmb, frS, LBASE(1),
      ga_qb + 64, ga_kb + 64, ga_vb + 64, ga_ob + 64,
      tf_in_b + 192, tf_out_b + 64, tf_ln1g + 64, tf_ln1b + 64,
      tf_fb1 + FF_, tf_fb2 + 64, tf_ln2g + 64, tf_ln2b + 64, xbuf, 1);

  final_kernel<<<B_, 256, 0, stream>>>(xbuf, pmb, q_embed,
                                       cls_in_w, cls_in_b, cls_out_w, cls_out_b,
                                       logit_w, logit_b, (float*)d_out);
}

// Round 5
// 267.206 us; speedup vs baseline: 6.1503x; 1.0613x over previous
//
#include <hip/hip_runtime.h>
#include <hip/hip_bf16.h>
#include <math.h>

// Problem constants
#define B_  8
#define N_  32
#define M_  16
#define LX  32
#define D_  64
#define IN_DIM_ 17
#define TT_ 63
#define H_  4
#define DH_ 16
#define P_TOT 4096          // B*N*M
#define BN_ 256             // B*N
#define FF_ 2048

// Fragment pool layout (slot = one short8/uint4 per lane-group entry)
#define FRAG_TOT 83200
#define OFF_INW  2048
#define OFF_OUTW 3584
#define OFF_FW1  4096
#define OFF_FW2  20480

typedef unsigned short ushort_t;
typedef __attribute__((ext_vector_type(8))) short short8;   // 8 bf16 (4 VGPRs)
typedef __attribute__((ext_vector_type(4))) float floatx4;  // MFMA C/D

#define MFMA16(a,b,c) __builtin_amdgcn_mfma_f32_16x16x32_bf16((a),(b),(c),0,0,0)

__device__ __forceinline__ ushort_t f2bf(float f){          // RNE float->bf16
  unsigned u = __float_as_uint(f);
  u += 0x7FFFu + ((u >> 16) & 1u);
  return (ushort_t)(u >> 16);
}
__device__ __forceinline__ float bf2f(ushort_t h){ return __uint_as_float(((unsigned)h) << 16); }

__device__ __forceinline__ uint4 pack8(const ushort_t* h){
  uint4 u;
  u.x = (unsigned)h[0] | ((unsigned)h[1] << 16);
  u.y = (unsigned)h[2] | ((unsigned)h[3] << 16);
  u.z = (unsigned)h[4] | ((unsigned)h[5] << 16);
  u.w = (unsigned)h[6] | ((unsigned)h[7] << 16);
  return u;
}

// split 8 consecutive floats into hi/lo bf16 short8
__device__ __forceinline__ void split8(const float* r, short8& hi, short8& lo){
  #pragma unroll
  for (int j = 0; j < 8; ++j){
    float v = r[j];
    ushort_t h = f2bf(v);
    ushort_t l2 = f2bf(v - bf2f(h));
    hi[j] = (short)h; lo[j] = (short)l2;
  }
}
// hi-only conversion
__device__ __forceinline__ uint4 cvt8(const float* r){
  ushort_t hh[8];
  #pragma unroll
  for (int j = 0; j < 8; ++j) hh[j] = f2bf(r[j]);
  return pack8(hh);
}

// 3-term split product: (ah+al)(bh+bl) ~= ah*bh + ah*bl + al*bh
__device__ __forceinline__ floatx4 mm3(short8 ah, short8 al, short8 bh, short8 bl, floatx4 c){
  c = MFMA16(ah, bh, c); c = MFMA16(ah, bl, c); c = MFMA16(al, bh, c); return c;
}

__device__ __forceinline__ float dot64(const float* __restrict__ a, const float* __restrict__ w){
  const float4* a4 = (const float4*)a;
  const float4* w4 = (const float4*)w;
  float acc = 0.f;
  #pragma unroll
  for (int k = 0; k < 16; ++k){ float4 x = a4[k], y = w4[k];
    acc += x.x*y.x + x.y*y.y + x.z*y.z + x.w*y.w; }
  return acc;
}
__device__ __forceinline__ float dot16(const float* __restrict__ a, const float* __restrict__ b){
  const float4* a4 = (const float4*)a; const float4* b4 = (const float4*)b;
  float acc = 0.f;
  #pragma unroll
  for (int k = 0; k < 4; ++k){ float4 x = a4[k], y = b4[k];
    acc += x.x*y.x + x.y*y.y + x.z*y.z + x.w*y.w; }
  return acc;
}

// pack A-frags (16 tokens x 64 k) from stride-68 LDS buffer into fragA (hi[128], lo[128])
__device__ __forceinline__ void packA68(const float* buf, short8* fA, int tid){
  if (tid < 128){
    int ln = tid & 63, ks = tid >> 6;
    const float* r = buf + (ln & 15)*68 + ks*32 + ((ln >> 4) & 3)*8;
    short8 hi, lo; split8(r, hi, lo);
    fA[tid] = hi; fA[128 + tid] = lo;
  }
}

// -------------------------------------------------------------------------
// Prep: convert ALL weight matrices to MFMA B-fragment pool (hi at [s], lo at
// [FRAG_TOT+s]). B[k][n]: n = nt*16 + (lane&15), k = ks*32 + quad*8 + j.
// w3 special: columns reordered so tile nt covers i = nt>>2 (constant per
// tile), t = (nt&3)*16 + lane&15 — epilogue x-reads become broadcasts.
// -------------------------------------------------------------------------
__global__ __launch_bounds__(256) void prep_kernel(
    const float* __restrict__ w1, const float* __restrict__ w2, const float* __restrict__ w3,
    const float* __restrict__ gqw, const float* __restrict__ gkw,
    const float* __restrict__ gvw, const float* __restrict__ gow,
    const float* __restrict__ inw, const float* __restrict__ outw,
    const float* __restrict__ fw1, const float* __restrict__ fw2,
    uint4* __restrict__ fr)
{
  int s = blockIdx.x*256 + threadIdx.x;
  if (s >= FRAG_TOT) return;
  const float* src; int Nr, Kr, KS, rel; int w3seg = 0;
  if (s < 256)      { src = w1; Nr=63;  Kr=17; KS=1; rel = s; }
  else if (s < 768) { src = w2; Nr=63;  Kr=63; KS=2; rel = s-256; }
  else if (s < 9472){ src = w3; Nr=1071;Kr=63; KS=2; rel = s-768; w3seg = 1; }
  else {
    int t = s - 9472, l = t / 36864, r2 = t - l*36864;
    if (r2 < 512)        { src = gqw + l*4096;   Nr=64;  Kr=64;   KS=2;  rel = r2; }
    else if (r2 < 1024)  { src = gkw + l*4096;   Nr=64;  Kr=64;   KS=2;  rel = r2-512; }
    else if (r2 < 1536)  { src = gvw + l*4096;   Nr=64;  Kr=64;   KS=2;  rel = r2-1024; }
    else if (r2 < 2048)  { src = gow + l*4096;   Nr=64;  Kr=64;   KS=2;  rel = r2-1536; }
    else if (r2 < 3584)  { src = inw + l*12288;  Nr=192; Kr=64;   KS=2;  rel = r2-2048; }
    else if (r2 < 4096)  { src = outw + l*4096;  Nr=64;  Kr=64;   KS=2;  rel = r2-3584; }
    else if (r2 < 20480) { src = fw1 + l*131072; Nr=2048;Kr=64;   KS=2;  rel = r2-4096; }
    else                 { src = fw2 + l*131072; Nr=64;  Kr=2048; KS=64; rel = r2-20480; }
  }
  int lane = rel & 63, tmp = rel >> 6;
  int ks = tmp % KS, nt = tmp / KS;
  int kb = ks*32 + ((lane >> 4) & 3)*8;
  int n, validn;
  if (w3seg){
    int i = nt >> 2, tq = nt & 3;
    int t = tq*16 + (lane & 15);
    n = t*17 + i;                         // source row of w3 (c = t*17+i)
    validn = (t < 63);
  } else {
    n = nt*16 + (lane & 15);
    validn = (n < Nr);
  }
  float v[8];
  #pragma unroll
  for (int j = 0; j < 8; ++j) v[j] = (validn && (kb + j) < Kr) ? src[n*Kr + kb + j] : 0.f;
  ushort_t hh[8], ll[8];
  #pragma unroll
  for (int j = 0; j < 8; ++j){ hh[j] = f2bf(v[j]); ll[j] = f2bf(v[j] - bf2f(hh[j])); }
  fr[s] = pack8(hh); fr[FRAG_TOT + s] = pack8(ll);
}

// -------------------------------------------------------------------------
// Fused TTCN — bf16 1-term MFMA, conflict-minimized layouts.
// xs stride 20, h-transposes stride 35, w3 tiles i-major (broadcast x-reads),
// b3 dropped (cancels in softmax num/den). LDS 26752 B -> 6 blocks/CU.
// -------------------------------------------------------------------------
__global__ __launch_bounds__(256) void ttcn_kernel(
    const float* __restrict__ x, const int* __restrict__ mask,
    const float* __restrict__ b1, const float* __restrict__ b2,
    const float* __restrict__ tb,
    const short8* __restrict__ w1bhi,
    const short8* __restrict__ w2bhi,
    const short8* __restrict__ w3bhi,
    float* __restrict__ xp, float* __restrict__ pm)
{
  __shared__ __align__(16) char pool[26752];
  float*  xs    = (float*)(pool + 0);        // 32x20 stride
  float*  msv   = (float*)(pool + 2560);     // 32
  short8* xfhi  = (short8*)(pool + 2688);    // 128 slots
  float*  h1t   = (float*)(pool + 4736);     // 64x35 (dead after P3)
  short8* h2fhi = (short8*)(pool + 4736);    // alias h1t (P5+)
  float*  colres= (float*)(pool + 8832);     // 17x64 (P6+, alias h1t tail)
  float*  h2t   = (float*)(pool + 13696);    // 64x35
  short8* h1fhi = (short8*)(pool + 22656);   // 256 slots

  const int p = blockIdx.x, tid = threadIdx.x;
  const int lane = tid & 63, wvi = tid >> 6;
  const int nidx = lane & 15, quad = lane >> 4;

  // P0: stage x (stride 20) + mask
  for (int idx = tid; idx < LX*IN_DIM_; idx += 256){
    int l = (idx * 3856) >> 16;             // idx/17 exact for idx<1088
    int i = idx - l*17;
    xs[l*20 + i] = x[p*(LX*IN_DIM_) + idx];
  }
  if (tid < LX) msv[tid] = (float)mask[p*LX + tid];
  __syncthreads();

  // P1: x A-fragments (hi only), K=32 (k>=17 zero-padded)
  if (tid < 128){
    int mt = tid >> 6;
    int l = mt*16 + nidx;
    float r[8];
    #pragma unroll
    for (int j = 0; j < 8; ++j){
      int k = quad*8 + j;
      r[j] = (k < IN_DIM_) ? xs[l*20 + k] : 0.f;
    }
    ((uint4*)xfhi)[tid] = cvt8(r);
  }
  __syncthreads();

  // P2: GEMM1  h1 = relu(x @ w1^T + b1)
  {
    short8 axh0 = xfhi[lane], axh1 = xfhi[64 + lane];
    short8 bh = w1bhi[wvi*64 + lane];
    floatx4 a0 = {0.f,0.f,0.f,0.f}, a1 = {0.f,0.f,0.f,0.f};
    a0 = MFMA16(axh0, bh, a0);
    a1 = MFMA16(axh1, bh, a1);
    int t = wvi*16 + nidx;
    float bb = (t < TT_) ? b1[t] : 0.f;
    #pragma unroll
    for (int r = 0; r < 4; ++r){
      h1t[t*35 + quad*4 + r]      = fmaxf(a0[r] + bb, 0.f);
      h1t[t*35 + 16 + quad*4 + r] = fmaxf(a1[r] + bb, 0.f);
    }
  }
  __syncthreads();

  // P3: h1 A-fragments (hi only)
  {
    int mt = tid >> 7, ks = (tid >> 6) & 1;
    int l = mt*16 + nidx;
    float r[8];
    #pragma unroll
    for (int j = 0; j < 8; ++j) r[j] = h1t[(ks*32 + quad*8 + j)*35 + l];
    ((uint4*)h1fhi)[tid] = cvt8(r);
  }
  __syncthreads();

  // P4: GEMM2  h2 = relu(h1 @ w2^T + b2)
  {
    short8 ah00 = h1fhi[lane],       ah01 = h1fhi[64 + lane];
    short8 ah10 = h1fhi[128 + lane], ah11 = h1fhi[192 + lane];
    short8 bh0 = w2bhi[(wvi*2+0)*64 + lane];
    short8 bh1 = w2bhi[(wvi*2+1)*64 + lane];
    floatx4 a0 = {0.f,0.f,0.f,0.f}, a1 = {0.f,0.f,0.f,0.f};
    a0 = MFMA16(ah00, bh0, a0); a0 = MFMA16(ah01, bh1, a0);
    a1 = MFMA16(ah10, bh0, a1); a1 = MFMA16(ah11, bh1, a1);
    int t = wvi*16 + nidx;
    float bb = (t < TT_) ? b2[t] : 0.f;
    #pragma unroll
    for (int r = 0; r < 4; ++r){
      h2t[t*35 + quad*4 + r]      = fmaxf(a0[r] + bb, 0.f);
      h2t[t*35 + 16 + quad*4 + r] = fmaxf(a1[r] + bb, 0.f);
    }
  }
  __syncthreads();

  // P5: h2 A-fragments (hi only), aliasing dead h1t
  {
    int mt = tid >> 7, ks = (tid >> 6) & 1;
    int l = mt*16 + nidx;
    float r[8];
    #pragma unroll
    for (int j = 0; j < 8; ++j) r[j] = h2t[(ks*32 + quad*8 + j)*35 + l];
    ((uint4*)h2fhi)[tid] = cvt8(r);
  }
  __syncthreads();

  // P6: GEMM3 (i-major tiles) + masked softmax over l + contraction with x
  {
    short8 ah00 = h2fhi[lane],       ah01 = h2fhi[64 + lane];
    short8 ah10 = h2fhi[128 + lane], ah11 = h2fhi[192 + lane];
    float msA[4], msB[4];
    #pragma unroll
    for (int r = 0; r < 4; ++r){ msA[r] = msv[quad*4 + r]; msB[r] = msv[quad*4 + 16 + r]; }
    short8 nbh0 = w3bhi[(wvi*2+0)*64 + lane];
    short8 nbh1 = w3bhi[(wvi*2+1)*64 + lane];
    for (int it = 0; it < 17; ++it){
      int tile = wvi + it*4;                 // waves cover tiles 0..67
      short8 bh0 = nbh0, bh1 = nbh1;
      if (it < 16){
        int nt = tile + 4;
        nbh0 = w3bhi[(nt*2+0)*64 + lane];
        nbh1 = w3bhi[(nt*2+1)*64 + lane];
      }
      floatx4 a0 = {0.f,0.f,0.f,0.f}, a1 = {0.f,0.f,0.f,0.f};
      a0 = MFMA16(ah00, bh0, a0); a0 = MFMA16(ah01, bh1, a0);
      a1 = MFMA16(ah10, bh0, a1); a1 = MFMA16(ah11, bh1, a1);

      int i_idx = tile >> 2;                 // constant within tile
      int t = ((tile & 3) << 4) + nidx;
      bool valid = t < 63;
      float f[8];
      #pragma unroll
      for (int r = 0; r < 4; ++r){
        f[r]     = (msA[r] != 0.f) ? a0[r] : -1e8f;
        f[r + 4] = (msB[r] != 0.f) ? a1[r] : -1e8f;
      }
      float mx = f[0];
      #pragma unroll
      for (int r = 1; r < 8; ++r) mx = fmaxf(mx, f[r]);
      mx = fmaxf(mx, __shfl_xor(mx, 16, 64));
      mx = fmaxf(mx, __shfl_xor(mx, 32, 64));
      float den = 0.f, num = 0.f;
      #pragma unroll
      for (int r = 0; r < 4; ++r){
        float e0 = __expf(f[r] - mx);
        den += e0; num = fmaf(e0, xs[(quad*4 + r)*20 + i_idx], num);
        float e1 = __expf(f[r+4] - mx);
        den += e1; num = fmaf(e1, xs[(quad*4 + 16 + r)*20 + i_idx], num);
      }
      den += __shfl_xor(den, 16, 64); den += __shfl_xor(den, 32, 64);
      num += __shfl_xor(num, 16, 64); num += __shfl_xor(num, 32, 64);
      if (quad == 0 && valid) colres[i_idx*64 + t] = num / den;
    }
  }
  __syncthreads();

  // P7: h_t[t] = relu(sum_i colres[i][t] + tb[t]); append mask_patch
  if (tid < TT_){
    float acc = 0.f;
    #pragma unroll
    for (int i2 = 0; i2 < IN_DIM_; ++i2) acc += colres[i2*64 + tid];
    xp[p*D_ + tid] = fmaxf(acc + tb[tid], 0.f);
  }
  if (tid == TT_){
    float s = 0.f;
    #pragma unroll
    for (int l = 0; l < LX; ++l) s += msv[l];
    float mp = (s > 0.f) ? 1.f : 0.f;
    xp[p*D_ + TT_] = mp;
    pm[p] = mp;
  }
}

// -------------------------------------------------------------------------
// BOTH transformer layers fused, one block per bn. Runtime l-loop; layer-1
// residual kept in registers; no device-wide sync between layers.
// -------------------------------------------------------------------------
__global__ __launch_bounds__(256) void layer12_kernel(
    const float* __restrict__ xin, const float* __restrict__ pm,
    const short8* __restrict__ frS,
    const float* __restrict__ gqb, const float* __restrict__ gkb,
    const float* __restrict__ gvb, const float* __restrict__ gob,
    const float* __restrict__ inb, const float* __restrict__ outb,
    const float* __restrict__ ln1g, const float* __restrict__ ln1b,
    const float* __restrict__ fb1, const float* __restrict__ fb2,
    const float* __restrict__ ln2g, const float* __restrict__ ln2b,
    float* __restrict__ xout)
{
  __shared__ __align__(16) float xb[16*68];
  __shared__ __align__(16) float xb2[16*68];
  __shared__ __align__(16) float q_[16*68];
  __shared__ __align__(16) float k_[16*68];
  __shared__ __align__(16) float v_[16*68];
  __shared__ __align__(16) float ao[16*68];
  __shared__ __align__(16) float ss[1024];
  __shared__ __align__(16) short8 fragA[256];
  __shared__ __align__(16) float hbuf[4*16*36];
  __shared__ __align__(16) float part[4*16*68];
  __shared__ float pmv[16], mur[16], rvr[16];

  const int bn = blockIdx.x, tid = threadIdx.x;
  const int lane = tid & 63, wvi = tid >> 6;
  const int nidx = lane & 15, quad = lane >> 4;
  const float* xin_p = xin + bn*1024;

  for (int o = tid; o < 1024; o += 256) xb[(o>>6)*68 + (o&63)] = xin_p[o];
  if (tid < 16) pmv[tid] = pm[bn*16 + tid];
  __syncthreads();

  for (int l = 0; l < 2; ++l){
    const int lbase = 9472 + l*36864;
    const float* gqbL = gqb + l*64;  const float* gkbL = gkb + l*64;
    const float* gvbL = gvb + l*64;  const float* gobL = gob + l*64;
    const float* inbL = inb + l*192; const float* outbL = outb + l*64;
    const float* ln1gL = ln1g + l*64; const float* ln1bL = ln1b + l*64;
    const float* fb1L = fb1 + l*2048; const float* fb2L = fb2 + l*64;
    const float* ln2gL = ln2g + l*64; const float* ln2bL = ln2b + l*64;

    // save layer input for the l==1 residual
    float xres[4];
    #pragma unroll
    for (int kk2 = 0; kk2 < 4; ++kk2){
      int o = tid + kk2*256;
      xres[kk2] = xb[(o>>6)*68 + (o&63)];
    }

    // ---- gattn QKV ----
    packA68(xb, fragA, tid);
    __syncthreads();
    {
      short8 axh0 = fragA[lane], axh1 = fragA[64+lane];
      short8 axl0 = fragA[128+lane], axl1 = fragA[192+lane];
      #pragma unroll
      for (int mat = 0; mat < 3; ++mat){
        int base = lbase + mat*512;
        short8 bh0 = frS[base + (wvi*2+0)*64 + lane];
        short8 bl0 = frS[FRAG_TOT + base + (wvi*2+0)*64 + lane];
        short8 bh1 = frS[base + (wvi*2+1)*64 + lane];
        short8 bl1 = frS[FRAG_TOT + base + (wvi*2+1)*64 + lane];
        floatx4 c = {0.f,0.f,0.f,0.f};
        c = mm3(axh0, axl0, bh0, bl0, c);
        c = mm3(axh1, axl1, bh1, bl1, c);
        int d = wvi*16 + nidx;
        float bb = (mat == 0 ? gqbL : mat == 1 ? gkbL : gvbL)[d];
        float* dst = (mat == 0 ? q_ : mat == 1 ? k_ : v_);
        #pragma unroll
        for (int r = 0; r < 4; ++r) dst[(quad*4+r)*68 + d] = c[r] + bb;
      }
    }
    __syncthreads();
    for (int o = tid; o < 1024; o += 256){
      int h = o >> 8, r = o & 255, qm = r >> 4, km = r & 15;
      float acc = dot16(q_ + qm*68 + h*16, k_ + km*68 + h*16);
      float dist = 5.0f * fabsf((float)(qm - km));
      float tbv = logf(expf(-dist) + 1e-12f);
      acc = acc * 0.25f + tbv;
      if (pmv[km] == 0.f) acc = -1e9f;
      ss[o] = acc;
    }
    __syncthreads();
    if (tid < 64){
      float* row = ss + tid*16;
      float mx = -1e30f;
      #pragma unroll
      for (int j = 0; j < 16; ++j) mx = fmaxf(mx, row[j]);
      float se = 0.f;
      #pragma unroll
      for (int j = 0; j < 16; ++j){ float e = __expf(row[j]-mx); row[j] = e; se += e; }
      float inv = 1.f/se;
      #pragma unroll
      for (int j = 0; j < 16; ++j) row[j] *= inv;
    }
    __syncthreads();
    for (int o = tid; o < 1024; o += 256){
      int m = o >> 6, d = o & 63, h = d >> 4;
      float acc = 0.f;
      #pragma unroll
      for (int km = 0; km < 16; ++km) acc += ss[h*256 + m*16 + km] * v_[km*68 + d];
      ao[m*68 + d] = acc;
    }
    __syncthreads();
    packA68(ao, fragA, tid);
    __syncthreads();
    {
      short8 axh0 = fragA[lane], axh1 = fragA[64+lane];
      short8 axl0 = fragA[128+lane], axl1 = fragA[192+lane];
      int base = lbase + 1536;   // gow
      short8 bh0 = frS[base + (wvi*2+0)*64 + lane];
      short8 bl0 = frS[FRAG_TOT + base + (wvi*2+0)*64 + lane];
      short8 bh1 = frS[base + (wvi*2+1)*64 + lane];
      short8 bl1 = frS[FRAG_TOT + base + (wvi*2+1)*64 + lane];
      floatx4 c = {0.f,0.f,0.f,0.f};
      c = mm3(axh0, axl0, bh0, bl0, c);
      c = mm3(axh1, axl1, bh1, bl1, c);
      int d = wvi*16 + nidx;
      float bb = gobL[d];
      float div = __expf((float)(d & ~1) * (-0.14391156831212793f)); // -ln(1e4)/64
      #pragma unroll
      for (int r = 0; r < 4; ++r){
        int tok = quad*4 + r;
        float arg = (float)tok * div;
        float pev = (d & 1) ? cosf(arg) : sinf(arg);
        xb[tok*68 + d] += (c[r] + bb) * pmv[tok] + pev;
      }
    }
    __syncthreads();

    // ---- MHA ----
    packA68(xb, fragA, tid);
    __syncthreads();
    {
      short8 axh0 = fragA[lane], axh1 = fragA[64+lane];
      short8 axl0 = fragA[128+lane], axl1 = fragA[192+lane];
      #pragma unroll
      for (int sel = 0; sel < 3; ++sel){
        int nt = sel*4 + wvi;
        int base = lbase + OFF_INW + nt*128;
        short8 bh0 = frS[base + lane];
        short8 bl0 = frS[FRAG_TOT + base + lane];
        short8 bh1 = frS[base + 64 + lane];
        short8 bl1 = frS[FRAG_TOT + base + 64 + lane];
        floatx4 c = {0.f,0.f,0.f,0.f};
        c = mm3(axh0, axl0, bh0, bl0, c);
        c = mm3(axh1, axl1, bh1, bl1, c);
        int d = wvi*16 + nidx;
        float bb = inbL[nt*16 + nidx];
        float* dst = (sel == 0 ? q_ : sel == 1 ? k_ : v_);
        #pragma unroll
        for (int r = 0; r < 4; ++r) dst[(quad*4+r)*68 + d] = c[r] + bb;
      }
    }
    __syncthreads();
    for (int o = tid; o < 1024; o += 256){
      int h = o >> 8, r = o & 255, qm = r >> 4, km = r & 15;
      ss[o] = 0.25f * dot16(q_ + qm*68 + h*16, k_ + km*68 + h*16);
    }
    __syncthreads();
    if (tid < 64){
      float* row = ss + tid*16;
      float mx = -1e30f;
      #pragma unroll
      for (int j = 0; j < 16; ++j) mx = fmaxf(mx, row[j]);
      float se = 0.f;
      #pragma unroll
      for (int j = 0; j < 16; ++j){ float e = __expf(row[j]-mx); row[j] = e; se += e; }
      float inv = 1.f/se;
      #pragma unroll
      for (int j = 0; j < 16; ++j) row[j] *= inv;
    }
    __syncthreads();
    for (int o = tid; o < 1024; o += 256){
      int m = o >> 6, d = o & 63, h = d >> 4;
      float acc = 0.f;
      #pragma unroll
      for (int km = 0; km < 16; ++km) acc += ss[h*256 + m*16 + km] * v_[km*68 + d];
      ao[m*68 + d] = acc;
    }
    __syncthreads();
    packA68(ao, fragA, tid);
    __syncthreads();
    {
      short8 axh0 = fragA[lane], axh1 = fragA[64+lane];
      short8 axl0 = fragA[128+lane], axl1 = fragA[192+lane];
      int base = lbase + OFF_OUTW;
      short8 bh0 = frS[base + (wvi*2+0)*64 + lane];
      short8 bl0 = frS[FRAG_TOT + base + (wvi*2+0)*64 + lane];
      short8 bh1 = frS[base + (wvi*2+1)*64 + lane];
      short8 bl1 = frS[FRAG_TOT + base + (wvi*2+1)*64 + lane];
      floatx4 c = {0.f,0.f,0.f,0.f};
      c = mm3(axh0, axl0, bh0, bl0, c);
      c = mm3(axh1, axl1, bh1, bl1, c);
      int d = wvi*16 + nidx;
      float bb = outbL[d];
      #pragma unroll
      for (int r = 0; r < 4; ++r) xb[(quad*4+r)*68 + d] += c[r] + bb;
    }
    __syncthreads();

    // ---- LN1 -> xb2 ----
    if (tid < 16){
      const float* row = xb + tid*68;
      float mu = 0.f;
      #pragma unroll
      for (int d = 0; d < 64; ++d) mu += row[d];
      mu *= (1.f/64.f);
      float var = 0.f;
      #pragma unroll
      for (int d = 0; d < 64; ++d){ float t = row[d]-mu; var += t*t; }
      var *= (1.f/64.f);
      mur[tid] = mu; rvr[tid] = rsqrtf(var + 1e-5f);
    }
    __syncthreads();
    for (int o = tid; o < 1024; o += 256){
      int m = o >> 6, d = o & 63;
      xb2[m*68 + d] = (xb[m*68 + d] - mur[m]) * rvr[m] * ln1gL[d] + ln1bL[d];
    }
    __syncthreads();
    packA68(xb2, fragA, tid);
    __syncthreads();

    // ---- FF (2048 hidden): per wave 512 j's, 16 ksteps ----
    {
      const int w = wvi;
      const int f1base = lbase + OFF_FW1, f2base = lbase + OFF_FW2;
      short8 axh0 = fragA[lane],     axh1 = fragA[64 + lane];
      short8 axl0 = fragA[128+lane], axl1 = fragA[192 + lane];
      floatx4 y0 = {0.f,0.f,0.f,0.f}, y1 = y0, y2 = y0, y3 = y0;
      float* hw = hbuf + w*576;

      short8 f1c[8], f1n[8];
      {
        int ntA = w*32;
        #pragma unroll
        for (int t2 = 0; t2 < 2; ++t2){
          int sb = f1base + ((ntA+t2)*2)*64 + lane;
          f1c[t2*4+0] = frS[sb];            f1c[t2*4+1] = frS[FRAG_TOT + sb];
          f1c[t2*4+2] = frS[sb + 64];       f1c[t2*4+3] = frS[FRAG_TOT + sb + 64];
        }
      }
      for (int it = 0; it < 16; ++it){
        int ntA = w*32 + it*2;
        floatx4 hA = {0.f,0.f,0.f,0.f}, hB = hA;
        hA = mm3(axh0, axl0, f1c[0], f1c[1], hA);
        hA = mm3(axh1, axl1, f1c[2], f1c[3], hA);
        hB = mm3(axh0, axl0, f1c[4], f1c[5], hB);
        hB = mm3(axh1, axl1, f1c[6], f1c[7], hB);
        float bbA = fb1L[ntA*16 + nidx], bbB = fb1L[ntA*16 + 16 + nidx];
        #pragma unroll
        for (int r = 0; r < 4; ++r){
          hw[(quad*4+r)*36 + nidx]      = fmaxf(hA[r] + bbA, 0.f);
          hw[(quad*4+r)*36 + 16 + nidx] = fmaxf(hB[r] + bbB, 0.f);
        }
        int kst = w*16 + it;
        short8 f2[8];
        #pragma unroll
        for (int ntd = 0; ntd < 4; ++ntd){
          int sb = f2base + (ntd*64 + kst)*64 + lane;
          f2[ntd*2]   = frS[sb];
          f2[ntd*2+1] = frS[FRAG_TOT + sb];
        }
        if (it < 15){
          int ntN = ntA + 2;
          #pragma unroll
          for (int t2 = 0; t2 < 2; ++t2){
            int sb = f1base + ((ntN+t2)*2)*64 + lane;
            f1n[t2*4+0] = frS[sb];            f1n[t2*4+1] = frS[FRAG_TOT + sb];
            f1n[t2*4+2] = frS[sb + 64];       f1n[t2*4+3] = frS[FRAG_TOT + sb + 64];
          }
        }
        short8 ah, al;
        split8(hw + (lane & 15)*36 + quad*8, ah, al);
        y0 = mm3(ah, al, f2[0], f2[1], y0);
        y1 = mm3(ah, al, f2[2], f2[3], y1);
        y2 = mm3(ah, al, f2[4], f2[5], y2);
        y3 = mm3(ah, al, f2[6], f2[7], y3);
        #pragma unroll
        for (int j = 0; j < 8; ++j) f1c[j] = f1n[j];
      }
      #pragma unroll
      for (int r = 0; r < 4; ++r){
        int row = (quad*4 + r)*68;
        part[w*1088 + row + nidx]      = y0[r];
        part[w*1088 + row + 16 + nidx] = y1[r];
        part[w*1088 + row + 32 + nidx] = y2[r];
        part[w*1088 + row + 48 + nidx] = y3[r];
      }
    }
    __syncthreads();
    for (int o = tid; o < 1024; o += 256){
      int tok = o >> 6, d = o & 63;
      float s = xb2[tok*68 + d] + fb2L[d];
      #pragma unroll
      for (int ww = 0; ww < 4; ++ww) s += part[ww*1088 + tok*68 + d];
      xb[tok*68 + d] = s;
    }
    __syncthreads();
    // ---- LN2 (+ layer-1 residual) ----
    if (tid < 16){
      const float* row = xb + tid*68;
      float mu = 0.f;
      #pragma unroll
      for (int d = 0; d < 64; ++d) mu += row[d];
      mu *= (1.f/64.f);
      float var = 0.f;
      #pragma unroll
      for (int d = 0; d < 64; ++d){ float t = row[d]-mu; var += t*t; }
      var *= (1.f/64.f);
      mur[tid] = mu; rvr[tid] = rsqrtf(var + 1e-5f);
    }
    __syncthreads();
    #pragma unroll
    for (int kk2 = 0; kk2 < 4; ++kk2){
      int o = tid + kk2*256;
      int tok = o >> 6, d = o & 63;
      float vv = (xb[tok*68 + d] - mur[tok]) * rvr[tok] * ln2gL[d] + ln2bL[d];
      if (l == 0) xb[tok*68 + d] = vv;                 // becomes layer-1 input
      else        xout[bn*1024 + o] = vv + xres[kk2];  // layer residual
    }
    __syncthreads();
  }
}

// -------------------------------------------------------------------------
// Classifier head. One block per b. (small; fp32)
// -------------------------------------------------------------------------
__global__ __launch_bounds__(256) void final_kernel(
    const float* __restrict__ xc, const float* __restrict__ pm,
    const float* __restrict__ q_embed,
    const float* __restrict__ cin_w, const float* __restrict__ cin_b,
    const float* __restrict__ cout_w, const float* __restrict__ cout_b,
    const float* __restrict__ logit_w, const float* __restrict__ logit_b,
    float* __restrict__ out)
{
  const int b = blockIdx.x;
  const int tid = threadIdx.x;
  __shared__ __align__(16) float xs[M_ * D_];
  __shared__ float kpmv[M_];
  __shared__ __align__(16) float qv[5 * D_], kv[M_ * D_], vv[M_ * D_];
  __shared__ float sv[H_ * 5 * M_];
  __shared__ __align__(16) float ao[5 * D_], zv[5 * D_];

  for (int o = tid; o < M_ * D_; o += 256) {
    int m = o >> 6, d = o & 63;
    float acc = 0.f;
    #pragma unroll
    for (int n = 0; n < N_; ++n) acc += xc[(((b * N_ + n) * M_ + m) * D_) + d];
    xs[o] = acc * (1.f / 32.f);
  }
  if (tid < M_) {
    float any = 0.f;
    #pragma unroll
    for (int n = 0; n < N_; ++n) any += (pm[(b * N_ + n) * M_ + tid] > 0.f) ? 1.f : 0.f;
    kpmv[tid] = (any > 0.f) ? 0.f : 1.f;
  }
  __syncthreads();

  for (int o = tid; o < 5 * D_; o += 256) {
    int qi = o >> 6, d = o & 63;
    qv[o] = cin_b[d] + dot64(q_embed + qi * D_, cin_w + d * D_);
  }
  for (int o = tid; o < 2 * M_ * D_; o += 256) {
    int sel = o >> 10, r = o & 1023, m = r >> 6, d = r & 63;
    float acc = cin_b[D_ + sel * D_ + d] + dot64(xs + m * D_, cin_w + (D_ + sel * D_ + d) * D_);
    ((sel == 0) ? kv : vv)[r] = acc;
  }
  __syncthreads();

  for (int o = tid; o < H_ * 5 * M_; o += 256) {
    int h = o / 80, r = o % 80, qi = r >> 4, km = r & 15;
    float acc = 0.25f * dot16(qv + qi * D_ + h * DH_, kv + km * D_ + h * DH_);
    if (kpmv[km] != 0.f) acc = -1e9f;
    sv[o] = acc;
  }
  __syncthreads();
  if (tid < H_ * 5) {
    int h = tid / 5, qi = tid % 5;
    float* row = sv + h * 80 + qi * M_;
    float mx = -1e30f;
    #pragma unroll
    for (int km = 0; km < M_; ++km) mx = fmaxf(mx, row[km]);
    float se = 0.f;
    #pragma unroll
    for (int km = 0; km < M_; ++km) { float e = __expf(row[km] - mx); row[km] = e; se += e; }
    float inv = 1.f / se;
    #pragma unroll
    for (int km = 0; km < M_; ++km) row[km] *= inv;
  }
  __syncthreads();
  for (int o = tid; o < 5 * D_; o += 256) {
    int qi = o >> 6, d = o & 63, h = d >> 4;
    float acc = 0.f;
    #pragma unroll
    for (int km = 0; km < M_; ++km) acc += sv[h * 80 + qi * M_ + km] * vv[km * D_ + d];
    ao[o] = acc;
  }
  __syncthreads();
  for (int o = tid; o < 5 * D_; o += 256) {
    int qi = o >> 6, d = o & 63;
    zv[o] = cout_b[d] + dot64(ao + qi * D_, cout_w + d * D_);
  }
  __syncthreads();
  if (tid < 5) {
    float acc = logit_b[0] + dot64(zv + tid * D_, logit_w);
    out[b * 5 + tid] = acc;
  }
}

// -------------------------------------------------------------------------
extern "C" void kernel_launch(void* const* d_in, const int* in_sizes, int n_in,
                              void* d_out, int out_size, void* d_ws, size_t ws_size,
                              hipStream_t stream) {
  const float* x       = (const float*)d_in[0];
  const int*   mask    = (const int*)  d_in[1];
  const float* ttcn_w1 = (const float*)d_in[2];
  const float* ttcn_b1 = (const float*)d_in[3];
  const float* ttcn_w2 = (const float*)d_in[4];
  const float* ttcn_b2 = (const float*)d_in[5];
  const float* ttcn_w3 = (const float*)d_in[6];
  const float* ttcn_b3 = (const float*)d_in[7];   // unused: cancels in softmax
  const float* t_bias  = (const float*)d_in[8];
  const float* ga_qw   = (const float*)d_in[9];
  const float* ga_qb   = (const float*)d_in[10];
  const float* ga_kw   = (const float*)d_in[11];
  const float* ga_kb   = (const float*)d_in[12];
  const float* ga_vw   = (const float*)d_in[13];
  const float* ga_vb   = (const float*)d_in[14];
  const float* ga_ow   = (const float*)d_in[15];
  const float* ga_ob   = (const float*)d_in[16];
  const float* tf_in_w = (const float*)d_in[17];
  const float* tf_in_b = (const float*)d_in[18];
  const float* tf_out_w= (const float*)d_in[19];
  const float* tf_out_b= (const float*)d_in[20];
  const float* tf_ln1g = (const float*)d_in[21];
  const float* tf_ln1b = (const float*)d_in[22];
  const float* tf_ln2g = (const float*)d_in[23];
  const float* tf_ln2b = (const float*)d_in[24];
  const float* tf_fw1  = (const float*)d_in[25];
  const float* tf_fb1  = (const float*)d_in[26];
  const float* tf_fw2  = (const float*)d_in[27];
  const float* tf_fb2  = (const float*)d_in[28];
  const float* q_embed = (const float*)d_in[29];
  const float* cls_in_w  = (const float*)d_in[30];
  const float* cls_in_b  = (const float*)d_in[31];
  const float* cls_out_w = (const float*)d_in[32];
  const float* cls_out_b = (const float*)d_in[33];
  const float* logit_w = (const float*)d_in[34];
  const float* logit_b = (const float*)d_in[35];
  (void)ttcn_b3;

  float* wsf  = (float*)d_ws;
  float* xp   = wsf;                        // 262144 f
  float* pmb  = wsf + P_TOT * D_;           // 4096 f
  float* xbuf = pmb + P_TOT;                // 262144 f
  uint4* fr   = (uint4*)(xbuf + P_TOT * D_);// 2*FRAG_TOT uint4
  const short8* frS = (const short8*)fr;

  prep_kernel<<<325, 256, 0, stream>>>(ttcn_w1, ttcn_w2, ttcn_w3,
      ga_qw, ga_kw, ga_vw, ga_ow, tf_in_w, tf_out_w, tf_fw1, tf_fw2, fr);

  ttcn_kernel<<<P_TOT, 256, 0, stream>>>(x, mask, ttcn_b1, ttcn_b2, t_bias,
      frS + 0, frS + 256, frS + 768,
      xp, pmb);

  layer12_kernel<<<BN_, 256, 0, stream>>>(xp, pmb, frS,
      ga_qb, ga_kb, ga_vb, ga_ob, tf_in_b, tf_out_b, tf_ln1g, tf_ln1b,
      tf_fb1, tf_fb2, tf_ln2g, tf_ln2b, xbuf);

  final_kernel<<<B_, 256, 0, stream>>>(xbuf, pmb, q_embed,
                                       cls_in_w, cls_in_b, cls_out_w, cls_out_b,
                                       logit_w, logit_b, (float*)d_out);
}

// Round 6
// 257.180 us; speedup vs baseline: 6.3901x; 1.0390x over previous
//
#include <hip/hip_runtime.h>
#include <hip/hip_bf16.h>
#include <math.h>

// Problem constants
#define B_  8
#define N_  32
#define M_  16
#define LX  32
#define D_  64
#define IN_DIM_ 17
#define TT_ 63
#define H_  4
#define DH_ 16
#define P_TOT 4096          // B*N*M
#define BN_ 256             // B*N
#define FF_ 2048

// Fragment pool layout (slot = one short8/uint4 per lane-group entry)
#define FRAG_TOT 83200
#define OFF_INW  2048
#define OFF_OUTW 3584
#define OFF_FW1  4096
#define OFF_FW2  20480

typedef unsigned short ushort_t;
typedef __attribute__((ext_vector_type(8))) short short8;   // 8 bf16 (4 VGPRs)
typedef __attribute__((ext_vector_type(4))) float floatx4;  // MFMA C/D

#define MFMA16(a,b,c) __builtin_amdgcn_mfma_f32_16x16x32_bf16((a),(b),(c),0,0,0)

__device__ __forceinline__ ushort_t f2bf(float f){          // RNE float->bf16
  unsigned u = __float_as_uint(f);
  u += 0x7FFFu + ((u >> 16) & 1u);
  return (ushort_t)(u >> 16);
}
__device__ __forceinline__ float bf2f(ushort_t h){ return __uint_as_float(((unsigned)h) << 16); }

__device__ __forceinline__ uint4 pack8(const ushort_t* h){
  uint4 u;
  u.x = (unsigned)h[0] | ((unsigned)h[1] << 16);
  u.y = (unsigned)h[2] | ((unsigned)h[3] << 16);
  u.z = (unsigned)h[4] | ((unsigned)h[5] << 16);
  u.w = (unsigned)h[6] | ((unsigned)h[7] << 16);
  return u;
}

// split 8 consecutive floats into hi/lo bf16 short8
__device__ __forceinline__ void split8(const float* r, short8& hi, short8& lo){
  #pragma unroll
  for (int j = 0; j < 8; ++j){
    float v = r[j];
    ushort_t h = f2bf(v);
    ushort_t l2 = f2bf(v - bf2f(h));
    hi[j] = (short)h; lo[j] = (short)l2;
  }
}
// hi-only conversion
__device__ __forceinline__ uint4 cvt8(const float* r){
  ushort_t hh[8];
  #pragma unroll
  for (int j = 0; j < 8; ++j) hh[j] = f2bf(r[j]);
  return pack8(hh);
}

// 3-term split product: (ah+al)(bh+bl) ~= ah*bh + ah*bl + al*bh
__device__ __forceinline__ floatx4 mm3(short8 ah, short8 al, short8 bh, short8 bl, floatx4 c){
  c = MFMA16(ah, bh, c); c = MFMA16(ah, bl, c); c = MFMA16(al, bh, c); return c;
}

__device__ __forceinline__ float dot64(const float* __restrict__ a, const float* __restrict__ w){
  const float4* a4 = (const float4*)a;
  const float4* w4 = (const float4*)w;
  float acc = 0.f;
  #pragma unroll
  for (int k = 0; k < 16; ++k){ float4 x = a4[k], y = w4[k];
    acc += x.x*y.x + x.y*y.y + x.z*y.z + x.w*y.w; }
  return acc;
}
__device__ __forceinline__ float dot16(const float* __restrict__ a, const float* __restrict__ b){
  const float4* a4 = (const float4*)a; const float4* b4 = (const float4*)b;
  float acc = 0.f;
  #pragma unroll
  for (int k = 0; k < 4; ++k){ float4 x = a4[k], y = b4[k];
    acc += x.x*y.x + x.y*y.y + x.z*y.z + x.w*y.w; }
  return acc;
}

// pack A-frags (16 tokens x 64 k) from stride-68 LDS buffer into fragA (hi[128], lo[128])
__device__ __forceinline__ void packA68(const float* buf, short8* fA, int tid){
  if (tid < 128){
    int ln = tid & 63, ks = tid >> 6;
    const float* r = buf + (ln & 15)*68 + ks*32 + ((ln >> 4) & 3)*8;
    short8 hi, lo; split8(r, hi, lo);
    fA[tid] = hi; fA[128 + tid] = lo;
  }
}

// -------------------------------------------------------------------------
// Prep: convert ALL weight matrices to MFMA B-fragment pool (hi at [s], lo at
// [FRAG_TOT+s]). B[k][n]: n = nt*16 + (lane&15), k = ks*32 + quad*8 + j.
// w3 special: (a) columns reordered so tile nt covers i = nt>>2 (constant per
// tile), t = (nt&3)*16 + lane&15; (b) k=63 slot set to 1.0 — carries the
// per-row mask value injected into the h2 A-fragment (epilogue mask via MFMA).
// -------------------------------------------------------------------------
__global__ __launch_bounds__(256) void prep_kernel(
    const float* __restrict__ w1, const float* __restrict__ w2, const float* __restrict__ w3,
    const float* __restrict__ gqw, const float* __restrict__ gkw,
    const float* __restrict__ gvw, const float* __restrict__ gow,
    const float* __restrict__ inw, const float* __restrict__ outw,
    const float* __restrict__ fw1, const float* __restrict__ fw2,
    uint4* __restrict__ fr)
{
  int s = blockIdx.x*256 + threadIdx.x;
  if (s >= FRAG_TOT) return;
  const float* src; int Nr, Kr, KS, rel; int w3seg = 0;
  if (s < 256)      { src = w1; Nr=63;  Kr=17; KS=1; rel = s; }
  else if (s < 768) { src = w2; Nr=63;  Kr=63; KS=2; rel = s-256; }
  else if (s < 9472){ src = w3; Nr=1071;Kr=63; KS=2; rel = s-768; w3seg = 1; }
  else {
    int t = s - 9472, l = t / 36864, r2 = t - l*36864;
    if (r2 < 512)        { src = gqw + l*4096;   Nr=64;  Kr=64;   KS=2;  rel = r2; }
    else if (r2 < 1024)  { src = gkw + l*4096;   Nr=64;  Kr=64;   KS=2;  rel = r2-512; }
    else if (r2 < 1536)  { src = gvw + l*4096;   Nr=64;  Kr=64;   KS=2;  rel = r2-1024; }
    else if (r2 < 2048)  { src = gow + l*4096;   Nr=64;  Kr=64;   KS=2;  rel = r2-1536; }
    else if (r2 < 3584)  { src = inw + l*12288;  Nr=192; Kr=64;   KS=2;  rel = r2-2048; }
    else if (r2 < 4096)  { src = outw + l*4096;  Nr=64;  Kr=64;   KS=2;  rel = r2-3584; }
    else if (r2 < 20480) { src = fw1 + l*131072; Nr=2048;Kr=64;   KS=2;  rel = r2-4096; }
    else                 { src = fw2 + l*131072; Nr=64;  Kr=2048; KS=64; rel = r2-20480; }
  }
  int lane = rel & 63, tmp = rel >> 6;
  int ks = tmp % KS, nt = tmp / KS;
  int kb = ks*32 + ((lane >> 4) & 3)*8;
  int n, validn;
  if (w3seg){
    int i = nt >> 2, tq = nt & 3;
    int t = tq*16 + (lane & 15);
    n = t*17 + i;                         // source row of w3 (c = t*17+i)
    validn = (t < 63);
  } else {
    n = nt*16 + (lane & 15);
    validn = (n < Nr);
  }
  float v[8];
  #pragma unroll
  for (int j = 0; j < 8; ++j){
    v[j] = (validn && (kb + j) < Kr) ? src[n*Kr + kb + j] : 0.f;
    if (w3seg && (kb + j) == 63) v[j] = 1.0f;   // mask-carrier column
  }
  ushort_t hh[8], ll[8];
  #pragma unroll
  for (int j = 0; j < 8; ++j){ hh[j] = f2bf(v[j]); ll[j] = f2bf(v[j] - bf2f(hh[j])); }
  fr[s] = pack8(hh); fr[FRAG_TOT + s] = pack8(ll);
}

// -------------------------------------------------------------------------
// Fused TTCN — bf16 1-term MFMA. Mask baked into GEMM3 via k=63 slot
// (A = mask? -1e8 : 0, B = 1.0), softmax without max-shift (values O(1);
// masked rows exp->0 exactly; all-masked fallback = column mean via xsumv).
// -------------------------------------------------------------------------
__global__ __launch_bounds__(256) void ttcn_kernel(
    const float* __restrict__ x, const int* __restrict__ mask,
    const float* __restrict__ b1, const float* __restrict__ b2,
    const float* __restrict__ tb,
    const short8* __restrict__ w1bhi,
    const short8* __restrict__ w2bhi,
    const short8* __restrict__ w3bhi,
    float* __restrict__ xp, float* __restrict__ pm)
{
  __shared__ __align__(16) char pool[26880];
  float*  xs    = (float*)(pool + 0);        // 32x20 stride
  float*  msv   = (float*)(pool + 2560);     // 32
  float*  xsumv = (float*)(pool + 2688);     // 17 (col sums of x for fallback)
  short8* xfhi  = (short8*)(pool + 2768);    // 128 slots
  float*  h1t   = (float*)(pool + 4816);     // 64x35 (dead after P3)
  short8* h2fhi = (short8*)(pool + 4816);    // alias h1t (P5+)
  float*  colres= (float*)(pool + 8912);     // 17x64 (P6+, alias h1t tail)
  float*  h2t   = (float*)(pool + 13776);    // 64x35
  short8* h1fhi = (short8*)(pool + 22736);   // 256 slots

  const int p = blockIdx.x, tid = threadIdx.x;
  const int lane = tid & 63, wvi = tid >> 6;
  const int nidx = lane & 15, quad = lane >> 4;

  // P0: stage x (stride 20) + mask
  for (int idx = tid; idx < LX*IN_DIM_; idx += 256){
    int l = (idx * 3856) >> 16;             // idx/17 exact for idx<1088
    int i = idx - l*17;
    xs[l*20 + i] = x[p*(LX*IN_DIM_) + idx];
  }
  if (tid < LX) msv[tid] = (float)mask[p*LX + tid];
  __syncthreads();

  // P1: x A-fragments (hi only), K=32 (k>=17 zero-padded); xsumv on spare lanes
  if (tid < 128){
    int mt = tid >> 6;
    int l = mt*16 + nidx;
    float r[8];
    #pragma unroll
    for (int j = 0; j < 8; ++j){
      int k = quad*8 + j;
      r[j] = (k < IN_DIM_) ? xs[l*20 + k] : 0.f;
    }
    ((uint4*)xfhi)[tid] = cvt8(r);
  } else if (tid < 128 + IN_DIM_){
    int i = tid - 128;
    float s = 0.f;
    #pragma unroll
    for (int l = 0; l < LX; ++l) s += xs[l*20 + i];
    xsumv[i] = s;
  }
  __syncthreads();

  // P2: GEMM1  h1 = relu(x @ w1^T + b1)
  {
    short8 axh0 = xfhi[lane], axh1 = xfhi[64 + lane];
    short8 bh = w1bhi[wvi*64 + lane];
    floatx4 a0 = {0.f,0.f,0.f,0.f}, a1 = {0.f,0.f,0.f,0.f};
    a0 = MFMA16(axh0, bh, a0);
    a1 = MFMA16(axh1, bh, a1);
    int t = wvi*16 + nidx;
    float bb = (t < TT_) ? b1[t] : 0.f;
    #pragma unroll
    for (int r = 0; r < 4; ++r){
      h1t[t*35 + quad*4 + r]      = fmaxf(a0[r] + bb, 0.f);
      h1t[t*35 + 16 + quad*4 + r] = fmaxf(a1[r] + bb, 0.f);
    }
  }
  __syncthreads();

  // P3: h1 A-fragments (hi only)
  {
    int mt = tid >> 7, ks = (tid >> 6) & 1;
    int l = mt*16 + nidx;
    float r[8];
    #pragma unroll
    for (int j = 0; j < 8; ++j) r[j] = h1t[(ks*32 + quad*8 + j)*35 + l];
    ((uint4*)h1fhi)[tid] = cvt8(r);
  }
  __syncthreads();

  // P4: GEMM2  h2 = relu(h1 @ w2^T + b2)
  {
    short8 ah00 = h1fhi[lane],       ah01 = h1fhi[64 + lane];
    short8 ah10 = h1fhi[128 + lane], ah11 = h1fhi[192 + lane];
    short8 bh0 = w2bhi[(wvi*2+0)*64 + lane];
    short8 bh1 = w2bhi[(wvi*2+1)*64 + lane];
    floatx4 a0 = {0.f,0.f,0.f,0.f}, a1 = {0.f,0.f,0.f,0.f};
    a0 = MFMA16(ah00, bh0, a0); a0 = MFMA16(ah01, bh1, a0);
    a1 = MFMA16(ah10, bh0, a1); a1 = MFMA16(ah11, bh1, a1);
    int t = wvi*16 + nidx;
    float bb = (t < TT_) ? b2[t] : 0.f;
    #pragma unroll
    for (int r = 0; r < 4; ++r){
      h2t[t*35 + quad*4 + r]      = fmaxf(a0[r] + bb, 0.f);
      h2t[t*35 + 16 + quad*4 + r] = fmaxf(a1[r] + bb, 0.f);
    }
  }
  __syncthreads();

  // P5: h2 A-fragments (hi only), aliasing dead h1t.
  // k=63 slot carries the row mask: masked l -> -1e8 (w3 B[63][*] = 1.0).
  {
    int mt = tid >> 7, ks = (tid >> 6) & 1;
    int l = mt*16 + nidx;
    float r[8];
    #pragma unroll
    for (int j = 0; j < 8; ++j) r[j] = h2t[(ks*32 + quad*8 + j)*35 + l];
    if (ks == 1 && quad == 3) r[7] = (msv[l] == 0.f) ? -1e8f : 0.f;
    ((uint4*)h2fhi)[tid] = cvt8(r);
  }
  __syncthreads();

  // P6: GEMM3 (i-major tiles; mask included in MFMA output) + softmax + contract
  {
    short8 ah00 = h2fhi[lane],       ah01 = h2fhi[64 + lane];
    short8 ah10 = h2fhi[128 + lane], ah11 = h2fhi[192 + lane];
    const int t_out = wvi*16 + nidx;          // constant per lane
    const bool valid = t_out < 63;
    const int rA = quad*4, rB = quad*4 + 16;  // xs row bases
    short8 nbh0 = w3bhi[(wvi*2+0)*64 + lane];
    short8 nbh1 = w3bhi[(wvi*2+1)*64 + lane];
    for (int it = 0; it < 17; ++it){
      short8 bh0 = nbh0, bh1 = nbh1;
      if (it < 16){
        int nt = wvi + it*4 + 4;
        nbh0 = w3bhi[(nt*2+0)*64 + lane];
        nbh1 = w3bhi[(nt*2+1)*64 + lane];
      }
      floatx4 a0 = {0.f,0.f,0.f,0.f}, a1 = {0.f,0.f,0.f,0.f};
      a0 = MFMA16(ah00, bh0, a0); a0 = MFMA16(ah01, bh1, a0);
      a1 = MFMA16(ah10, bh0, a1); a1 = MFMA16(ah11, bh1, a1);

      float den = 0.f, num = 0.f;
      #pragma unroll
      for (int r = 0; r < 4; ++r){
        float e0 = __expf(a0[r]);             // masked rows -> exp(-1e8) = 0
        den += e0; num = fmaf(e0, xs[(rA + r)*20 + it], num);
        float e1 = __expf(a1[r]);
        den += e1; num = fmaf(e1, xs[(rB + r)*20 + it], num);
      }
      den += __shfl_xor(den, 16, 64); den += __shfl_xor(den, 32, 64);
      num += __shfl_xor(num, 16, 64); num += __shfl_xor(num, 32, 64);
      if (quad == 0 && valid){
        float res = (den > 0.f) ? num / den : xsumv[it] * (1.f/32.f);
        colres[it*64 + t_out] = res;
      }
    }
  }
  __syncthreads();

  // P7: h_t[t] = relu(sum_i colres[i][t] + tb[t]); append mask_patch
  if (tid < TT_){
    float acc = 0.f;
    #pragma unroll
    for (int i2 = 0; i2 < IN_DIM_; ++i2) acc += colres[i2*64 + tid];
    xp[p*D_ + tid] = fmaxf(acc + tb[tid], 0.f);
  }
  if (tid == TT_){
    float s = 0.f;
    #pragma unroll
    for (int l = 0; l < LX; ++l) s += msv[l];
    float mp = (s > 0.f) ? 1.f : 0.f;
    xp[p*D_ + TT_] = mp;
    pm[p] = mp;
  }
}

// -------------------------------------------------------------------------
// BOTH transformer layers fused, one block per bn. tbias + pos-enc tables
// precomputed in LDS once (transcendental hoist).
// -------------------------------------------------------------------------
__global__ __launch_bounds__(256) void layer12_kernel(
    const float* __restrict__ xin, const float* __restrict__ pm,
    const short8* __restrict__ frS,
    const float* __restrict__ gqb, const float* __restrict__ gkb,
    const float* __restrict__ gvb, const float* __restrict__ gob,
    const float* __restrict__ inb, const float* __restrict__ outb,
    const float* __restrict__ ln1g, const float* __restrict__ ln1b,
    const float* __restrict__ fb1, const float* __restrict__ fb2,
    const float* __restrict__ ln2g, const float* __restrict__ ln2b,
    float* __restrict__ xout)
{
  __shared__ __align__(16) float xb[16*68];
  __shared__ __align__(16) float xb2[16*68];
  __shared__ __align__(16) float q_[16*68];
  __shared__ __align__(16) float k_[16*68];
  __shared__ __align__(16) float v_[16*68];
  __shared__ __align__(16) float ao[16*68];
  __shared__ __align__(16) float ss[1024];
  __shared__ __align__(16) short8 fragA[256];
  __shared__ __align__(16) float hbuf[4*16*36];
  __shared__ __align__(16) float part[4*16*68];
  __shared__ __align__(16) float pe_t[1024];
  __shared__ float tbt[16];
  __shared__ float pmv[16], mur[16], rvr[16];

  const int bn = blockIdx.x, tid = threadIdx.x;
  const int lane = tid & 63, wvi = tid >> 6;
  const int nidx = lane & 15, quad = lane >> 4;
  const float* xin_p = xin + bn*1024;

  for (int o = tid; o < 1024; o += 256) xb[(o>>6)*68 + (o&63)] = xin_p[o];
  if (tid < 16) pmv[tid] = pm[bn*16 + tid];
  // tables (once)
  for (int o = tid; o < 1024; o += 256){
    int tok = o >> 6, d = o & 63;
    float div = __expf((float)(d & ~1) * (-0.14391156831212793f)); // -ln(1e4)/64
    float arg = (float)tok * div;
    pe_t[o] = (d & 1) ? cosf(arg) : sinf(arg);
  }
  if (tid >= 32 && tid < 48) tbt[tid-32] = logf(expf(-5.0f*(float)(tid-32)) + 1e-12f);
  __syncthreads();

  for (int l = 0; l < 2; ++l){
    const int lbase = 9472 + l*36864;
    const float* gqbL = gqb + l*64;  const float* gkbL = gkb + l*64;
    const float* gvbL = gvb + l*64;  const float* gobL = gob + l*64;
    const float* inbL = inb + l*192; const float* outbL = outb + l*64;
    const float* ln1gL = ln1g + l*64; const float* ln1bL = ln1b + l*64;
    const float* fb1L = fb1 + l*2048; const float* fb2L = fb2 + l*64;
    const float* ln2gL = ln2g + l*64; const float* ln2bL = ln2b + l*64;

    // save layer input for the l==1 residual
    float xres[4];
    #pragma unroll
    for (int kk2 = 0; kk2 < 4; ++kk2){
      int o = tid + kk2*256;
      xres[kk2] = xb[(o>>6)*68 + (o&63)];
    }

    // ---- gattn QKV ----
    packA68(xb, fragA, tid);
    __syncthreads();
    {
      short8 axh0 = fragA[lane], axh1 = fragA[64+lane];
      short8 axl0 = fragA[128+lane], axl1 = fragA[192+lane];
      #pragma unroll
      for (int mat = 0; mat < 3; ++mat){
        int base = lbase + mat*512;
        short8 bh0 = frS[base + (wvi*2+0)*64 + lane];
        short8 bl0 = frS[FRAG_TOT + base + (wvi*2+0)*64 + lane];
        short8 bh1 = frS[base + (wvi*2+1)*64 + lane];
        short8 bl1 = frS[FRAG_TOT + base + (wvi*2+1)*64 + lane];
        floatx4 c = {0.f,0.f,0.f,0.f};
        c = mm3(axh0, axl0, bh0, bl0, c);
        c = mm3(axh1, axl1, bh1, bl1, c);
        int d = wvi*16 + nidx;
        float bb = (mat == 0 ? gqbL : mat == 1 ? gkbL : gvbL)[d];
        float* dst = (mat == 0 ? q_ : mat == 1 ? k_ : v_);
        #pragma unroll
        for (int r = 0; r < 4; ++r) dst[(quad*4+r)*68 + d] = c[r] + bb;
      }
    }
    __syncthreads();
    for (int o = tid; o < 1024; o += 256){
      int h = o >> 8, r = o & 255, qm = r >> 4, km = r & 15;
      float acc = dot16(q_ + qm*68 + h*16, k_ + km*68 + h*16);
      int dd = qm - km; if (dd < 0) dd = -dd;
      acc = acc * 0.25f + tbt[dd];
      if (pmv[km] == 0.f) acc = -1e9f;
      ss[o] = acc;
    }
    __syncthreads();
    if (tid < 64){
      float* row = ss + tid*16;
      float mx = -1e30f;
      #pragma unroll
      for (int j = 0; j < 16; ++j) mx = fmaxf(mx, row[j]);
      float se = 0.f;
      #pragma unroll
      for (int j = 0; j < 16; ++j){ float e = __expf(row[j]-mx); row[j] = e; se += e; }
      float inv = 1.f/se;
      #pragma unroll
      for (int j = 0; j < 16; ++j) row[j] *= inv;
    }
    __syncthreads();
    for (int o = tid; o < 1024; o += 256){
      int m = o >> 6, d = o & 63, h = d >> 4;
      float acc = 0.f;
      #pragma unroll
      for (int km = 0; km < 16; ++km) acc += ss[h*256 + m*16 + km] * v_[km*68 + d];
      ao[m*68 + d] = acc;
    }
    __syncthreads();
    packA68(ao, fragA, tid);
    __syncthreads();
    {
      short8 axh0 = fragA[lane], axh1 = fragA[64+lane];
      short8 axl0 = fragA[128+lane], axl1 = fragA[192+lane];
      int base = lbase + 1536;   // gow
      short8 bh0 = frS[base + (wvi*2+0)*64 + lane];
      short8 bl0 = frS[FRAG_TOT + base + (wvi*2+0)*64 + lane];
      short8 bh1 = frS[base + (wvi*2+1)*64 + lane];
      short8 bl1 = frS[FRAG_TOT + base + (wvi*2+1)*64 + lane];
      floatx4 c = {0.f,0.f,0.f,0.f};
      c = mm3(axh0, axl0, bh0, bl0, c);
      c = mm3(axh1, axl1, bh1, bl1, c);
      int d = wvi*16 + nidx;
      float bb = gobL[d];
      #pragma unroll
      for (int r = 0; r < 4; ++r){
        int tok = quad*4 + r;
        xb[tok*68 + d] += (c[r] + bb) * pmv[tok] + pe_t[tok*64 + d];
      }
    }
    __syncthreads();

    // ---- MHA ----
    packA68(xb, fragA, tid);
    __syncthreads();
    {
      short8 axh0 = fragA[lane], axh1 = fragA[64+lane];
      short8 axl0 = fragA[128+lane], axl1 = fragA[192+lane];
      #pragma unroll
      for (int sel = 0; sel < 3; ++sel){
        int nt = sel*4 + wvi;
        int base = lbase + OFF_INW + nt*128;
        short8 bh0 = frS[base + lane];
        short8 bl0 = frS[FRAG_TOT + base + lane];
        short8 bh1 = frS[base + 64 + lane];
        short8 bl1 = frS[FRAG_TOT + base + 64 + lane];
        floatx4 c = {0.f,0.f,0.f,0.f};
        c = mm3(axh0, axl0, bh0, bl0, c);
        c = mm3(axh1, axl1, bh1, bl1, c);
        int d = wvi*16 + nidx;
        float bb = inbL[nt*16 + nidx];
        float* dst = (sel == 0 ? q_ : sel == 1 ? k_ : v_);
        #pragma unroll
        for (int r = 0; r < 4; ++r) dst[(quad*4+r)*68 + d] = c[r] + bb;
      }
    }
    __syncthreads();
    for (int o = tid; o < 1024; o += 256){
      int h = o >> 8, r = o & 255, qm = r >> 4, km = r & 15;
      ss[o] = 0.25f * dot16(q_ + qm*68 + h*16, k_ + km*68 + h*16);
    }
    __syncthreads();
    if (tid < 64){
      float* row = ss + tid*16;
      float mx = -1e30f;
      #pragma unroll
      for (int j = 0; j < 16; ++j) mx = fmaxf(mx, row[j]);
      float se = 0.f;
      #pragma unroll
      for (int j = 0; j < 16; ++j){ float e = __expf(row[j]-mx); row[j] = e; se += e; }
      float inv = 1.f/se;
      #pragma unroll
      for (int j = 0; j < 16; ++j) row[j] *= inv;
    }
    __syncthreads();
    for (int o = tid; o < 1024; o += 256){
      int m = o >> 6, d = o & 63, h = d >> 4;
      float acc = 0.f;
      #pragma unroll
      for (int km = 0; km < 16; ++km) acc += ss[h*256 + m*16 + km] * v_[km*68 + d];
      ao[m*68 + d] = acc;
    }
    __syncthreads();
    packA68(ao, fragA, tid);
    __syncthreads();
    {
      short8 axh0 = fragA[lane], axh1 = fragA[64+lane];
      short8 axl0 = fragA[128+lane], axl1 = fragA[192+lane];
      int base = lbase + OFF_OUTW;
      short8 bh0 = frS[base + (wvi*2+0)*64 + lane];
      short8 bl0 = frS[FRAG_TOT + base + (wvi*2+0)*64 + lane];
      short8 bh1 = frS[base + (wvi*2+1)*64 + lane];
      short8 bl1 = frS[FRAG_TOT + base + (wvi*2+1)*64 + lane];
      floatx4 c = {0.f,0.f,0.f,0.f};
      c = mm3(axh0, axl0, bh0, bl0, c);
      c = mm3(axh1, axl1, bh1, bl1, c);
      int d = wvi*16 + nidx;
      float bb = outbL[d];
      #pragma unroll
      for (int r = 0; r < 4; ++r) xb[(quad*4+r)*68 + d] += c[r] + bb;
    }
    __syncthreads();

    // ---- LN1 -> xb2 ----
    if (tid < 16){
      const float* row = xb + tid*68;
      float mu = 0.f;
      #pragma unroll
      for (int d = 0; d < 64; ++d) mu += row[d];
      mu *= (1.f/64.f);
      float var = 0.f;
      #pragma unroll
      for (int d = 0; d < 64; ++d){ float t = row[d]-mu; var += t*t; }
      var *= (1.f/64.f);
      mur[tid] = mu; rvr[tid] = rsqrtf(var + 1e-5f);
    }
    __syncthreads();
    for (int o = tid; o < 1024; o += 256){
      int m = o >> 6, d = o & 63;
      xb2[m*68 + d] = (xb[m*68 + d] - mur[m]) * rvr[m] * ln1gL[d] + ln1bL[d];
    }
    __syncthreads();
    packA68(xb2, fragA, tid);
    __syncthreads();

    // ---- FF (2048 hidden): per wave 512 j's, 16 ksteps ----
    {
      const int w = wvi;
      const int f1base = lbase + OFF_FW1, f2base = lbase + OFF_FW2;
      short8 axh0 = fragA[lane],     axh1 = fragA[64 + lane];
      short8 axl0 = fragA[128+lane], axl1 = fragA[192 + lane];
      floatx4 y0 = {0.f,0.f,0.f,0.f}, y1 = y0, y2 = y0, y3 = y0;
      float* hw = hbuf + w*576;

      short8 f1c[8], f1n[8];
      {
        int ntA = w*32;
        #pragma unroll
        for (int t2 = 0; t2 < 2; ++t2){
          int sb = f1base + ((ntA+t2)*2)*64 + lane;
          f1c[t2*4+0] = frS[sb];            f1c[t2*4+1] = frS[FRAG_TOT + sb];
          f1c[t2*4+2] = frS[sb + 64];       f1c[t2*4+3] = frS[FRAG_TOT + sb + 64];
        }
      }
      for (int it = 0; it < 16; ++it){
        int ntA = w*32 + it*2;
        floatx4 hA = {0.f,0.f,0.f,0.f}, hB = hA;
        hA = mm3(axh0, axl0, f1c[0], f1c[1], hA);
        hA = mm3(axh1, axl1, f1c[2], f1c[3], hA);
        hB = mm3(axh0, axl0, f1c[4], f1c[5], hB);
        hB = mm3(axh1, axl1, f1c[6], f1c[7], hB);
        float bbA = fb1L[ntA*16 + nidx], bbB = fb1L[ntA*16 + 16 + nidx];
        #pragma unroll
        for (int r = 0; r < 4; ++r){
          hw[(quad*4+r)*36 + nidx]      = fmaxf(hA[r] + bbA, 0.f);
          hw[(quad*4+r)*36 + 16 + nidx] = fmaxf(hB[r] + bbB, 0.f);
        }
        int kst = w*16 + it;
        short8 f2[8];
        #pragma unroll
        for (int ntd = 0; ntd < 4; ++ntd){
          int sb = f2base + (ntd*64 + kst)*64 + lane;
          f2[ntd*2]   = frS[sb];
          f2[ntd*2+1] = frS[FRAG_TOT + sb];
        }
        if (it < 15){
          int ntN = ntA + 2;
          #pragma unroll
          for (int t2 = 0; t2 < 2; ++t2){
            int sb = f1base + ((ntN+t2)*2)*64 + lane;
            f1n[t2*4+0] = frS[sb];            f1n[t2*4+1] = frS[FRAG_TOT + sb];
            f1n[t2*4+2] = frS[sb + 64];       f1n[t2*4+3] = frS[FRAG_TOT + sb + 64];
          }
        }
        short8 ah, al;
        split8(hw + (lane & 15)*36 + quad*8, ah, al);
        y0 = mm3(ah, al, f2[0], f2[1], y0);
        y1 = mm3(ah, al, f2[2], f2[3], y1);
        y2 = mm3(ah, al, f2[4], f2[5], y2);
        y3 = mm3(ah, al, f2[6], f2[7], y3);
        #pragma unroll
        for (int j = 0; j < 8; ++j) f1c[j] = f1n[j];
      }
      #pragma unroll
      for (int r = 0; r < 4; ++r){
        int row = (quad*4 + r)*68;
        part[w*1088 + row + nidx]      = y0[r];
        part[w*1088 + row + 16 + nidx] = y1[r];
        part[w*1088 + row + 32 + nidx] = y2[r];
        part[w*1088 + row + 48 + nidx] = y3[r];
      }
    }
    __syncthreads();
    for (int o = tid; o < 1024; o += 256){
      int tok = o >> 6, d = o & 63;
      float s = xb2[tok*68 + d] + fb2L[d];
      #pragma unroll
      for (int ww = 0; ww < 4; ++ww) s += part[ww*1088 + tok*68 + d];
      xb[tok*68 + d] = s;
    }
    __syncthreads();
    // ---- LN2 (+ layer-1 residual) ----
    if (tid < 16){
      const float* row = xb + tid*68;
      float mu = 0.f;
      #pragma unroll
      for (int d = 0; d < 64; ++d) mu += row[d];
      mu *= (1.f/64.f);
      float var = 0.f;
      #pragma unroll
      for (int d = 0; d < 64; ++d){ float t = row[d]-mu; var += t*t; }
      var *= (1.f/64.f);
      mur[tid] = mu; rvr[tid] = rsqrtf(var + 1e-5f);
    }
    __syncthreads();
    #pragma unroll
    for (int kk2 = 0; kk2 < 4; ++kk2){
      int o = tid + kk2*256;
      int tok = o >> 6, d = o & 63;
      float vv = (xb[tok*68 + d] - mur[tok]) * rvr[tok] * ln2gL[d] + ln2bL[d];
      if (l == 0) xb[tok*68 + d] = vv;                 // becomes layer-1 input
      else        xout[bn*1024 + o] = vv + xres[kk2];  // layer residual
    }
    __syncthreads();
  }
}

// -------------------------------------------------------------------------
// Classifier head. One block per b. (small; fp32)
// -------------------------------------------------------------------------
__global__ __launch_bounds__(256) void final_kernel(
    const float* __restrict__ xc, const float* __restrict__ pm,
    const float* __restrict__ q_embed,
    const float* __restrict__ cin_w, const float* __restrict__ cin_b,
    const float* __restrict__ cout_w, const float* __restrict__ cout_b,
    const float* __restrict__ logit_w, const float* __restrict__ logit_b,
    float* __restrict__ out)
{
  const int b = blockIdx.x;
  const int tid = threadIdx.x;
  __shared__ __align__(16) float xs[M_ * D_];
  __shared__ float kpmv[M_];
  __shared__ __align__(16) float qv[5 * D_], kv[M_ * D_], vv[M_ * D_];
  __shared__ float sv[H_ * 5 * M_];
  __shared__ __align__(16) float ao[5 * D_], zv[5 * D_];

  for (int o = tid; o < M_ * D_; o += 256) {
    int m = o >> 6, d = o & 63;
    float acc = 0.f;
    #pragma unroll
    for (int n = 0; n < N_; ++n) acc += xc[(((b * N_ + n) * M_ + m) * D_) + d];
    xs[o] = acc * (1.f / 32.f);
  }
  if (tid < M_) {
    float any = 0.f;
    #pragma unroll
    for (int n = 0; n < N_; ++n) any += (pm[(b * N_ + n) * M_ + tid] > 0.f) ? 1.f : 0.f;
    kpmv[tid] = (any > 0.f) ? 0.f : 1.f;
  }
  __syncthreads();

  for (int o = tid; o < 5 * D_; o += 256) {
    int qi = o >> 6, d = o & 63;
    qv[o] = cin_b[d] + dot64(q_embed + qi * D_, cin_w + d * D_);
  }
  for (int o = tid; o < 2 * M_ * D_; o += 256) {
    int sel = o >> 10, r = o & 1023, m = r >> 6, d = r & 63;
    float acc = cin_b[D_ + sel * D_ + d] + dot64(xs + m * D_, cin_w + (D_ + sel * D_ + d) * D_);
    ((sel == 0) ? kv : vv)[r] = acc;
  }
  __syncthreads();

  for (int o = tid; o < H_ * 5 * M_; o += 256) {
    int h = o / 80, r = o % 80, qi = r >> 4, km = r & 15;
    float acc = 0.25f * dot16(qv + qi * D_ + h * DH_, kv + km * D_ + h * DH_);
    if (kpmv[km] != 0.f) acc = -1e9f;
    sv[o] = acc;
  }
  __syncthreads();
  if (tid < H_ * 5) {
    int h = tid / 5, qi = tid % 5;
    float* row = sv + h * 80 + qi * M_;
    float mx = -1e30f;
    #pragma unroll
    for (int km = 0; km < M_; ++km) mx = fmaxf(mx, row[km]);
    float se = 0.f;
    #pragma unroll
    for (int km = 0; km < M_; ++km) { float e = __expf(row[km] - mx); row[km] = e; se += e; }
    float inv = 1.f / se;
    #pragma unroll
    for (int km = 0; km < M_; ++km) row[km] *= inv;
  }
  __syncthreads();
  for (int o = tid; o < 5 * D_; o += 256) {
    int qi = o >> 6, d = o & 63, h = d >> 4;
    float acc = 0.f;
    #pragma unroll
    for (int km = 0; km < M_; ++km) acc += sv[h * 80 + qi * M_ + km] * vv[km * D_ + d];
    ao[o] = acc;
  }
  __syncthreads();
  for (int o = tid; o < 5 * D_; o += 256) {
    int qi = o >> 6, d = o & 63;
    zv[o] = cout_b[d] + dot64(ao + qi * D_, cout_w + d * D_);
  }
  __syncthreads();
  if (tid < 5) {
    float acc = logit_b[0] + dot64(zv + tid * D_, logit_w);
    out[b * 5 + tid] = acc;
  }
}

// -------------------------------------------------------------------------
extern "C" void kernel_launch(void* const* d_in, const int* in_sizes, int n_in,
                              void* d_out, int out_size, void* d_ws, size_t ws_size,
                              hipStream_t stream) {
  const float* x       = (const float*)d_in[0];
  const int*   mask    = (const int*)  d_in[1];
  const float* ttcn_w1 = (const float*)d_in[2];
  const float* ttcn_b1 = (const float*)d_in[3];
  const float* ttcn_w2 = (const float*)d_in[4];
  const float* ttcn_b2 = (const float*)d_in[5];
  const float* ttcn_w3 = (const float*)d_in[6];
  const float* ttcn_b3 = (const float*)d_in[7];   // unused: cancels in softmax
  const float* t_bias  = (const float*)d_in[8];
  const float* ga_qw   = (const float*)d_in[9];
  const float* ga_qb   = (const float*)d_in[10];
  const float* ga_kw   = (const float*)d_in[11];
  const float* ga_kb   = (const float*)d_in[12];
  const float* ga_vw   = (const float*)d_in[13];
  const float* ga_vb   = (const float*)d_in[14];
  const float* ga_ow   = (const float*)d_in[15];
  const float* ga_ob   = (const float*)d_in[16];
  const float* tf_in_w = (const float*)d_in[17];
  const float* tf_in_b = (const float*)d_in[18];
  const float* tf_out_w= (const float*)d_in[19];
  const float* tf_out_b= (const float*)d_in[20];
  const float* tf_ln1g = (const float*)d_in[21];
  const float* tf_ln1b = (const float*)d_in[22];
  const float* tf_ln2g = (const float*)d_in[23];
  const float* tf_ln2b = (const float*)d_in[24];
  const float* tf_fw1  = (const float*)d_in[25];
  const float* tf_fb1  = (const float*)d_in[26];
  const float* tf_fw2  = (const float*)d_in[27];
  const float* tf_fb2  = (const float*)d_in[28];
  const float* q_embed = (const float*)d_in[29];
  const float* cls_in_w  = (const float*)d_in[30];
  const float* cls_in_b  = (const float*)d_in[31];
  const float* cls_out_w = (const float*)d_in[32];
  const float* cls_out_b = (const float*)d_in[33];
  const float* logit_w = (const float*)d_in[34];
  const float* logit_b = (const float*)d_in[35];
  (void)ttcn_b3;

  float* wsf  = (float*)d_ws;
  float* xp   = wsf;                        // 262144 f
  float* pmb  = wsf + P_TOT * D_;           // 4096 f
  float* xbuf = pmb + P_TOT;                // 262144 f
  uint4* fr   = (uint4*)(xbuf + P_TOT * D_);// 2*FRAG_TOT uint4
  const short8* frS = (const short8*)fr;

  prep_kernel<<<325, 256, 0, stream>>>(ttcn_w1, ttcn_w2, ttcn_w3,
      ga_qw, ga_kw, ga_vw, ga_ow, tf_in_w, tf_out_w, tf_fw1, tf_fw2, fr);

  ttcn_kernel<<<P_TOT, 256, 0, stream>>>(x, mask, ttcn_b1, ttcn_b2, t_bias,
      frS + 0, frS + 256, frS + 768,
      xp, pmb);

  layer12_kernel<<<BN_, 256, 0, stream>>>(xp, pmb, frS,
      ga_qb, ga_kb, ga_vb, ga_ob, tf_in_b, tf_out_b, tf_ln1g, tf_ln1b,
      tf_fb1, tf_fb2, tf_ln2g, tf_ln2b, xbuf);

  final_kernel<<<B_, 256, 0, stream>>>(xbuf, pmb, q_embed,
                                       cls_in_w, cls_in_b, cls_out_w, cls_out_b,
                                       logit_w, logit_b, (float*)d_out);
}

// Round 7
// 240.247 us; speedup vs baseline: 6.8404x; 1.0705x over previous
//
#include <hip/hip_runtime.h>
#include <hip/hip_bf16.h>
#include <math.h>

// Problem constants
#define B_  8
#define N_  32
#define M_  16
#define LX  32
#define D_  64
#define IN_DIM_ 17
#define TT_ 63
#define H_  4
#define DH_ 16
#define P_TOT 4096          // B*N*M
#define BN_ 256             // B*N
#define FF_ 2048

// Fragment pool layout (slot = one short8/uint4 per lane-group entry)
#define FRAG_TOT 83200
#define OFF_INW  2048
#define OFF_OUTW 3584
#define OFF_FW1  4096
#define OFF_FW2  20480

typedef unsigned short ushort_t;
typedef __attribute__((ext_vector_type(8))) short short8;   // 8 bf16 (4 VGPRs)
typedef __attribute__((ext_vector_type(4))) float floatx4;  // MFMA C/D

#define MFMA16(a,b,c) __builtin_amdgcn_mfma_f32_16x16x32_bf16((a),(b),(c),0,0,0)

__device__ __forceinline__ float fast_exp2(float x){
#if __has_builtin(__builtin_amdgcn_exp2f)
  return __builtin_amdgcn_exp2f(x);
#else
  return __expf(x * 0.6931471805599453f);
#endif
}
__device__ __forceinline__ float fast_rcp(float x){
#if __has_builtin(__builtin_amdgcn_rcpf)
  return __builtin_amdgcn_rcpf(x);
#else
  return 1.0f / x;
#endif
}

__device__ __forceinline__ ushort_t f2bf(float f){          // RNE float->bf16
  unsigned u = __float_as_uint(f);
  u += 0x7FFFu + ((u >> 16) & 1u);
  return (ushort_t)(u >> 16);
}
__device__ __forceinline__ float bf2f(ushort_t h){ return __uint_as_float(((unsigned)h) << 16); }

__device__ __forceinline__ uint4 pack8(const ushort_t* h){
  uint4 u;
  u.x = (unsigned)h[0] | ((unsigned)h[1] << 16);
  u.y = (unsigned)h[2] | ((unsigned)h[3] << 16);
  u.z = (unsigned)h[4] | ((unsigned)h[5] << 16);
  u.w = (unsigned)h[6] | ((unsigned)h[7] << 16);
  return u;
}

// split 8 consecutive floats into hi/lo bf16 short8
__device__ __forceinline__ void split8(const float* r, short8& hi, short8& lo){
  #pragma unroll
  for (int j = 0; j < 8; ++j){
    float v = r[j];
    ushort_t h = f2bf(v);
    ushort_t l2 = f2bf(v - bf2f(h));
    hi[j] = (short)h; lo[j] = (short)l2;
  }
}
// hi-only conversion -> uint4
__device__ __forceinline__ uint4 cvt8(const float* r){
  ushort_t hh[8];
  #pragma unroll
  for (int j = 0; j < 8; ++j) hh[j] = f2bf(r[j]);
  return pack8(hh);
}
// hi-only conversion -> short8
__device__ __forceinline__ short8 cvt8s(const float* r){
  union { uint4 u4; short8 s8; } cv;
  cv.u4 = cvt8(r);
  return cv.s8;
}

// 3-term split product: (ah+al)(bh+bl) ~= ah*bh + ah*bl + al*bh
__device__ __forceinline__ floatx4 mm3(short8 ah, short8 al, short8 bh, short8 bl, floatx4 c){
  c = MFMA16(ah, bh, c); c = MFMA16(ah, bl, c); c = MFMA16(al, bh, c); return c;
}

__device__ __forceinline__ float dot64(const float* __restrict__ a, const float* __restrict__ w){
  const float4* a4 = (const float4*)a;
  const float4* w4 = (const float4*)w;
  float acc = 0.f;
  #pragma unroll
  for (int k = 0; k < 16; ++k){ float4 x = a4[k], y = w4[k];
    acc += x.x*y.x + x.y*y.y + x.z*y.z + x.w*y.w; }
  return acc;
}
__device__ __forceinline__ float dot16(const float* __restrict__ a, const float* __restrict__ b){
  const float4* a4 = (const float4*)a; const float4* b4 = (const float4*)b;
  float acc = 0.f;
  #pragma unroll
  for (int k = 0; k < 4; ++k){ float4 x = a4[k], y = b4[k];
    acc += x.x*y.x + x.y*y.y + x.z*y.z + x.w*y.w; }
  return acc;
}

// pack A-frags (16 tokens x 64 k) from stride-68 LDS buffer into fragA (hi[128], lo[128])
__device__ __forceinline__ void packA68(const float* buf, short8* fA, int tid){
  if (tid < 128){
    int ln = tid & 63, ks = tid >> 6;
    const float* r = buf + (ln & 15)*68 + ks*32 + ((ln >> 4) & 3)*8;
    short8 hi, lo; split8(r, hi, lo);
    fA[tid] = hi; fA[128 + tid] = lo;
  }
}

// -------------------------------------------------------------------------
// Prep: convert ALL weight matrices to MFMA B-fragment pool (hi at [s], lo at
// [FRAG_TOT+s]; lo only written for attn segments — ttcn + FF consume hi only).
// B[k][n]: n = nt*16 + (lane&15), k = ks*32 + quad*8 + j.
// w3 special: (a) columns reordered so tile nt covers i = nt>>2 (constant per
// tile), t = (nt&3)*16 + lane&15; (b) k=63 slot = 1.0 (mask carrier);
// (c) ALL w3 values scaled by log2(e) so epilogue uses raw v_exp_f32.
// -------------------------------------------------------------------------
__global__ __launch_bounds__(256) void prep_kernel(
    const float* __restrict__ w1, const float* __restrict__ w2, const float* __restrict__ w3,
    const float* __restrict__ gqw, const float* __restrict__ gkw,
    const float* __restrict__ gvw, const float* __restrict__ gow,
    const float* __restrict__ inw, const float* __restrict__ outw,
    const float* __restrict__ fw1, const float* __restrict__ fw2,
    uint4* __restrict__ fr)
{
  int s = blockIdx.x*256 + threadIdx.x;
  if (s >= FRAG_TOT) return;
  const float* src; int Nr, Kr, KS, rel; int w3seg = 0, noLo = 0;
  if (s < 256)      { src = w1; Nr=63;  Kr=17; KS=1; rel = s; noLo = 1; }
  else if (s < 768) { src = w2; Nr=63;  Kr=63; KS=2; rel = s-256; noLo = 1; }
  else if (s < 9472){ src = w3; Nr=1071;Kr=63; KS=2; rel = s-768; w3seg = 1; noLo = 1; }
  else {
    int t = s - 9472, l = t / 36864, r2 = t - l*36864;
    if (r2 < 512)        { src = gqw + l*4096;   Nr=64;  Kr=64;   KS=2;  rel = r2; }
    else if (r2 < 1024)  { src = gkw + l*4096;   Nr=64;  Kr=64;   KS=2;  rel = r2-512; }
    else if (r2 < 1536)  { src = gvw + l*4096;   Nr=64;  Kr=64;   KS=2;  rel = r2-1024; }
    else if (r2 < 2048)  { src = gow + l*4096;   Nr=64;  Kr=64;   KS=2;  rel = r2-1536; }
    else if (r2 < 3584)  { src = inw + l*12288;  Nr=192; Kr=64;   KS=2;  rel = r2-2048; }
    else if (r2 < 4096)  { src = outw + l*4096;  Nr=64;  Kr=64;   KS=2;  rel = r2-3584; }
    else if (r2 < 20480) { src = fw1 + l*131072; Nr=2048;Kr=64;   KS=2;  rel = r2-4096; noLo = 1; }
    else                 { src = fw2 + l*131072; Nr=64;  Kr=2048; KS=64; rel = r2-20480; noLo = 1; }
  }
  int lane = rel & 63, tmp = rel >> 6;
  int ks = tmp % KS, nt = tmp / KS;
  int kb = ks*32 + ((lane >> 4) & 3)*8;
  int n, validn;
  if (w3seg){
    int i = nt >> 2, tq = nt & 3;
    int t = tq*16 + (lane & 15);
    n = t*17 + i;                         // source row of w3 (c = t*17+i)
    validn = (t < 63);
  } else {
    n = nt*16 + (lane & 15);
    validn = (n < Nr);
  }
  float v[8];
  #pragma unroll
  for (int j = 0; j < 8; ++j){
    v[j] = (validn && (kb + j) < Kr) ? src[n*Kr + kb + j] : 0.f;
    if (w3seg){
      if ((kb + j) == 63) v[j] = 1.0f;               // mask-carrier column
      v[j] *= 1.4426950408889634f;                   // log2(e) for exp2 epilogue
    }
  }
  ushort_t hh[8];
  #pragma unroll
  for (int j = 0; j < 8; ++j) hh[j] = f2bf(v[j]);
  fr[s] = pack8(hh);
  if (!noLo){
    ushort_t ll[8];
    #pragma unroll
    for (int j = 0; j < 8; ++j) ll[j] = f2bf(v[j] - bf2f(hh[j]));
    fr[FRAG_TOT + s] = pack8(ll);
  }
}

// -------------------------------------------------------------------------
// Fused TTCN — bf16 1-term MFMA. Mask baked into GEMM3 via k=63 slot;
// w3 pre-scaled by log2e -> epilogue is raw exp2; masked rows exp2 -> 0.
// All-masked fallback = column mean via xsumv.
// -------------------------------------------------------------------------
__global__ __launch_bounds__(256) void ttcn_kernel(
    const float* __restrict__ x, const int* __restrict__ mask,
    const float* __restrict__ b1, const float* __restrict__ b2,
    const float* __restrict__ tb,
    const short8* __restrict__ w1bhi,
    const short8* __restrict__ w2bhi,
    const short8* __restrict__ w3bhi,
    float* __restrict__ xp, float* __restrict__ pm)
{
  __shared__ __align__(16) char pool[26880];
  float*  xs    = (float*)(pool + 0);        // 32x20 stride
  float*  msv   = (float*)(pool + 2560);     // 32
  float*  xsumv = (float*)(pool + 2688);     // 17 (col sums of x for fallback)
  short8* xfhi  = (short8*)(pool + 2768);    // 128 slots
  float*  h1t   = (float*)(pool + 4816);     // 64x35 (dead after P3)
  short8* h2fhi = (short8*)(pool + 4816);    // alias h1t (P5+)
  float*  colres= (float*)(pool + 8912);     // 17x64 (P6+, alias h1t tail)
  float*  h2t   = (float*)(pool + 13776);    // 64x35
  short8* h1fhi = (short8*)(pool + 22736);   // 256 slots

  const int p = blockIdx.x, tid = threadIdx.x;
  const int lane = tid & 63, wvi = tid >> 6;
  const int nidx = lane & 15, quad = lane >> 4;

  // P0: stage x (stride 20) + mask
  for (int idx = tid; idx < LX*IN_DIM_; idx += 256){
    int l = (idx * 3856) >> 16;             // idx/17 exact for idx<1088
    int i = idx - l*17;
    xs[l*20 + i] = x[p*(LX*IN_DIM_) + idx];
  }
  if (tid < LX) msv[tid] = (float)mask[p*LX + tid];
  __syncthreads();

  // P1: x A-fragments (hi only), K=32 (k>=17 zero-padded); xsumv on spare lanes
  if (tid < 128){
    int mt = tid >> 6;
    int l = mt*16 + nidx;
    float r[8];
    #pragma unroll
    for (int j = 0; j < 8; ++j){
      int k = quad*8 + j;
      r[j] = (k < IN_DIM_) ? xs[l*20 + k] : 0.f;
    }
    ((uint4*)xfhi)[tid] = cvt8(r);
  } else if (tid < 128 + IN_DIM_){
    int i = tid - 128;
    float s = 0.f;
    #pragma unroll
    for (int l = 0; l < LX; ++l) s += xs[l*20 + i];
    xsumv[i] = s;
  }
  __syncthreads();

  // P2: GEMM1  h1 = relu(x @ w1^T + b1)
  {
    short8 axh0 = xfhi[lane], axh1 = xfhi[64 + lane];
    short8 bh = w1bhi[wvi*64 + lane];
    floatx4 a0 = {0.f,0.f,0.f,0.f}, a1 = {0.f,0.f,0.f,0.f};
    a0 = MFMA16(axh0, bh, a0);
    a1 = MFMA16(axh1, bh, a1);
    int t = wvi*16 + nidx;
    float bb = (t < TT_) ? b1[t] : 0.f;
    #pragma unroll
    for (int r = 0; r < 4; ++r){
      h1t[t*35 + quad*4 + r]      = fmaxf(a0[r] + bb, 0.f);
      h1t[t*35 + 16 + quad*4 + r] = fmaxf(a1[r] + bb, 0.f);
    }
  }
  __syncthreads();

  // P3: h1 A-fragments (hi only)
  {
    int mt = tid >> 7, ks = (tid >> 6) & 1;
    int l = mt*16 + nidx;
    float r[8];
    #pragma unroll
    for (int j = 0; j < 8; ++j) r[j] = h1t[(ks*32 + quad*8 + j)*35 + l];
    ((uint4*)h1fhi)[tid] = cvt8(r);
  }
  __syncthreads();

  // P4: GEMM2  h2 = relu(h1 @ w2^T + b2)
  {
    short8 ah00 = h1fhi[lane],       ah01 = h1fhi[64 + lane];
    short8 ah10 = h1fhi[128 + lane], ah11 = h1fhi[192 + lane];
    short8 bh0 = w2bhi[(wvi*2+0)*64 + lane];
    short8 bh1 = w2bhi[(wvi*2+1)*64 + lane];
    floatx4 a0 = {0.f,0.f,0.f,0.f}, a1 = {0.f,0.f,0.f,0.f};
    a0 = MFMA16(ah00, bh0, a0); a0 = MFMA16(ah01, bh1, a0);
    a1 = MFMA16(ah10, bh0, a1); a1 = MFMA16(ah11, bh1, a1);
    int t = wvi*16 + nidx;
    float bb = (t < TT_) ? b2[t] : 0.f;
    #pragma unroll
    for (int r = 0; r < 4; ++r){
      h2t[t*35 + quad*4 + r]      = fmaxf(a0[r] + bb, 0.f);
      h2t[t*35 + 16 + quad*4 + r] = fmaxf(a1[r] + bb, 0.f);
    }
  }
  __syncthreads();

  // P5: h2 A-fragments (hi only), aliasing dead h1t.
  // k=63 slot carries the row mask: masked l -> -1e8 (w3 B[63][*] = log2e).
  {
    int mt = tid >> 7, ks = (tid >> 6) & 1;
    int l = mt*16 + nidx;
    float r[8];
    #pragma unroll
    for (int j = 0; j < 8; ++j) r[j] = h2t[(ks*32 + quad*8 + j)*35 + l];
    if (ks == 1 && quad == 3) r[7] = (msv[l] == 0.f) ? -1e8f : 0.f;
    ((uint4*)h2fhi)[tid] = cvt8(r);
  }
  __syncthreads();

  // P6: GEMM3 (i-major tiles; mask + log2e folded into MFMA) + softmax + contract
  {
    short8 ah00 = h2fhi[lane],       ah01 = h2fhi[64 + lane];
    short8 ah10 = h2fhi[128 + lane], ah11 = h2fhi[192 + lane];
    const int t_out = wvi*16 + nidx;          // constant per lane
    const bool valid = t_out < 63;
    const int rA = quad*4, rB = quad*4 + 16;  // xs row bases
    short8 nbh0 = w3bhi[(wvi*2+0)*64 + lane];
    short8 nbh1 = w3bhi[(wvi*2+1)*64 + lane];
    for (int it = 0; it < 17; ++it){
      short8 bh0 = nbh0, bh1 = nbh1;
      if (it < 16){
        int nt = wvi + it*4 + 4;
        nbh0 = w3bhi[(nt*2+0)*64 + lane];
        nbh1 = w3bhi[(nt*2+1)*64 + lane];
      }
      floatx4 a0 = {0.f,0.f,0.f,0.f}, a1 = {0.f,0.f,0.f,0.f};
      a0 = MFMA16(ah00, bh0, a0); a0 = MFMA16(ah01, bh1, a0);
      a1 = MFMA16(ah10, bh0, a1); a1 = MFMA16(ah11, bh1, a1);

      float den0 = 0.f, den1 = 0.f, num0 = 0.f, num1 = 0.f;
      #pragma unroll
      for (int r = 0; r < 4; ++r){
        float e0 = fast_exp2(a0[r]);          // masked rows -> exp2(-1.44e8) = 0
        den0 += e0; num0 = fmaf(e0, xs[(rA + r)*20 + it], num0);
        float e1 = fast_exp2(a1[r]);
        den1 += e1; num1 = fmaf(e1, xs[(rB + r)*20 + it], num1);
      }
      float den = den0 + den1, num = num0 + num1;
      den += __shfl_xor(den, 16, 64); den += __shfl_xor(den, 32, 64);
      num += __shfl_xor(num, 16, 64); num += __shfl_xor(num, 32, 64);
      if (quad == 0 && valid){
        float res = (den > 0.f) ? num * fast_rcp(den) : xsumv[it] * (1.f/32.f);
        colres[it*64 + t_out] = res;
      }
    }
  }
  __syncthreads();

  // P7: h_t[t] = relu(sum_i colres[i][t] + tb[t]); append mask_patch
  if (tid < TT_){
    float acc = 0.f;
    #pragma unroll
    for (int i2 = 0; i2 < IN_DIM_; ++i2) acc += colres[i2*64 + tid];
    xp[p*D_ + tid] = fmaxf(acc + tb[tid], 0.f);
  }
  if (tid == TT_){
    float s = 0.f;
    #pragma unroll
    for (int l = 0; l < LX; ++l) s += msv[l];
    float mp = (s > 0.f) ? 1.f : 0.f;
    xp[p*D_ + TT_] = mp;
    pm[p] = mp;
  }
}

// -------------------------------------------------------------------------
// BOTH transformer layers fused, one block per bn. Attn projections 3-term
// split-bf16 (accuracy); FF pure 1-term bf16 (threshold is bf16-grade).
// tbias + pos-enc tables precomputed in LDS once.
// -------------------------------------------------------------------------
__global__ __launch_bounds__(256) void layer12_kernel(
    const float* __restrict__ xin, const float* __restrict__ pm,
    const short8* __restrict__ frS,
    const float* __restrict__ gqb, const float* __restrict__ gkb,
    const float* __restrict__ gvb, const float* __restrict__ gob,
    const float* __restrict__ inb, const float* __restrict__ outb,
    const float* __restrict__ ln1g, const float* __restrict__ ln1b,
    const float* __restrict__ fb1, const float* __restrict__ fb2,
    const float* __restrict__ ln2g, const float* __restrict__ ln2b,
    float* __restrict__ xout)
{
  __shared__ __align__(16) float xb[16*68];
  __shared__ __align__(16) float xb2[16*68];
  __shared__ __align__(16) float q_[16*68];
  __shared__ __align__(16) float k_[16*68];
  __shared__ __align__(16) float v_[16*68];
  __shared__ __align__(16) float ao[16*68];
  __shared__ __align__(16) float ss[1024];
  __shared__ __align__(16) short8 fragA[256];
  __shared__ __align__(16) float hbuf[4*16*36];
  __shared__ __align__(16) float part[4*16*68];
  __shared__ __align__(16) float pe_t[1024];
  __shared__ float tbt[16];
  __shared__ float pmv[16], mur[16], rvr[16];

  const int bn = blockIdx.x, tid = threadIdx.x;
  const int lane = tid & 63, wvi = tid >> 6;
  const int nidx = lane & 15, quad = lane >> 4;
  const float* xin_p = xin + bn*1024;

  for (int o = tid; o < 1024; o += 256) xb[(o>>6)*68 + (o&63)] = xin_p[o];
  if (tid < 16) pmv[tid] = pm[bn*16 + tid];
  // tables (once)
  for (int o = tid; o < 1024; o += 256){
    int tok = o >> 6, d = o & 63;
    float div = __expf((float)(d & ~1) * (-0.14391156831212793f)); // -ln(1e4)/64
    float arg = (float)tok * div;
    pe_t[o] = (d & 1) ? cosf(arg) : sinf(arg);
  }
  if (tid >= 32 && tid < 48) tbt[tid-32] = logf(expf(-5.0f*(float)(tid-32)) + 1e-12f);
  __syncthreads();

  for (int l = 0; l < 2; ++l){
    const int lbase = 9472 + l*36864;
    const float* gqbL = gqb + l*64;  const float* gkbL = gkb + l*64;
    const float* gvbL = gvb + l*64;  const float* gobL = gob + l*64;
    const float* inbL = inb + l*192; const float* outbL = outb + l*64;
    const float* ln1gL = ln1g + l*64; const float* ln1bL = ln1b + l*64;
    const float* fb1L = fb1 + l*2048; const float* fb2L = fb2 + l*64;
    const float* ln2gL = ln2g + l*64; const float* ln2bL = ln2b + l*64;

    // save layer input for the l==1 residual
    float xres[4];
    #pragma unroll
    for (int kk2 = 0; kk2 < 4; ++kk2){
      int o = tid + kk2*256;
      xres[kk2] = xb[(o>>6)*68 + (o&63)];
    }

    // ---- gattn QKV ----
    packA68(xb, fragA, tid);
    __syncthreads();
    {
      short8 axh0 = fragA[lane], axh1 = fragA[64+lane];
      short8 axl0 = fragA[128+lane], axl1 = fragA[192+lane];
      #pragma unroll
      for (int mat = 0; mat < 3; ++mat){
        int base = lbase + mat*512;
        short8 bh0 = frS[base + (wvi*2+0)*64 + lane];
        short8 bl0 = frS[FRAG_TOT + base + (wvi*2+0)*64 + lane];
        short8 bh1 = frS[base + (wvi*2+1)*64 + lane];
        short8 bl1 = frS[FRAG_TOT + base + (wvi*2+1)*64 + lane];
        floatx4 c = {0.f,0.f,0.f,0.f};
        c = mm3(axh0, axl0, bh0, bl0, c);
        c = mm3(axh1, axl1, bh1, bl1, c);
        int d = wvi*16 + nidx;
        float bb = (mat == 0 ? gqbL : mat == 1 ? gkbL : gvbL)[d];
        float* dst = (mat == 0 ? q_ : mat == 1 ? k_ : v_);
        #pragma unroll
        for (int r = 0; r < 4; ++r) dst[(quad*4+r)*68 + d] = c[r] + bb;
      }
    }
    __syncthreads();
    for (int o = tid; o < 1024; o += 256){
      int h = o >> 8, r = o & 255, qm = r >> 4, km = r & 15;
      float acc = dot16(q_ + qm*68 + h*16, k_ + km*68 + h*16);
      int dd = qm - km; if (dd < 0) dd = -dd;
      acc = acc * 0.25f + tbt[dd];
      if (pmv[km] == 0.f) acc = -1e9f;
      ss[o] = acc;
    }
    __syncthreads();
    if (tid < 64){
      float* row = ss + tid*16;
      float mx = -1e30f;
      #pragma unroll
      for (int j = 0; j < 16; ++j) mx = fmaxf(mx, row[j]);
      float se = 0.f;
      #pragma unroll
      for (int j = 0; j < 16; ++j){ float e = __expf(row[j]-mx); row[j] = e; se += e; }
      float inv = fast_rcp(se);
      #pragma unroll
      for (int j = 0; j < 16; ++j) row[j] *= inv;
    }
    __syncthreads();
    for (int o = tid; o < 1024; o += 256){
      int m = o >> 6, d = o & 63, h = d >> 4;
      float acc = 0.f;
      #pragma unroll
      for (int km = 0; km < 16; ++km) acc += ss[h*256 + m*16 + km] * v_[km*68 + d];
      ao[m*68 + d] = acc;
    }
    __syncthreads();
    packA68(ao, fragA, tid);
    __syncthreads();
    {
      short8 axh0 = fragA[lane], axh1 = fragA[64+lane];
      short8 axl0 = fragA[128+lane], axl1 = fragA[192+lane];
      int base = lbase + 1536;   // gow
      short8 bh0 = frS[base + (wvi*2+0)*64 + lane];
      short8 bl0 = frS[FRAG_TOT + base + (wvi*2+0)*64 + lane];
      short8 bh1 = frS[base + (wvi*2+1)*64 + lane];
      short8 bl1 = frS[FRAG_TOT + base + (wvi*2+1)*64 + lane];
      floatx4 c = {0.f,0.f,0.f,0.f};
      c = mm3(axh0, axl0, bh0, bl0, c);
      c = mm3(axh1, axl1, bh1, bl1, c);
      int d = wvi*16 + nidx;
      float bb = gobL[d];
      #pragma unroll
      for (int r = 0; r < 4; ++r){
        int tok = quad*4 + r;
        xb[tok*68 + d] += (c[r] + bb) * pmv[tok] + pe_t[tok*64 + d];
      }
    }
    __syncthreads();

    // ---- MHA ----
    packA68(xb, fragA, tid);
    __syncthreads();
    {
      short8 axh0 = fragA[lane], axh1 = fragA[64+lane];
      short8 axl0 = fragA[128+lane], axl1 = fragA[192+lane];
      #pragma unroll
      for (int sel = 0; sel < 3; ++sel){
        int nt = sel*4 + wvi;
        int base = lbase + OFF_INW + nt*128;
        short8 bh0 = frS[base + lane];
        short8 bl0 = frS[FRAG_TOT + base + lane];
        short8 bh1 = frS[base + 64 + lane];
        short8 bl1 = frS[FRAG_TOT + base + 64 + lane];
        floatx4 c = {0.f,0.f,0.f,0.f};
        c = mm3(axh0, axl0, bh0, bl0, c);
        c = mm3(axh1, axl1, bh1, bl1, c);
        int d = wvi*16 + nidx;
        float bb = inbL[nt*16 + nidx];
        float* dst = (sel == 0 ? q_ : sel == 1 ? k_ : v_);
        #pragma unroll
        for (int r = 0; r < 4; ++r) dst[(quad*4+r)*68 + d] = c[r] + bb;
      }
    }
    __syncthreads();
    for (int o = tid; o < 1024; o += 256){
      int h = o >> 8, r = o & 255, qm = r >> 4, km = r & 15;
      ss[o] = 0.25f * dot16(q_ + qm*68 + h*16, k_ + km*68 + h*16);
    }
    __syncthreads();
    if (tid < 64){
      float* row = ss + tid*16;
      float mx = -1e30f;
      #pragma unroll
      for (int j = 0; j < 16; ++j) mx = fmaxf(mx, row[j]);
      float se = 0.f;
      #pragma unroll
      for (int j = 0; j < 16; ++j){ float e = __expf(row[j]-mx); row[j] = e; se += e; }
      float inv = fast_rcp(se);
      #pragma unroll
      for (int j = 0; j < 16; ++j) row[j] *= inv;
    }
    __syncthreads();
    for (int o = tid; o < 1024; o += 256){
      int m = o >> 6, d = o & 63, h = d >> 4;
      float acc = 0.f;
      #pragma unroll
      for (int km = 0; km < 16; ++km) acc += ss[h*256 + m*16 + km] * v_[km*68 + d];
      ao[m*68 + d] = acc;
    }
    __syncthreads();
    packA68(ao, fragA, tid);
    __syncthreads();
    {
      short8 axh0 = fragA[lane], axh1 = fragA[64+lane];
      short8 axl0 = fragA[128+lane], axl1 = fragA[192+lane];
      int base = lbase + OFF_OUTW;
      short8 bh0 = frS[base + (wvi*2+0)*64 + lane];
      short8 bl0 = frS[FRAG_TOT + base + (wvi*2+0)*64 + lane];
      short8 bh1 = frS[base + (wvi*2+1)*64 + lane];
      short8 bl1 = frS[FRAG_TOT + base + (wvi*2+1)*64 + lane];
      floatx4 c = {0.f,0.f,0.f,0.f};
      c = mm3(axh0, axl0, bh0, bl0, c);
      c = mm3(axh1, axl1, bh1, bl1, c);
      int d = wvi*16 + nidx;
      float bb = outbL[d];
      #pragma unroll
      for (int r = 0; r < 4; ++r) xb[(quad*4+r)*68 + d] += c[r] + bb;
    }
    __syncthreads();

    // ---- LN1 -> xb2 ----
    if (tid < 16){
      const float* row = xb + tid*68;
      float mu = 0.f;
      #pragma unroll
      for (int d = 0; d < 64; ++d) mu += row[d];
      mu *= (1.f/64.f);
      float var = 0.f;
      #pragma unroll
      for (int d = 0; d < 64; ++d){ float t = row[d]-mu; var += t*t; }
      var *= (1.f/64.f);
      mur[tid] = mu; rvr[tid] = rsqrtf(var + 1e-5f);
    }
    __syncthreads();
    for (int o = tid; o < 1024; o += 256){
      int m = o >> 6, d = o & 63;
      xb2[m*68 + d] = (xb[m*68 + d] - mur[m]) * rvr[m] * ln1gL[d] + ln1bL[d];
    }
    __syncthreads();
    packA68(xb2, fragA, tid);
    __syncthreads();

    // ---- FF (2048 hidden): pure 1-term bf16; per wave 512 j's, 16 ksteps ----
    {
      const int w = wvi;
      const int f1base = lbase + OFF_FW1, f2base = lbase + OFF_FW2;
      short8 axh0 = fragA[lane], axh1 = fragA[64 + lane];
      floatx4 y0 = {0.f,0.f,0.f,0.f}, y1 = y0, y2 = y0, y3 = y0;
      float* hw = hbuf + w*576;

      short8 f1c[4], f1n[4];
      {
        int ntA = w*32;
        #pragma unroll
        for (int t2 = 0; t2 < 2; ++t2){
          int sb = f1base + ((ntA+t2)*2)*64 + lane;
          f1c[t2*2+0] = frS[sb];
          f1c[t2*2+1] = frS[sb + 64];
        }
      }
      for (int it = 0; it < 16; ++it){
        int ntA = w*32 + it*2;
        floatx4 hA = {0.f,0.f,0.f,0.f}, hB = hA;
        hA = MFMA16(axh0, f1c[0], hA); hA = MFMA16(axh1, f1c[1], hA);
        hB = MFMA16(axh0, f1c[2], hB); hB = MFMA16(axh1, f1c[3], hB);
        float bbA = fb1L[ntA*16 + nidx], bbB = fb1L[ntA*16 + 16 + nidx];
        #pragma unroll
        for (int r = 0; r < 4; ++r){
          hw[(quad*4+r)*36 + nidx]      = fmaxf(hA[r] + bbA, 0.f);
          hw[(quad*4+r)*36 + 16 + nidx] = fmaxf(hB[r] + bbB, 0.f);
        }
        int kst = w*16 + it;
        short8 f2[4];
        #pragma unroll
        for (int ntd = 0; ntd < 4; ++ntd)
          f2[ntd] = frS[f2base + (ntd*64 + kst)*64 + lane];
        if (it < 15){
          int ntN = ntA + 2;
          #pragma unroll
          for (int t2 = 0; t2 < 2; ++t2){
            int sb = f1base + ((ntN+t2)*2)*64 + lane;
            f1n[t2*2+0] = frS[sb];
            f1n[t2*2+1] = frS[sb + 64];
          }
        }
        short8 ah = cvt8s(hw + (lane & 15)*36 + quad*8);
        y0 = MFMA16(ah, f2[0], y0);
        y1 = MFMA16(ah, f2[1], y1);
        y2 = MFMA16(ah, f2[2], y2);
        y3 = MFMA16(ah, f2[3], y3);
        #pragma unroll
        for (int j = 0; j < 4; ++j) f1c[j] = f1n[j];
      }
      #pragma unroll
      for (int r = 0; r < 4; ++r){
        int row = (quad*4 + r)*68;
        part[w*1088 + row + nidx]      = y0[r];
        part[w*1088 + row + 16 + nidx] = y1[r];
        part[w*1088 + row + 32 + nidx] = y2[r];
        part[w*1088 + row + 48 + nidx] = y3[r];
      }
    }
    __syncthreads();
    for (int o = tid; o < 1024; o += 256){
      int tok = o >> 6, d = o & 63;
      float s = xb2[tok*68 + d] + fb2L[d];
      #pragma unroll
      for (int ww = 0; ww < 4; ++ww) s += part[ww*1088 + tok*68 + d];
      xb[tok*68 + d] = s;
    }
    __syncthreads();
    // ---- LN2 (+ layer-1 residual) ----
    if (tid < 16){
      const float* row = xb + tid*68;
      float mu = 0.f;
      #pragma unroll
      for (int d = 0; d < 64; ++d) mu += row[d];
      mu *= (1.f/64.f);
      float var = 0.f;
      #pragma unroll
      for (int d = 0; d < 64; ++d){ float t = row[d]-mu; var += t*t; }
      var *= (1.f/64.f);
      mur[tid] = mu; rvr[tid] = rsqrtf(var + 1e-5f);
    }
    __syncthreads();
    #pragma unroll
    for (int kk2 = 0; kk2 < 4; ++kk2){
      int o = tid + kk2*256;
      int tok = o >> 6, d = o & 63;
      float vv = (xb[tok*68 + d] - mur[tok]) * rvr[tok] * ln2gL[d] + ln2bL[d];
      if (l == 0) xb[tok*68 + d] = vv;                 // becomes layer-1 input
      else        xout[bn*1024 + o] = vv + xres[kk2];  // layer residual
    }
    __syncthreads();
  }
}

// -------------------------------------------------------------------------
// Classifier head. One block per b. (small; fp32)
// -------------------------------------------------------------------------
__global__ __launch_bounds__(256) void final_kernel(
    const float* __restrict__ xc, const float* __restrict__ pm,
    const float* __restrict__ q_embed,
    const float* __restrict__ cin_w, const float* __restrict__ cin_b,
    const float* __restrict__ cout_w, const float* __restrict__ cout_b,
    const float* __restrict__ logit_w, const float* __restrict__ logit_b,
    float* __restrict__ out)
{
  const int b = blockIdx.x;
  const int tid = threadIdx.x;
  __shared__ __align__(16) float xs[M_ * D_];
  __shared__ float kpmv[M_];
  __shared__ __align__(16) float qv[5 * D_], kv[M_ * D_], vv[M_ * D_];
  __shared__ float sv[H_ * 5 * M_];
  __shared__ __align__(16) float ao[5 * D_], zv[5 * D_];

  for (int o = tid; o < M_ * D_; o += 256) {
    int m = o >> 6, d = o & 63;
    float acc = 0.f;
    #pragma unroll
    for (int n = 0; n < N_; ++n) acc += xc[(((b * N_ + n) * M_ + m) * D_) + d];
    xs[o] = acc * (1.f / 32.f);
  }
  if (tid < M_) {
    float any = 0.f;
    #pragma unroll
    for (int n = 0; n < N_; ++n) any += (pm[(b * N_ + n) * M_ + tid] > 0.f) ? 1.f : 0.f;
    kpmv[tid] = (any > 0.f) ? 0.f : 1.f;
  }
  __syncthreads();

  for (int o = tid; o < 5 * D_; o += 256) {
    int qi = o >> 6, d = o & 63;
    qv[o] = cin_b[d] + dot64(q_embed + qi * D_, cin_w + d * D_);
  }
  for (int o = tid; o < 2 * M_ * D_; o += 256) {
    int sel = o >> 10, r = o & 1023, m = r >> 6, d = r & 63;
    float acc = cin_b[D_ + sel * D_ + d] + dot64(xs + m * D_, cin_w + (D_ + sel * D_ + d) * D_);
    ((sel == 0) ? kv : vv)[r] = acc;
  }
  __syncthreads();

  for (int o = tid; o < H_ * 5 * M_; o += 256) {
    int h = o / 80, r = o % 80, qi = r >> 4, km = r & 15;
    float acc = 0.25f * dot16(qv + qi * D_ + h * DH_, kv + km * D_ + h * DH_);
    if (kpmv[km] != 0.f) acc = -1e9f;
    sv[o] = acc;
  }
  __syncthreads();
  if (tid < H_ * 5) {
    int h = tid / 5, qi = tid % 5;
    float* row = sv + h * 80 + qi * M_;
    float mx = -1e30f;
    #pragma unroll
    for (int km = 0; km < M_; ++km) mx = fmaxf(mx, row[km]);
    float se = 0.f;
    #pragma unroll
    for (int km = 0; km < M_; ++km) { float e = __expf(row[km] - mx); row[km] = e; se += e; }
    float inv = 1.f / se;
    #pragma unroll
    for (int km = 0; km < M_; ++km) row[km] *= inv;
  }
  __syncthreads();
  for (int o = tid; o < 5 * D_; o += 256) {
    int qi = o >> 6, d = o & 63, h = d >> 4;
    float acc = 0.f;
    #pragma unroll
    for (int km = 0; km < M_; ++km) acc += sv[h * 80 + qi * M_ + km] * vv[km * D_ + d];
    ao[o] = acc;
  }
  __syncthreads();
  for (int o = tid; o < 5 * D_; o += 256) {
    int qi = o >> 6, d = o & 63;
    zv[o] = cout_b[d] + dot64(ao + qi * D_, cout_w + d * D_);
  }
  __syncthreads();
  if (tid < 5) {
    float acc = logit_b[0] + dot64(zv + tid * D_, logit_w);
    out[b * 5 + tid] = acc;
  }
}

// -------------------------------------------------------------------------
extern "C" void kernel_launch(void* const* d_in, const int* in_sizes, int n_in,
                              void* d_out, int out_size, void* d_ws, size_t ws_size,
                              hipStream_t stream) {
  const float* x       = (const float*)d_in[0];
  const int*   mask    = (const int*)  d_in[1];
  const float* ttcn_w1 = (const float*)d_in[2];
  const float* ttcn_b1 = (const float*)d_in[3];
  const float* ttcn_w2 = (const float*)d_in[4];
  const float* ttcn_b2 = (const float*)d_in[5];
  const float* ttcn_w3 = (const float*)d_in[6];
  const float* ttcn_b3 = (const float*)d_in[7];   // unused: cancels in softmax
  const float* t_bias  = (const float*)d_in[8];
  const float* ga_qw   = (const float*)d_in[9];
  const float* ga_qb   = (const float*)d_in[10];
  const float* ga_kw   = (const float*)d_in[11];
  const float* ga_kb   = (const float*)d_in[12];
  const float* ga_vw   = (const float*)d_in[13];
  const float* ga_vb   = (const float*)d_in[14];
  const float* ga_ow   = (const float*)d_in[15];
  const float* ga_ob   = (const float*)d_in[16];
  const float* tf_in_w = (const float*)d_in[17];
  const float* tf_in_b = (const float*)d_in[18];
  const float* tf_out_w= (const float*)d_in[19];
  const float* tf_out_b= (const float*)d_in[20];
  const float* tf_ln1g = (const float*)d_in[21];
  const float* tf_ln1b = (const float*)d_in[22];
  const float* tf_ln2g = (const float*)d_in[23];
  const float* tf_ln2b = (const float*)d_in[24];
  const float* tf_fw1  = (const float*)d_in[25];
  const float* tf_fb1  = (const float*)d_in[26];
  const float* tf_fw2  = (const float*)d_in[27];
  const float* tf_fb2  = (const float*)d_in[28];
  const float* q_embed = (const float*)d_in[29];
  const float* cls_in_w  = (const float*)d_in[30];
  const float* cls_in_b  = (const float*)d_in[31];
  const float* cls_out_w = (const float*)d_in[32];
  const float* cls_out_b = (const float*)d_in[33];
  const float* logit_w = (const float*)d_in[34];
  const float* logit_b = (const float*)d_in[35];
  (void)ttcn_b3;

  float* wsf  = (float*)d_ws;
  float* xp   = wsf;                        // 262144 f
  float* pmb  = wsf + P_TOT * D_;           // 4096 f
  float* xbuf = pmb + P_TOT;                // 262144 f
  uint4* fr   = (uint4*)(xbuf + P_TOT * D_);// 2*FRAG_TOT uint4
  const short8* frS = (const short8*)fr;

  prep_kernel<<<325, 256, 0, stream>>>(ttcn_w1, ttcn_w2, ttcn_w3,
      ga_qw, ga_kw, ga_vw, ga_ow, tf_in_w, tf_out_w, tf_fw1, tf_fw2, fr);

  ttcn_kernel<<<P_TOT, 256, 0, stream>>>(x, mask, ttcn_b1, ttcn_b2, t_bias,
      frS + 0, frS + 256, frS + 768,
      xp, pmb);

  layer12_kernel<<<BN_, 256, 0, stream>>>(xp, pmb, frS,
      ga_qb, ga_kb, ga_vb, ga_ob, tf_in_b, tf_out_b, tf_ln1g, tf_ln1b,
      tf_fb1, tf_fb2, tf_ln2g, tf_ln2b, xbuf);

  final_kernel<<<B_, 256, 0, stream>>>(xbuf, pmb, q_embed,
                                       cls_in_w, cls_in_b, cls_out_w, cls_out_b,
                                       logit_w, logit_b, (float*)d_out);
}

// Round 8
// 235.279 us; speedup vs baseline: 6.9849x; 1.0211x over previous
//
#include <hip/hip_runtime.h>
#include <hip/hip_bf16.h>
#include <math.h>

// Problem constants
#define B_  8
#define N_  32
#define M_  16
#define LX  32
#define D_  64
#define IN_DIM_ 17
#define TT_ 63
#define H_  4
#define DH_ 16
#define P_TOT 4096          // B*N*M
#define BN_ 256             // B*N
#define FF_ 2048

// Fragment pool layout (slot = one short8/uint4 per lane-group entry)
#define FRAG_TOT 83200
#define OFF_INW  2048
#define OFF_OUTW 3584
#define OFF_FW1  4096
#define OFF_FW2  20480

typedef unsigned short ushort_t;
typedef __attribute__((ext_vector_type(8))) short short8;   // 8 bf16 (4 VGPRs)
typedef __attribute__((ext_vector_type(4))) float floatx4;  // MFMA C/D

#define MFMA16(a,b,c) __builtin_amdgcn_mfma_f32_16x16x32_bf16((a),(b),(c),0,0,0)

__device__ __forceinline__ float fast_exp2(float x){
#if __has_builtin(__builtin_amdgcn_exp2f)
  return __builtin_amdgcn_exp2f(x);
#else
  return __expf(x * 0.6931471805599453f);
#endif
}
__device__ __forceinline__ float fast_rcp(float x){
#if __has_builtin(__builtin_amdgcn_rcpf)
  return __builtin_amdgcn_rcpf(x);
#else
  return 1.0f / x;
#endif
}

__device__ __forceinline__ ushort_t f2bf(float f){          // RNE float->bf16
  unsigned u = __float_as_uint(f);
  u += 0x7FFFu + ((u >> 16) & 1u);
  return (ushort_t)(u >> 16);
}
__device__ __forceinline__ float bf2f(ushort_t h){ return __uint_as_float(((unsigned)h) << 16); }

__device__ __forceinline__ uint4 pack8(const ushort_t* h){
  uint4 u;
  u.x = (unsigned)h[0] | ((unsigned)h[1] << 16);
  u.y = (unsigned)h[2] | ((unsigned)h[3] << 16);
  u.z = (unsigned)h[4] | ((unsigned)h[5] << 16);
  u.w = (unsigned)h[6] | ((unsigned)h[7] << 16);
  return u;
}

// split 8 consecutive floats into hi/lo bf16 short8
__device__ __forceinline__ void split8(const float* r, short8& hi, short8& lo){
  #pragma unroll
  for (int j = 0; j < 8; ++j){
    float v = r[j];
    ushort_t h = f2bf(v);
    ushort_t l2 = f2bf(v - bf2f(h));
    hi[j] = (short)h; lo[j] = (short)l2;
  }
}
// hi-only conversion -> uint4
__device__ __forceinline__ uint4 cvt8(const float* r){
  ushort_t hh[8];
  #pragma unroll
  for (int j = 0; j < 8; ++j) hh[j] = f2bf(r[j]);
  return pack8(hh);
}
// hi-only conversion -> short8
__device__ __forceinline__ short8 cvt8s(const float* r){
  union { uint4 u4; short8 s8; } cv;
  cv.u4 = cvt8(r);
  return cv.s8;
}

// 3-term split product: (ah+al)(bh+bl) ~= ah*bh + ah*bl + al*bh
__device__ __forceinline__ floatx4 mm3(short8 ah, short8 al, short8 bh, short8 bl, floatx4 c){
  c = MFMA16(ah, bh, c); c = MFMA16(ah, bl, c); c = MFMA16(al, bh, c); return c;
}

__device__ __forceinline__ float dot64(const float* __restrict__ a, const float* __restrict__ w){
  const float4* a4 = (const float4*)a;
  const float4* w4 = (const float4*)w;
  float acc = 0.f;
  #pragma unroll
  for (int k = 0; k < 16; ++k){ float4 x = a4[k], y = w4[k];
    acc += x.x*y.x + x.y*y.y + x.z*y.z + x.w*y.w; }
  return acc;
}
__device__ __forceinline__ float dot16(const float* __restrict__ a, const float* __restrict__ b){
  const float4* a4 = (const float4*)a; const float4* b4 = (const float4*)b;
  float acc = 0.f;
  #pragma unroll
  for (int k = 0; k < 4; ++k){ float4 x = a4[k], y = b4[k];
    acc += x.x*y.x + x.y*y.y + x.z*y.z + x.w*y.w; }
  return acc;
}

// pack A-frags (16 tokens x 64 k) from stride-68 LDS buffer into fragA (hi[128], lo[128])
__device__ __forceinline__ void packA68(const float* buf, short8* fA, int tid){
  if (tid < 128){
    int ln = tid & 63, ks = tid >> 6;
    const float* r = buf + (ln & 15)*68 + ks*32 + ((ln >> 4) & 3)*8;
    short8 hi, lo; split8(r, hi, lo);
    fA[tid] = hi; fA[128 + tid] = lo;
  }
}

// -------------------------------------------------------------------------
// Prep: convert ALL weight matrices to MFMA B-fragment pool (hi at [s], lo at
// [FRAG_TOT+s]; lo only written for attn segments — ttcn + FF consume hi only).
// B[k][n]: n = nt*16 + (lane&15), k = ks*32 + quad*8 + j.
// w3 special: (a) columns reordered so tile nt covers i = nt>>2 (constant per
// tile), t = (nt&3)*16 + lane&15; (b) k=63 slot = 1.0 (mask carrier);
// (c) ALL w3 values scaled by log2(e) so epilogue uses raw v_exp_f32.
// -------------------------------------------------------------------------
__global__ __launch_bounds__(256) void prep_kernel(
    const float* __restrict__ w1, const float* __restrict__ w2, const float* __restrict__ w3,
    const float* __restrict__ gqw, const float* __restrict__ gkw,
    const float* __restrict__ gvw, const float* __restrict__ gow,
    const float* __restrict__ inw, const float* __restrict__ outw,
    const float* __restrict__ fw1, const float* __restrict__ fw2,
    uint4* __restrict__ fr)
{
  int s = blockIdx.x*256 + threadIdx.x;
  if (s >= FRAG_TOT) return;
  const float* src; int Nr, Kr, KS, rel; int w3seg = 0, noLo = 0;
  if (s < 256)      { src = w1; Nr=63;  Kr=17; KS=1; rel = s; noLo = 1; }
  else if (s < 768) { src = w2; Nr=63;  Kr=63; KS=2; rel = s-256; noLo = 1; }
  else if (s < 9472){ src = w3; Nr=1071;Kr=63; KS=2; rel = s-768; w3seg = 1; noLo = 1; }
  else {
    int t = s - 9472, l = t / 36864, r2 = t - l*36864;
    if (r2 < 512)        { src = gqw + l*4096;   Nr=64;  Kr=64;   KS=2;  rel = r2; }
    else if (r2 < 1024)  { src = gkw + l*4096;   Nr=64;  Kr=64;   KS=2;  rel = r2-512; }
    else if (r2 < 1536)  { src = gvw + l*4096;   Nr=64;  Kr=64;   KS=2;  rel = r2-1024; }
    else if (r2 < 2048)  { src = gow + l*4096;   Nr=64;  Kr=64;   KS=2;  rel = r2-1536; }
    else if (r2 < 3584)  { src = inw + l*12288;  Nr=192; Kr=64;   KS=2;  rel = r2-2048; }
    else if (r2 < 4096)  { src = outw + l*4096;  Nr=64;  Kr=64;   KS=2;  rel = r2-3584; }
    else if (r2 < 20480) { src = fw1 + l*131072; Nr=2048;Kr=64;   KS=2;  rel = r2-4096; noLo = 1; }
    else                 { src = fw2 + l*131072; Nr=64;  Kr=2048; KS=64; rel = r2-20480; noLo = 1; }
  }
  int lane = rel & 63, tmp = rel >> 6;
  int ks = tmp % KS, nt = tmp / KS;
  int kb = ks*32 + ((lane >> 4) & 3)*8;
  int n, validn;
  if (w3seg){
    int i = nt >> 2, tq = nt & 3;
    int t = tq*16 + (lane & 15);
    n = t*17 + i;                         // source row of w3 (c = t*17+i)
    validn = (t < 63);
  } else {
    n = nt*16 + (lane & 15);
    validn = (n < Nr);
  }
  float v[8];
  #pragma unroll
  for (int j = 0; j < 8; ++j){
    v[j] = (validn && (kb + j) < Kr) ? src[n*Kr + kb + j] : 0.f;
    if (w3seg){
      if ((kb + j) == 63) v[j] = 1.0f;               // mask-carrier column
      v[j] *= 1.4426950408889634f;                   // log2(e) for exp2 epilogue
    }
  }
  ushort_t hh[8];
  #pragma unroll
  for (int j = 0; j < 8; ++j) hh[j] = f2bf(v[j]);
  fr[s] = pack8(hh);
  if (!noLo){
    ushort_t ll[8];
    #pragma unroll
    for (int j = 0; j < 8; ++j) ll[j] = f2bf(v[j] - bf2f(hh[j]));
    fr[FRAG_TOT + s] = pack8(ll);
  }
}

// -------------------------------------------------------------------------
// Fused TTCN — bf16 1-term MFMA. Mask baked into GEMM3 via k=63 slot;
// w3 pre-scaled by log2e -> epilogue is raw exp2; masked rows exp2 -> 0.
// All-masked fallback = column mean via xsumv.
// -------------------------------------------------------------------------
__global__ __launch_bounds__(256) void ttcn_kernel(
    const float* __restrict__ x, const int* __restrict__ mask,
    const float* __restrict__ b1, const float* __restrict__ b2,
    const float* __restrict__ tb,
    const short8* __restrict__ w1bhi,
    const short8* __restrict__ w2bhi,
    const short8* __restrict__ w3bhi,
    float* __restrict__ xp, float* __restrict__ pm)
{
  __shared__ __align__(16) char pool[26880];
  float*  xs    = (float*)(pool + 0);        // 32x20 stride
  float*  msv   = (float*)(pool + 2560);     // 32
  float*  xsumv = (float*)(pool + 2688);     // 17 (col sums of x for fallback)
  short8* xfhi  = (short8*)(pool + 2768);    // 128 slots
  float*  h1t   = (float*)(pool + 4816);     // 64x35 (dead after P3)
  short8* h2fhi = (short8*)(pool + 4816);    // alias h1t (P5+)
  float*  colres= (float*)(pool + 8912);     // 17x64 (P6+, alias h1t tail)
  float*  h2t   = (float*)(pool + 13776);    // 64x35
  short8* h1fhi = (short8*)(pool + 22736);   // 256 slots

  const int p = blockIdx.x, tid = threadIdx.x;
  const int lane = tid & 63, wvi = tid >> 6;
  const int nidx = lane & 15, quad = lane >> 4;

  // P0: stage x (stride 20) + mask
  for (int idx = tid; idx < LX*IN_DIM_; idx += 256){
    int l = (idx * 3856) >> 16;             // idx/17 exact for idx<1088
    int i = idx - l*17;
    xs[l*20 + i] = x[p*(LX*IN_DIM_) + idx];
  }
  if (tid < LX) msv[tid] = (float)mask[p*LX + tid];
  __syncthreads();

  // P1: x A-fragments (hi only), K=32 (k>=17 zero-padded); xsumv on spare lanes
  if (tid < 128){
    int mt = tid >> 6;
    int l = mt*16 + nidx;
    float r[8];
    #pragma unroll
    for (int j = 0; j < 8; ++j){
      int k = quad*8 + j;
      r[j] = (k < IN_DIM_) ? xs[l*20 + k] : 0.f;
    }
    ((uint4*)xfhi)[tid] = cvt8(r);
  } else if (tid < 128 + IN_DIM_){
    int i = tid - 128;
    float s = 0.f;
    #pragma unroll
    for (int l = 0; l < LX; ++l) s += xs[l*20 + i];
    xsumv[i] = s;
  }
  __syncthreads();

  // P2: GEMM1  h1 = relu(x @ w1^T + b1)
  {
    short8 axh0 = xfhi[lane], axh1 = xfhi[64 + lane];
    short8 bh = w1bhi[wvi*64 + lane];
    floatx4 a0 = {0.f,0.f,0.f,0.f}, a1 = {0.f,0.f,0.f,0.f};
    a0 = MFMA16(axh0, bh, a0);
    a1 = MFMA16(axh1, bh, a1);
    int t = wvi*16 + nidx;
    float bb = (t < TT_) ? b1[t] : 0.f;
    #pragma unroll
    for (int r = 0; r < 4; ++r){
      h1t[t*35 + quad*4 + r]      = fmaxf(a0[r] + bb, 0.f);
      h1t[t*35 + 16 + quad*4 + r] = fmaxf(a1[r] + bb, 0.f);
    }
  }
  __syncthreads();

  // P3: h1 A-fragments (hi only)
  {
    int mt = tid >> 7, ks = (tid >> 6) & 1;
    int l = mt*16 + nidx;
    float r[8];
    #pragma unroll
    for (int j = 0; j < 8; ++j) r[j] = h1t[(ks*32 + quad*8 + j)*35 + l];
    ((uint4*)h1fhi)[tid] = cvt8(r);
  }
  __syncthreads();

  // P4: GEMM2  h2 = relu(h1 @ w2^T + b2)
  {
    short8 ah00 = h1fhi[lane],       ah01 = h1fhi[64 + lane];
    short8 ah10 = h1fhi[128 + lane], ah11 = h1fhi[192 + lane];
    short8 bh0 = w2bhi[(wvi*2+0)*64 + lane];
    short8 bh1 = w2bhi[(wvi*2+1)*64 + lane];
    floatx4 a0 = {0.f,0.f,0.f,0.f}, a1 = {0.f,0.f,0.f,0.f};
    a0 = MFMA16(ah00, bh0, a0); a0 = MFMA16(ah01, bh1, a0);
    a1 = MFMA16(ah10, bh0, a1); a1 = MFMA16(ah11, bh1, a1);
    int t = wvi*16 + nidx;
    float bb = (t < TT_) ? b2[t] : 0.f;
    #pragma unroll
    for (int r = 0; r < 4; ++r){
      h2t[t*35 + quad*4 + r]      = fmaxf(a0[r] + bb, 0.f);
      h2t[t*35 + 16 + quad*4 + r] = fmaxf(a1[r] + bb, 0.f);
    }
  }
  __syncthreads();

  // P5: h2 A-fragments (hi only), aliasing dead h1t.
  // k=63 slot carries the row mask: masked l -> -1e8 (w3 B[63][*] = log2e).
  {
    int mt = tid >> 7, ks = (tid >> 6) & 1;
    int l = mt*16 + nidx;
    float r[8];
    #pragma unroll
    for (int j = 0; j < 8; ++j) r[j] = h2t[(ks*32 + quad*8 + j)*35 + l];
    if (ks == 1 && quad == 3) r[7] = (msv[l] == 0.f) ? -1e8f : 0.f;
    ((uint4*)h2fhi)[tid] = cvt8(r);
  }
  __syncthreads();

  // P6: GEMM3 (i-major tiles; mask + log2e folded into MFMA) + softmax + contract
  {
    short8 ah00 = h2fhi[lane],       ah01 = h2fhi[64 + lane];
    short8 ah10 = h2fhi[128 + lane], ah11 = h2fhi[192 + lane];
    const int t_out = wvi*16 + nidx;          // constant per lane
    const bool valid = t_out < 63;
    const int rA = quad*4, rB = quad*4 + 16;  // xs row bases
    short8 nbh0 = w3bhi[(wvi*2+0)*64 + lane];
    short8 nbh1 = w3bhi[(wvi*2+1)*64 + lane];
    for (int it = 0; it < 17; ++it){
      short8 bh0 = nbh0, bh1 = nbh1;
      if (it < 16){
        int nt = wvi + it*4 + 4;
        nbh0 = w3bhi[(nt*2+0)*64 + lane];
        nbh1 = w3bhi[(nt*2+1)*64 + lane];
      }
      floatx4 a0 = {0.f,0.f,0.f,0.f}, a1 = {0.f,0.f,0.f,0.f};
      a0 = MFMA16(ah00, bh0, a0); a0 = MFMA16(ah01, bh1, a0);
      a1 = MFMA16(ah10, bh0, a1); a1 = MFMA16(ah11, bh1, a1);

      float den0 = 0.f, den1 = 0.f, num0 = 0.f, num1 = 0.f;
      #pragma unroll
      for (int r = 0; r < 4; ++r){
        float e0 = fast_exp2(a0[r]);          // masked rows -> exp2(-1.44e8) = 0
        den0 += e0; num0 = fmaf(e0, xs[(rA + r)*20 + it], num0);
        float e1 = fast_exp2(a1[r]);
        den1 += e1; num1 = fmaf(e1, xs[(rB + r)*20 + it], num1);
      }
      float den = den0 + den1, num = num0 + num1;
      den += __shfl_xor(den, 16, 64); den += __shfl_xor(den, 32, 64);
      num += __shfl_xor(num, 16, 64); num += __shfl_xor(num, 32, 64);
      if (quad == 0 && valid){
        float res = (den > 0.f) ? num * fast_rcp(den) : xsumv[it] * (1.f/32.f);
        colres[it*64 + t_out] = res;
      }
    }
  }
  __syncthreads();

  // P7: h_t[t] = relu(sum_i colres[i][t] + tb[t]); append mask_patch
  if (tid < TT_){
    float acc = 0.f;
    #pragma unroll
    for (int i2 = 0; i2 < IN_DIM_; ++i2) acc += colres[i2*64 + tid];
    xp[p*D_ + tid] = fmaxf(acc + tb[tid], 0.f);
  }
  if (tid == TT_){
    float s = 0.f;
    #pragma unroll
    for (int l = 0; l < LX; ++l) s += msv[l];
    float mp = (s > 0.f) ? 1.f : 0.f;
    xp[p*D_ + TT_] = mp;
    pm[p] = mp;
  }
}

// -------------------------------------------------------------------------
// BOTH transformer layers fused, one block per bn (= 1 wave/SIMD: zero TLP,
// so B-frags are register-prefetched PHASES ahead of use to build ILP).
// Merged score+softmax phases (all 256 threads, shfl-group reductions).
// -------------------------------------------------------------------------
__global__ __launch_bounds__(256) void layer12_kernel(
    const float* __restrict__ xin, const float* __restrict__ pm,
    const short8* __restrict__ frS,
    const float* __restrict__ gqb, const float* __restrict__ gkb,
    const float* __restrict__ gvb, const float* __restrict__ gob,
    const float* __restrict__ inb, const float* __restrict__ outb,
    const float* __restrict__ ln1g, const float* __restrict__ ln1b,
    const float* __restrict__ fb1, const float* __restrict__ fb2,
    const float* __restrict__ ln2g, const float* __restrict__ ln2b,
    float* __restrict__ xout)
{
  __shared__ __align__(16) float xb[16*68];
  __shared__ __align__(16) float xb2[16*68];
  __shared__ __align__(16) float q_[16*68];
  __shared__ __align__(16) float k_[16*68];
  __shared__ __align__(16) float v_[16*68];
  __shared__ __align__(16) float ao[16*68];
  __shared__ __align__(16) float ss[1024];
  __shared__ __align__(16) short8 fragA[256];
  __shared__ __align__(16) float hbuf[4*16*36];
  __shared__ __align__(16) float part[4*16*68];
  __shared__ __align__(16) float pe_t[1024];
  __shared__ float tbt[16];
  __shared__ float pmv[16], mur[16], rvr[16];

  const int bn = blockIdx.x, tid = threadIdx.x;
  const int lane = tid & 63, wvi = tid >> 6;
  const int nidx = lane & 15, quad = lane >> 4;
  const float* xin_p = xin + bn*1024;

  for (int o = tid; o < 1024; o += 256) xb[(o>>6)*68 + (o&63)] = xin_p[o];
  if (tid < 16) pmv[tid] = pm[bn*16 + tid];
  // tables (once)
  for (int o = tid; o < 1024; o += 256){
    int tok = o >> 6, d = o & 63;
    float div = __expf((float)(d & ~1) * (-0.14391156831212793f)); // -ln(1e4)/64
    float arg = (float)tok * div;
    pe_t[o] = (d & 1) ? cosf(arg) : sinf(arg);
  }
  if (tid >= 32 && tid < 48) tbt[tid-32] = logf(expf(-5.0f*(float)(tid-32)) + 1e-12f);
  __syncthreads();

  for (int l = 0; l < 2; ++l){
    const int lbase = 9472 + l*36864;
    const float* gqbL = gqb + l*64;  const float* gkbL = gkb + l*64;
    const float* gvbL = gvb + l*64;  const float* gobL = gob + l*64;
    const float* inbL = inb + l*192; const float* outbL = outb + l*64;
    const float* ln1gL = ln1g + l*64; const float* ln1bL = ln1b + l*64;
    const float* fb1L = fb1 + l*2048; const float* fb2L = fb2 + l*64;
    const float* ln2gL = ln2g + l*64; const float* ln2bL = ln2b + l*64;

    // save layer input for the l==1 residual
    float xres[4];
    #pragma unroll
    for (int kk2 = 0; kk2 < 4; ++kk2){
      int o = tid + kk2*256;
      xres[kk2] = xb[(o>>6)*68 + (o&63)];
    }

    // ================= PREFETCH WAVE 1: QKV(12) + gattn-out(4) + MHA-in(12)
    short8 gb[3][4], ob4[4], mb[3][4];
    #pragma unroll
    for (int mat = 0; mat < 3; ++mat){
      int base = lbase + mat*512;
      gb[mat][0] = frS[base + (wvi*2+0)*64 + lane];
      gb[mat][1] = frS[FRAG_TOT + base + (wvi*2+0)*64 + lane];
      gb[mat][2] = frS[base + (wvi*2+1)*64 + lane];
      gb[mat][3] = frS[FRAG_TOT + base + (wvi*2+1)*64 + lane];
    }
    {
      int base = lbase + 1536;   // gow
      ob4[0] = frS[base + (wvi*2+0)*64 + lane];
      ob4[1] = frS[FRAG_TOT + base + (wvi*2+0)*64 + lane];
      ob4[2] = frS[base + (wvi*2+1)*64 + lane];
      ob4[3] = frS[FRAG_TOT + base + (wvi*2+1)*64 + lane];
    }
    #pragma unroll
    for (int sel = 0; sel < 3; ++sel){
      int base = lbase + OFF_INW + (sel*4 + wvi)*128;
      mb[sel][0] = frS[base + lane];
      mb[sel][1] = frS[FRAG_TOT + base + lane];
      mb[sel][2] = frS[base + 64 + lane];
      mb[sel][3] = frS[FRAG_TOT + base + 64 + lane];
    }

    // ---- gattn QKV ----
    packA68(xb, fragA, tid);
    __syncthreads();
    {
      short8 axh0 = fragA[lane], axh1 = fragA[64+lane];
      short8 axl0 = fragA[128+lane], axl1 = fragA[192+lane];
      #pragma unroll
      for (int mat = 0; mat < 3; ++mat){
        floatx4 c = {0.f,0.f,0.f,0.f};
        c = mm3(axh0, axl0, gb[mat][0], gb[mat][1], c);
        c = mm3(axh1, axl1, gb[mat][2], gb[mat][3], c);
        int d = wvi*16 + nidx;
        float bb = (mat == 0 ? gqbL : mat == 1 ? gkbL : gvbL)[d];
        float* dst = (mat == 0 ? q_ : mat == 1 ? k_ : v_);
        #pragma unroll
        for (int r = 0; r < 4; ++r) dst[(quad*4+r)*68 + d] = c[r] + bb;
      }
    }
    __syncthreads();
    // ---- merged scores+softmax (row per 4-lane group) ----
    {
      int row = tid >> 2;                 // h*16+qm
      int h = row >> 4, qm = row & 15;
      int km0 = (tid & 3) * 4;
      float s4[4];
      #pragma unroll
      for (int j = 0; j < 4; ++j){
        int km = km0 + j;
        float acc = dot16(q_ + qm*68 + h*16, k_ + km*68 + h*16);
        int dd = qm - km; if (dd < 0) dd = -dd;
        acc = acc * 0.25f + tbt[dd];
        if (pmv[km] == 0.f) acc = -1e9f;
        s4[j] = acc;
      }
      float mx = fmaxf(fmaxf(s4[0], s4[1]), fmaxf(s4[2], s4[3]));
      mx = fmaxf(mx, __shfl_xor(mx, 1, 64));
      mx = fmaxf(mx, __shfl_xor(mx, 2, 64));
      float e4[4], se = 0.f;
      #pragma unroll
      for (int j = 0; j < 4; ++j){ e4[j] = __expf(s4[j]-mx); se += e4[j]; }
      se += __shfl_xor(se, 1, 64);
      se += __shfl_xor(se, 2, 64);
      float inv = fast_rcp(se);
      #pragma unroll
      for (int j = 0; j < 4; ++j) ss[row*16 + km0 + j] = e4[j]*inv;
    }
    __syncthreads();
    for (int o = tid; o < 1024; o += 256){
      int m = o >> 6, d = o & 63, h = d >> 4;
      float acc = 0.f;
      #pragma unroll
      for (int km = 0; km < 16; ++km) acc += ss[h*256 + m*16 + km] * v_[km*68 + d];
      ao[m*68 + d] = acc;
    }
    __syncthreads();
    packA68(ao, fragA, tid);
    __syncthreads();
    {
      short8 axh0 = fragA[lane], axh1 = fragA[64+lane];
      short8 axl0 = fragA[128+lane], axl1 = fragA[192+lane];
      floatx4 c = {0.f,0.f,0.f,0.f};
      c = mm3(axh0, axl0, ob4[0], ob4[1], c);
      c = mm3(axh1, axl1, ob4[2], ob4[3], c);
      int d = wvi*16 + nidx;
      float bb = gobL[d];
      #pragma unroll
      for (int r = 0; r < 4; ++r){
        int tok = quad*4 + r;
        xb[tok*68 + d] += (c[r] + bb) * pmv[tok] + pe_t[tok*64 + d];
      }
    }
    __syncthreads();

    // ================= PREFETCH WAVE 2: MHA-out(4) + FF f1/f2 initial (8)
    short8 mob[4], f1c[4], f2c[4];
    {
      int base = lbase + OFF_OUTW;
      mob[0] = frS[base + (wvi*2+0)*64 + lane];
      mob[1] = frS[FRAG_TOT + base + (wvi*2+0)*64 + lane];
      mob[2] = frS[base + (wvi*2+1)*64 + lane];
      mob[3] = frS[FRAG_TOT + base + (wvi*2+1)*64 + lane];
    }
    {
      int f1base = lbase + OFF_FW1, f2base = lbase + OFF_FW2;
      #pragma unroll
      for (int t2 = 0; t2 < 2; ++t2){
        int sb = f1base + ((wvi*32+t2)*2)*64 + lane;
        f1c[t2*2+0] = frS[sb];
        f1c[t2*2+1] = frS[sb + 64];
      }
      #pragma unroll
      for (int ntd = 0; ntd < 4; ++ntd)
        f2c[ntd] = frS[f2base + (ntd*64 + wvi*16)*64 + lane];
    }

    // ---- MHA QKV (frags prefetched) ----
    packA68(xb, fragA, tid);
    __syncthreads();
    {
      short8 axh0 = fragA[lane], axh1 = fragA[64+lane];
      short8 axl0 = fragA[128+lane], axl1 = fragA[192+lane];
      #pragma unroll
      for (int sel = 0; sel < 3; ++sel){
        floatx4 c = {0.f,0.f,0.f,0.f};
        c = mm3(axh0, axl0, mb[sel][0], mb[sel][1], c);
        c = mm3(axh1, axl1, mb[sel][2], mb[sel][3], c);
        int d = wvi*16 + nidx;
        float bb = inbL[(sel*4 + wvi)*16 + nidx];
        float* dst = (sel == 0 ? q_ : sel == 1 ? k_ : v_);
        #pragma unroll
        for (int r = 0; r < 4; ++r) dst[(quad*4+r)*68 + d] = c[r] + bb;
      }
    }
    __syncthreads();
    {
      int row = tid >> 2;
      int h = row >> 4, qm = row & 15;
      int km0 = (tid & 3) * 4;
      float s4[4];
      #pragma unroll
      for (int j = 0; j < 4; ++j)
        s4[j] = 0.25f * dot16(q_ + qm*68 + h*16, k_ + (km0+j)*68 + h*16);
      float mx = fmaxf(fmaxf(s4[0], s4[1]), fmaxf(s4[2], s4[3]));
      mx = fmaxf(mx, __shfl_xor(mx, 1, 64));
      mx = fmaxf(mx, __shfl_xor(mx, 2, 64));
      float e4[4], se = 0.f;
      #pragma unroll
      for (int j = 0; j < 4; ++j){ e4[j] = __expf(s4[j]-mx); se += e4[j]; }
      se += __shfl_xor(se, 1, 64);
      se += __shfl_xor(se, 2, 64);
      float inv = fast_rcp(se);
      #pragma unroll
      for (int j = 0; j < 4; ++j) ss[row*16 + km0 + j] = e4[j]*inv;
    }
    __syncthreads();
    for (int o = tid; o < 1024; o += 256){
      int m = o >> 6, d = o & 63, h = d >> 4;
      float acc = 0.f;
      #pragma unroll
      for (int km = 0; km < 16; ++km) acc += ss[h*256 + m*16 + km] * v_[km*68 + d];
      ao[m*68 + d] = acc;
    }
    __syncthreads();
    packA68(ao, fragA, tid);
    __syncthreads();
    {
      short8 axh0 = fragA[lane], axh1 = fragA[64+lane];
      short8 axl0 = fragA[128+lane], axl1 = fragA[192+lane];
      floatx4 c = {0.f,0.f,0.f,0.f};
      c = mm3(axh0, axl0, mob[0], mob[1], c);
      c = mm3(axh1, axl1, mob[2], mob[3], c);
      int d = wvi*16 + nidx;
      float bb = outbL[d];
      #pragma unroll
      for (int r = 0; r < 4; ++r) xb[(quad*4+r)*68 + d] += c[r] + bb;
    }
    __syncthreads();

    // ---- LN1 (64 threads, 4 lanes/row) -> xb2 ----
    if (tid < 64){
      int row = tid >> 2, seg = tid & 3;
      const float* rp = xb + row*68 + seg*16;
      float s = 0.f;
      #pragma unroll
      for (int j = 0; j < 16; ++j) s += rp[j];
      s += __shfl_xor(s, 1, 64); s += __shfl_xor(s, 2, 64);
      float mu = s * (1.f/64.f);
      float v = 0.f;
      #pragma unroll
      for (int j = 0; j < 16; ++j){ float t = rp[j]-mu; v += t*t; }
      v += __shfl_xor(v, 1, 64); v += __shfl_xor(v, 2, 64);
      if (seg == 0){ mur[row] = mu; rvr[row] = rsqrtf(v*(1.f/64.f) + 1e-5f); }
    }
    __syncthreads();
    for (int o = tid; o < 1024; o += 256){
      int m = o >> 6, d = o & 63;
      xb2[m*68 + d] = (xb[m*68 + d] - mur[m]) * rvr[m] * ln1gL[d] + ln1bL[d];
    }
    __syncthreads();
    packA68(xb2, fragA, tid);
    __syncthreads();

    // ---- FF (2048 hidden): 1-term bf16; f1 & f2 both prefetched 1 iter ahead
    {
      const int w = wvi;
      const int f1base = lbase + OFF_FW1, f2base = lbase + OFF_FW2;
      short8 axh0 = fragA[lane], axh1 = fragA[64 + lane];
      floatx4 y0 = {0.f,0.f,0.f,0.f}, y1 = y0, y2 = y0, y3 = y0;
      float* hw = hbuf + w*576;

      short8 f1n[4], f2n[4];
      for (int it = 0; it < 16; ++it){
        int ntA = w*32 + it*2;
        floatx4 hA = {0.f,0.f,0.f,0.f}, hB = hA;
        hA = MFMA16(axh0, f1c[0], hA); hA = MFMA16(axh1, f1c[1], hA);
        hB = MFMA16(axh0, f1c[2], hB); hB = MFMA16(axh1, f1c[3], hB);
        float bbA = fb1L[ntA*16 + nidx], bbB = fb1L[ntA*16 + 16 + nidx];
        #pragma unroll
        for (int r = 0; r < 4; ++r){
          hw[(quad*4+r)*36 + nidx]      = fmaxf(hA[r] + bbA, 0.f);
          hw[(quad*4+r)*36 + 16 + nidx] = fmaxf(hB[r] + bbB, 0.f);
        }
        if (it < 15){
          int ntN = ntA + 2, kstN = w*16 + it + 1;
          #pragma unroll
          for (int t2 = 0; t2 < 2; ++t2){
            int sb = f1base + ((ntN+t2)*2)*64 + lane;
            f1n[t2*2+0] = frS[sb];
            f1n[t2*2+1] = frS[sb + 64];
          }
          #pragma unroll
          for (int ntd = 0; ntd < 4; ++ntd)
            f2n[ntd] = frS[f2base + (ntd*64 + kstN)*64 + lane];
        }
        short8 ah = cvt8s(hw + (lane & 15)*36 + quad*8);
        y0 = MFMA16(ah, f2c[0], y0);
        y1 = MFMA16(ah, f2c[1], y1);
        y2 = MFMA16(ah, f2c[2], y2);
        y3 = MFMA16(ah, f2c[3], y3);
        #pragma unroll
        for (int j = 0; j < 4; ++j){ f1c[j] = f1n[j]; f2c[j] = f2n[j]; }
      }
      #pragma unroll
      for (int r = 0; r < 4; ++r){
        int row = (quad*4 + r)*68;
        part[w*1088 + row + nidx]      = y0[r];
        part[w*1088 + row + 16 + nidx] = y1[r];
        part[w*1088 + row + 32 + nidx] = y2[r];
        part[w*1088 + row + 48 + nidx] = y3[r];
      }
    }
    __syncthreads();
    for (int o = tid; o < 1024; o += 256){
      int tok = o >> 6, d = o & 63;
      float s = xb2[tok*68 + d] + fb2L[d];
      #pragma unroll
      for (int ww = 0; ww < 4; ++ww) s += part[ww*1088 + tok*68 + d];
      xb[tok*68 + d] = s;
    }
    __syncthreads();
    // ---- LN2 (64 threads) + layer-1 residual ----
    if (tid < 64){
      int row = tid >> 2, seg = tid & 3;
      const float* rp = xb + row*68 + seg*16;
      float s = 0.f;
      #pragma unroll
      for (int j = 0; j < 16; ++j) s += rp[j];
      s += __shfl_xor(s, 1, 64); s += __shfl_xor(s, 2, 64);
      float mu = s * (1.f/64.f);
      float v = 0.f;
      #pragma unroll
      for (int j = 0; j < 16; ++j){ float t = rp[j]-mu; v += t*t; }
      v += __shfl_xor(v, 1, 64); v += __shfl_xor(v, 2, 64);
      if (seg == 0){ mur[row] = mu; rvr[row] = rsqrtf(v*(1.f/64.f) + 1e-5f); }
    }
    __syncthreads();
    #pragma unroll
    for (int kk2 = 0; kk2 < 4; ++kk2){
      int o = tid + kk2*256;
      int tok = o >> 6, d = o & 63;
      float vv = (xb[tok*68 + d] - mur[tok]) * rvr[tok] * ln2gL[d] + ln2bL[d];
      if (l == 0) xb[tok*68 + d] = vv;                 // becomes layer-1 input
      else        xout[bn*1024 + o] = vv + xres[kk2];  // layer residual
    }
    __syncthreads();
  }
}

// -------------------------------------------------------------------------
// Classifier head. One block per b. (small; fp32)
// -------------------------------------------------------------------------
__global__ __launch_bounds__(256) void final_kernel(
    const float* __restrict__ xc, const float* __restrict__ pm,
    const float* __restrict__ q_embed,
    const float* __restrict__ cin_w, const float* __restrict__ cin_b,
    const float* __restrict__ cout_w, const float* __restrict__ cout_b,
    const float* __restrict__ logit_w, const float* __restrict__ logit_b,
    float* __restrict__ out)
{
  const int b = blockIdx.x;
  const int tid = threadIdx.x;
  __shared__ __align__(16) float xs[M_ * D_];
  __shared__ float kpmv[M_];
  __shared__ __align__(16) float qv[5 * D_], kv[M_ * D_], vv[M_ * D_];
  __shared__ float sv[H_ * 5 * M_];
  __shared__ __align__(16) float ao[5 * D_], zv[5 * D_];

  for (int o = tid; o < M_ * D_; o += 256) {
    int m = o >> 6, d = o & 63;
    float acc = 0.f;
    #pragma unroll
    for (int n = 0; n < N_; ++n) acc += xc[(((b * N_ + n) * M_ + m) * D_) + d];
    xs[o] = acc * (1.f / 32.f);
  }
  if (tid < M_) {
    float any = 0.f;
    #pragma unroll
    for (int n = 0; n < N_; ++n) any += (pm[(b * N_ + n) * M_ + tid] > 0.f) ? 1.f : 0.f;
    kpmv[tid] = (any > 0.f) ? 0.f : 1.f;
  }
  __syncthreads();

  for (int o = tid; o < 5 * D_; o += 256) {
    int qi = o >> 6, d = o & 63;
    qv[o] = cin_b[d] + dot64(q_embed + qi * D_, cin_w + d * D_);
  }
  for (int o = tid; o < 2 * M_ * D_; o += 256) {
    int sel = o >> 10, r = o & 1023, m = r >> 6, d = r & 63;
    float acc = cin_b[D_ + sel * D_ + d] + dot64(xs + m * D_, cin_w + (D_ + sel * D_ + d) * D_);
    ((sel == 0) ? kv : vv)[r] = acc;
  }
  __syncthreads();

  for (int o = tid; o < H_ * 5 * M_; o += 256) {
    int h = o / 80, r = o % 80, qi = r >> 4, km = r & 15;
    float acc = 0.25f * dot16(qv + qi * D_ + h * DH_, kv + km * D_ + h * DH_);
    if (kpmv[km] != 0.f) acc = -1e9f;
    sv[o] = acc;
  }
  __syncthreads();
  if (tid < H_ * 5) {
    int h = tid / 5, qi = tid % 5;
    float* row = sv + h * 80 + qi * M_;
    float mx = -1e30f;
    #pragma unroll
    for (int km = 0; km < M_; ++km) mx = fmaxf(mx, row[km]);
    float se = 0.f;
    #pragma unroll
    for (int km = 0; km < M_; ++km) { float e = __expf(row[km] - mx); row[km] = e; se += e; }
    float inv = 1.f / se;
    #pragma unroll
    for (int km = 0; km < M_; ++km) row[km] *= inv;
  }
  __syncthreads();
  for (int o = tid; o < 5 * D_; o += 256) {
    int qi = o >> 6, d = o & 63, h = d >> 4;
    float acc = 0.f;
    #pragma unroll
    for (int km = 0; km < M_; ++km) acc += sv[h * 80 + qi * M_ + km] * vv[km * D_ + d];
    ao[o] = acc;
  }
  __syncthreads();
  for (int o = tid; o < 5 * D_; o += 256) {
    int qi = o >> 6, d = o & 63;
    zv[o] = cout_b[d] + dot64(ao + qi * D_, cout_w + d * D_);
  }
  __syncthreads();
  if (tid < 5) {
    float acc = logit_b[0] + dot64(zv + tid * D_, logit_w);
    out[b * 5 + tid] = acc;
  }
}

// -------------------------------------------------------------------------
extern "C" void kernel_launch(void* const* d_in, const int* in_sizes, int n_in,
                              void* d_out, int out_size, void* d_ws, size_t ws_size,
                              hipStream_t stream) {
  const float* x       = (const float*)d_in[0];
  const int*   mask    = (const int*)  d_in[1];
  const float* ttcn_w1 = (const float*)d_in[2];
  const float* ttcn_b1 = (const float*)d_in[3];
  const float* ttcn_w2 = (const float*)d_in[4];
  const float* ttcn_b2 = (const float*)d_in[5];
  const float* ttcn_w3 = (const float*)d_in[6];
  const float* ttcn_b3 = (const float*)d_in[7];   // unused: cancels in softmax
  const float* t_bias  = (const float*)d_in[8];
  const float* ga_qw   = (const float*)d_in[9];
  const float* ga_qb   = (const float*)d_in[10];
  const float* ga_kw   = (const float*)d_in[11];
  const float* ga_kb   = (const float*)d_in[12];
  const float* ga_vw   = (const float*)d_in[13];
  const float* ga_vb   = (const float*)d_in[14];
  const float* ga_ow   = (const float*)d_in[15];
  const float* ga_ob   = (const float*)d_in[16];
  const float* tf_in_w = (const float*)d_in[17];
  const float* tf_in_b = (const float*)d_in[18];
  const float* tf_out_w= (const float*)d_in[19];
  const float* tf_out_b= (const float*)d_in[20];
  const float* tf_ln1g = (const float*)d_in[21];
  const float* tf_ln1b = (const float*)d_in[22];
  const float* tf_ln2g = (const float*)d_in[23];
  const float* tf_ln2b = (const float*)d_in[24];
  const float* tf_fw1  = (const float*)d_in[25];
  const float* tf_fb1  = (const float*)d_in[26];
  const float* tf_fw2  = (const float*)d_in[27];
  const float* tf_fb2  = (const float*)d_in[28];
  const float* q_embed = (const float*)d_in[29];
  const float* cls_in_w  = (const float*)d_in[30];
  const float* cls_in_b  = (const float*)d_in[31];
  const float* cls_out_w = (const float*)d_in[32];
  const float* cls_out_b = (const float*)d_in[33];
  const float* logit_w = (const float*)d_in[34];
  const float* logit_b = (const float*)d_in[35];
  (void)ttcn_b3;

  float* wsf  = (float*)d_ws;
  float* xp   = wsf;                        // 262144 f
  float* pmb  = wsf + P_TOT * D_;           // 4096 f
  float* xbuf = pmb + P_TOT;                // 262144 f
  uint4* fr   = (uint4*)(xbuf + P_TOT * D_);// 2*FRAG_TOT uint4
  const short8* frS = (const short8*)fr;

  prep_kernel<<<325, 256, 0, stream>>>(ttcn_w1, ttcn_w2, ttcn_w3,
      ga_qw, ga_kw, ga_vw, ga_ow, tf_in_w, tf_out_w, tf_fw1, tf_fw2, fr);

  ttcn_kernel<<<P_TOT, 256, 0, stream>>>(x, mask, ttcn_b1, ttcn_b2, t_bias,
      frS + 0, frS + 256, frS + 768,
      xp, pmb);

  layer12_kernel<<<BN_, 256, 0, stream>>>(xp, pmb, frS,
      ga_qb, ga_kb, ga_vb, ga_ob, tf_in_b, tf_out_b, tf_ln1g, tf_ln1b,
      tf_fb1, tf_fb2, tf_ln2g, tf_ln2b, xbuf);

  final_kernel<<<B_, 256, 0, stream>>>(xbuf, pmb, q_embed,
                                       cls_in_w, cls_in_b, cls_out_w, cls_out_b,
                                       logit_w, logit_b, (float*)d_out);
}

// Round 9
// 234.057 us; speedup vs baseline: 7.0213x; 1.0052x over previous
//
#include <hip/hip_runtime.h>
#include <hip/hip_bf16.h>
#include <math.h>

// Problem constants
#define B_  8
#define N_  32
#define M_  16
#define LX  32
#define D_  64
#define IN_DIM_ 17
#define TT_ 63
#define H_  4
#define DH_ 16
#define P_TOT 4096          // B*N*M
#define BN_ 256             // B*N
#define FF_ 2048

// Fragment pool layout (slot = one short8/uint4 per lane-group entry)
#define FRAG_TOT 83200
#define OFF_INW  2048
#define OFF_OUTW 3584
#define OFF_FW1  4096
#define OFF_FW2  20480

typedef unsigned short ushort_t;
typedef __attribute__((ext_vector_type(8))) short short8;   // 8 bf16 (4 VGPRs)
typedef __attribute__((ext_vector_type(4))) float floatx4;  // MFMA C/D

#define MFMA16(a,b,c) __builtin_amdgcn_mfma_f32_16x16x32_bf16((a),(b),(c),0,0,0)

__device__ __forceinline__ float fast_exp2(float x){
#if __has_builtin(__builtin_amdgcn_exp2f)
  return __builtin_amdgcn_exp2f(x);
#else
  return __expf(x * 0.6931471805599453f);
#endif
}
__device__ __forceinline__ float fast_rcp(float x){
#if __has_builtin(__builtin_amdgcn_rcpf)
  return __builtin_amdgcn_rcpf(x);
#else
  return 1.0f / x;
#endif
}

__device__ __forceinline__ ushort_t f2bf(float f){          // RNE float->bf16
  unsigned u = __float_as_uint(f);
  u += 0x7FFFu + ((u >> 16) & 1u);
  return (ushort_t)(u >> 16);
}
__device__ __forceinline__ float bf2f(ushort_t h){ return __uint_as_float(((unsigned)h) << 16); }

__device__ __forceinline__ uint4 pack8(const ushort_t* h){
  uint4 u;
  u.x = (unsigned)h[0] | ((unsigned)h[1] << 16);
  u.y = (unsigned)h[2] | ((unsigned)h[3] << 16);
  u.z = (unsigned)h[4] | ((unsigned)h[5] << 16);
  u.w = (unsigned)h[6] | ((unsigned)h[7] << 16);
  return u;
}

// split 8 consecutive floats into hi/lo bf16 short8
__device__ __forceinline__ void split8(const float* r, short8& hi, short8& lo){
  #pragma unroll
  for (int j = 0; j < 8; ++j){
    float v = r[j];
    ushort_t h = f2bf(v);
    ushort_t l2 = f2bf(v - bf2f(h));
    hi[j] = (short)h; lo[j] = (short)l2;
  }
}
// hi-only conversion -> uint4
__device__ __forceinline__ uint4 cvt8(const float* r){
  ushort_t hh[8];
  #pragma unroll
  for (int j = 0; j < 8; ++j) hh[j] = f2bf(r[j]);
  return pack8(hh);
}
// hi-only conversion -> short8
__device__ __forceinline__ short8 cvt8s(const float* r){
  union { uint4 u4; short8 s8; } cv;
  cv.u4 = cvt8(r);
  return cv.s8;
}

// 3-term split product: (ah+al)(bh+bl) ~= ah*bh + ah*bl + al*bh
__device__ __forceinline__ floatx4 mm3(short8 ah, short8 al, short8 bh, short8 bl, floatx4 c){
  c = MFMA16(ah, bh, c); c = MFMA16(ah, bl, c); c = MFMA16(al, bh, c); return c;
}

__device__ __forceinline__ float dot64(const float* __restrict__ a, const float* __restrict__ w){
  const float4* a4 = (const float4*)a;
  const float4* w4 = (const float4*)w;
  float acc = 0.f;
  #pragma unroll
  for (int k = 0; k < 16; ++k){ float4 x = a4[k], y = w4[k];
    acc += x.x*y.x + x.y*y.y + x.z*y.z + x.w*y.w; }
  return acc;
}
__device__ __forceinline__ float dot16(const float* __restrict__ a, const float* __restrict__ b){
  const float4* a4 = (const float4*)a; const float4* b4 = (const float4*)b;
  float acc = 0.f;
  #pragma unroll
  for (int k = 0; k < 4; ++k){ float4 x = a4[k], y = b4[k];
    acc += x.x*y.x + x.y*y.y + x.z*y.z + x.w*y.w; }
  return acc;
}

// pack A-frags (16 tokens x 64 k) from stride-68 LDS buffer into fragA (hi[128], lo[128])
__device__ __forceinline__ void packA68(const float* buf, short8* fA, int tid){
  if (tid < 128){
    int ln = tid & 63, ks = tid >> 6;
    const float* r = buf + (ln & 15)*68 + ks*32 + ((ln >> 4) & 3)*8;
    short8 hi, lo; split8(r, hi, lo);
    fA[tid] = hi; fA[128 + tid] = lo;
  }
}

// -------------------------------------------------------------------------
// Prep: convert ALL weight matrices to MFMA B-fragment pool (hi at [s], lo at
// [FRAG_TOT+s]; lo only written for attn segments — ttcn + FF consume hi only).
// B[k][n]: n = nt*16 + (lane&15), k = ks*32 + quad*8 + j.
// w3 special: (a) columns reordered so tile nt covers i = nt>>2 (constant per
// tile), t = (nt&3)*16 + lane&15; (b) k=63 slot = 1.0 (mask carrier);
// (c) ALL w3 values scaled by log2(e) so epilogue uses raw v_exp_f32.
// -------------------------------------------------------------------------
__global__ __launch_bounds__(256) void prep_kernel(
    const float* __restrict__ w1, const float* __restrict__ w2, const float* __restrict__ w3,
    const float* __restrict__ gqw, const float* __restrict__ gkw,
    const float* __restrict__ gvw, const float* __restrict__ gow,
    const float* __restrict__ inw, const float* __restrict__ outw,
    const float* __restrict__ fw1, const float* __restrict__ fw2,
    uint4* __restrict__ fr)
{
  int s = blockIdx.x*256 + threadIdx.x;
  if (s >= FRAG_TOT) return;
  const float* src; int Nr, Kr, KS, rel; int w3seg = 0, noLo = 0;
  if (s < 256)      { src = w1; Nr=63;  Kr=17; KS=1; rel = s; noLo = 1; }
  else if (s < 768) { src = w2; Nr=63;  Kr=63; KS=2; rel = s-256; noLo = 1; }
  else if (s < 9472){ src = w3; Nr=1071;Kr=63; KS=2; rel = s-768; w3seg = 1; noLo = 1; }
  else {
    int t = s - 9472, l = t / 36864, r2 = t - l*36864;
    if (r2 < 512)        { src = gqw + l*4096;   Nr=64;  Kr=64;   KS=2;  rel = r2; }
    else if (r2 < 1024)  { src = gkw + l*4096;   Nr=64;  Kr=64;   KS=2;  rel = r2-512; }
    else if (r2 < 1536)  { src = gvw + l*4096;   Nr=64;  Kr=64;   KS=2;  rel = r2-1024; }
    else if (r2 < 2048)  { src = gow + l*4096;   Nr=64;  Kr=64;   KS=2;  rel = r2-1536; }
    else if (r2 < 3584)  { src = inw + l*12288;  Nr=192; Kr=64;   KS=2;  rel = r2-2048; }
    else if (r2 < 4096)  { src = outw + l*4096;  Nr=64;  Kr=64;   KS=2;  rel = r2-3584; }
    else if (r2 < 20480) { src = fw1 + l*131072; Nr=2048;Kr=64;   KS=2;  rel = r2-4096; noLo = 1; }
    else                 { src = fw2 + l*131072; Nr=64;  Kr=2048; KS=64; rel = r2-20480; noLo = 1; }
  }
  int lane = rel & 63, tmp = rel >> 6;
  int ks = tmp % KS, nt = tmp / KS;
  int kb = ks*32 + ((lane >> 4) & 3)*8;
  int n, validn;
  if (w3seg){
    int i = nt >> 2, tq = nt & 3;
    int t = tq*16 + (lane & 15);
    n = t*17 + i;                         // source row of w3 (c = t*17+i)
    validn = (t < 63);
  } else {
    n = nt*16 + (lane & 15);
    validn = (n < Nr);
  }
  float v[8];
  #pragma unroll
  for (int j = 0; j < 8; ++j){
    v[j] = (validn && (kb + j) < Kr) ? src[n*Kr + kb + j] : 0.f;
    if (w3seg){
      if ((kb + j) == 63) v[j] = 1.0f;               // mask-carrier column
      v[j] *= 1.4426950408889634f;                   // log2(e) for exp2 epilogue
    }
  }
  ushort_t hh[8];
  #pragma unroll
  for (int j = 0; j < 8; ++j) hh[j] = f2bf(v[j]);
  fr[s] = pack8(hh);
  if (!noLo){
    ushort_t ll[8];
    #pragma unroll
    for (int j = 0; j < 8; ++j) ll[j] = f2bf(v[j] - bf2f(hh[j]));
    fr[FRAG_TOT + s] = pack8(ll);
  }
}

// -------------------------------------------------------------------------
// Fused TTCN — bf16 1-term MFMA. h1/h2 stored DIRECTLY as bf16 in [l][t]
// (stride 72 shorts) so GEMM2/3 A-frags are single ds_read_b128's — the old
// fp32->frag transpose phases (and 2 barriers) are gone. xst[i][l] transposed
// copy gives the P6 epilogue float4 x-reads. Mask carrier = register fixup.
// LDS 16.5 KB -> ~8 blocks/CU. Numerically identical to R8.
// -------------------------------------------------------------------------
__global__ __launch_bounds__(256) void ttcn_kernel(
    const float* __restrict__ x, const int* __restrict__ mask,
    const float* __restrict__ b1, const float* __restrict__ b2,
    const float* __restrict__ tb,
    const short8* __restrict__ w1bhi,
    const short8* __restrict__ w2bhi,
    const short8* __restrict__ w3bhi,
    float* __restrict__ xp, float* __restrict__ pm)
{
  __shared__ __align__(16) char pool[16512];
  float*    xs    = (float*)(pool + 0);        // 32x20 f (row l, stride 20)
  float*    xst   = (float*)(pool + 2560);     // 17x36 f (row i, stride 36)
  float*    msv   = (float*)(pool + 5008);     // 32 f
  float*    xsumv = (float*)(pool + 5136);     // 17 f (+pad)
  short8*   xfhi  = (short8*)(pool + 5216);    // 128 slots
  ushort_t* h1t   = (ushort_t*)(pool + 7264);  // 32x72 bf16 [l][t] (dead after P4)
  float*    colres= (float*)(pool + 7264);     // 17x64 f (alias h1t, written P6)
  ushort_t* h2t   = (ushort_t*)(pool + 11872); // 32x72 bf16 [l][t]

  const int p = blockIdx.x, tid = threadIdx.x;
  const int lane = tid & 63, wvi = tid >> 6;
  const int nidx = lane & 15, quad = lane >> 4;

  // P0: stage x (stride 20) + mask
  for (int idx = tid; idx < LX*IN_DIM_; idx += 256){
    int l = (idx * 3856) >> 16;             // idx/17 exact for idx<1088
    int i = idx - l*17;
    xs[l*20 + i] = x[p*(LX*IN_DIM_) + idx];
  }
  if (tid < LX) msv[tid] = (float)mask[p*LX + tid];
  __syncthreads();

  // P1: x A-fragments (hi only) on threads <128; xsumv + xst on the rest
  if (tid < 128){
    int mt = tid >> 6;
    int l = mt*16 + nidx;
    float r[8];
    #pragma unroll
    for (int j = 0; j < 8; ++j){
      int k = quad*8 + j;
      r[j] = (k < IN_DIM_) ? xs[l*20 + k] : 0.f;
    }
    ((uint4*)xfhi)[tid] = cvt8(r);
  } else {
    if (tid < 128 + IN_DIM_){
      int i = tid - 128;
      float s = 0.f;
      #pragma unroll
      for (int l = 0; l < LX; ++l) s += xs[l*20 + i];
      xsumv[i] = s;
    }
    for (int idx = tid - 128; idx < 544; idx += 128){
      int i = idx >> 5, l = idx & 31;
      xst[i*36 + l] = xs[l*20 + i];
    }
  }
  __syncthreads();

  // P2: GEMM1  h1 = relu(x @ w1^T + b1) -> bf16 [l][t] stride 72
  {
    short8 axh0 = xfhi[lane], axh1 = xfhi[64 + lane];
    short8 bh = w1bhi[wvi*64 + lane];
    floatx4 a0 = {0.f,0.f,0.f,0.f}, a1 = {0.f,0.f,0.f,0.f};
    a0 = MFMA16(axh0, bh, a0);
    a1 = MFMA16(axh1, bh, a1);
    int t = wvi*16 + nidx;
    float bb = (t < TT_) ? b1[t] : 0.f;
    #pragma unroll
    for (int r = 0; r < 4; ++r){
      h1t[(quad*4+r)*72 + t]      = f2bf(fmaxf(a0[r] + bb, 0.f));
      h1t[(16+quad*4+r)*72 + t]   = f2bf(fmaxf(a1[r] + bb, 0.f));
    }
  }
  __syncthreads();

  // P4: GEMM2  h2 = relu(h1 @ w2^T + b2); A-frags = direct b128 from h1t
  {
    short8 ah[2][2];
    #pragma unroll
    for (int mt = 0; mt < 2; ++mt)
      #pragma unroll
      for (int ks = 0; ks < 2; ++ks){
        int l = mt*16 + nidx;
        ah[mt][ks] = *(const short8*)((const char*)h1t + (l*72 + ks*32 + quad*8)*2);
      }
    short8 bh0 = w2bhi[(wvi*2+0)*64 + lane];
    short8 bh1 = w2bhi[(wvi*2+1)*64 + lane];
    floatx4 a0 = {0.f,0.f,0.f,0.f}, a1 = {0.f,0.f,0.f,0.f};
    a0 = MFMA16(ah[0][0], bh0, a0); a0 = MFMA16(ah[0][1], bh1, a0);
    a1 = MFMA16(ah[1][0], bh0, a1); a1 = MFMA16(ah[1][1], bh1, a1);
    int t = wvi*16 + nidx;
    float bb = (t < TT_) ? b2[t] : 0.f;
    #pragma unroll
    for (int r = 0; r < 4; ++r){
      h2t[(quad*4+r)*72 + t]      = f2bf(fmaxf(a0[r] + bb, 0.f));
      h2t[(16+quad*4+r)*72 + t]   = f2bf(fmaxf(a1[r] + bb, 0.f));
    }
  }
  __syncthreads();

  // P6: GEMM3 (i-major tiles; mask + log2e folded into MFMA) + softmax + contract
  {
    short8 ah[2][2];
    #pragma unroll
    for (int mt = 0; mt < 2; ++mt)
      #pragma unroll
      for (int ks = 0; ks < 2; ++ks){
        int l = mt*16 + nidx;
        ah[mt][ks] = *(const short8*)((const char*)h2t + (l*72 + ks*32 + quad*8)*2);
      }
    // mask carrier: A[l][63] = -1e8 (bf16) for masked l; w3 B[63][*] = log2e
    if (quad == 3){
      ah[0][1][7] = (short)((msv[nidx]      == 0.f) ? f2bf(-1e8f) : (ushort_t)0);
      ah[1][1][7] = (short)((msv[16 + nidx] == 0.f) ? f2bf(-1e8f) : (ushort_t)0);
    }
    const int t_out = wvi*16 + nidx;          // constant per lane
    const bool valid = t_out < 63;
    const int rA = quad*4;
    short8 nbh0 = w3bhi[(wvi*2+0)*64 + lane];
    short8 nbh1 = w3bhi[(wvi*2+1)*64 + lane];
    for (int it = 0; it < 17; ++it){
      short8 bh0 = nbh0, bh1 = nbh1;
      if (it < 16){
        int nt = wvi + it*4 + 4;
        nbh0 = w3bhi[(nt*2+0)*64 + lane];
        nbh1 = w3bhi[(nt*2+1)*64 + lane];
      }
      floatx4 a0 = {0.f,0.f,0.f,0.f}, a1 = {0.f,0.f,0.f,0.f};
      a0 = MFMA16(ah[0][0], bh0, a0); a0 = MFMA16(ah[0][1], bh1, a0);
      a1 = MFMA16(ah[1][0], bh0, a1); a1 = MFMA16(ah[1][1], bh1, a1);

      const float4 xA = *(const float4*)(xst + it*36 + rA);
      const float4 xB = *(const float4*)(xst + it*36 + rA + 16);
      float den0 = 0.f, den1 = 0.f, num0 = 0.f, num1 = 0.f;
      float e;
      e = fast_exp2(a0[0]); den0 += e; num0 = fmaf(e, xA.x, num0);
      e = fast_exp2(a0[1]); den0 += e; num0 = fmaf(e, xA.y, num0);
      e = fast_exp2(a0[2]); den0 += e; num0 = fmaf(e, xA.z, num0);
      e = fast_exp2(a0[3]); den0 += e; num0 = fmaf(e, xA.w, num0);
      e = fast_exp2(a1[0]); den1 += e; num1 = fmaf(e, xB.x, num1);
      e = fast_exp2(a1[1]); den1 += e; num1 = fmaf(e, xB.y, num1);
      e = fast_exp2(a1[2]); den1 += e; num1 = fmaf(e, xB.z, num1);
      e = fast_exp2(a1[3]); den1 += e; num1 = fmaf(e, xB.w, num1);
      float den = den0 + den1, num = num0 + num1;
      den += __shfl_xor(den, 16, 64); den += __shfl_xor(den, 32, 64);
      num += __shfl_xor(num, 16, 64); num += __shfl_xor(num, 32, 64);
      if (quad == 0 && valid){
        float res = (den > 0.f) ? num * fast_rcp(den) : xsumv[it] * (1.f/32.f);
        colres[it*64 + t_out] = res;
      }
    }
  }
  __syncthreads();

  // P7: h_t[t] = relu(sum_i colres[i][t] + tb[t]); append mask_patch
  if (tid < TT_){
    float acc = 0.f;
    #pragma unroll
    for (int i2 = 0; i2 < IN_DIM_; ++i2) acc += colres[i2*64 + tid];
    xp[p*D_ + tid] = fmaxf(acc + tb[tid], 0.f);
  }
  if (tid == TT_){
    float s = 0.f;
    #pragma unroll
    for (int l = 0; l < LX; ++l) s += msv[l];
    float mp = (s > 0.f) ? 1.f : 0.f;
    xp[p*D_ + TT_] = mp;
    pm[p] = mp;
  }
}

// -------------------------------------------------------------------------
// BOTH transformer layers fused, one block per bn (= 1 wave/SIMD: zero TLP,
// so B-frags are register-prefetched PHASES ahead of use to build ILP).
// Merged score+softmax phases (all 256 threads, shfl-group reductions).
// -------------------------------------------------------------------------
__global__ __launch_bounds__(256) void layer12_kernel(
    const float* __restrict__ xin, const float* __restrict__ pm,
    const short8* __restrict__ frS,
    const float* __restrict__ gqb, const float* __restrict__ gkb,
    const float* __restrict__ gvb, const float* __restrict__ gob,
    const float* __restrict__ inb, const float* __restrict__ outb,
    const float* __restrict__ ln1g, const float* __restrict__ ln1b,
    const float* __restrict__ fb1, const float* __restrict__ fb2,
    const float* __restrict__ ln2g, const float* __restrict__ ln2b,
    float* __restrict__ xout)
{
  __shared__ __align__(16) float xb[16*68];
  __shared__ __align__(16) float xb2[16*68];
  __shared__ __align__(16) float q_[16*68];
  __shared__ __align__(16) float k_[16*68];
  __shared__ __align__(16) float v_[16*68];
  __shared__ __align__(16) float ao[16*68];
  __shared__ __align__(16) float ss[1024];
  __shared__ __align__(16) short8 fragA[256];
  __shared__ __align__(16) float hbuf[4*16*36];
  __shared__ __align__(16) float part[4*16*68];
  __shared__ __align__(16) float pe_t[1024];
  __shared__ float tbt[16];
  __shared__ float pmv[16], mur[16], rvr[16];

  const int bn = blockIdx.x, tid = threadIdx.x;
  const int lane = tid & 63, wvi = tid >> 6;
  const int nidx = lane & 15, quad = lane >> 4;
  const float* xin_p = xin + bn*1024;

  for (int o = tid; o < 1024; o += 256) xb[(o>>6)*68 + (o&63)] = xin_p[o];
  if (tid < 16) pmv[tid] = pm[bn*16 + tid];
  // tables (once)
  for (int o = tid; o < 1024; o += 256){
    int tok = o >> 6, d = o & 63;
    float div = __expf((float)(d & ~1) * (-0.14391156831212793f)); // -ln(1e4)/64
    float arg = (float)tok * div;
    pe_t[o] = (d & 1) ? cosf(arg) : sinf(arg);
  }
  if (tid >= 32 && tid < 48) tbt[tid-32] = logf(expf(-5.0f*(float)(tid-32)) + 1e-12f);
  __syncthreads();

  for (int l = 0; l < 2; ++l){
    const int lbase = 9472 + l*36864;
    const float* gqbL = gqb + l*64;  const float* gkbL = gkb + l*64;
    const float* gvbL = gvb + l*64;  const float* gobL = gob + l*64;
    const float* inbL = inb + l*192; const float* outbL = outb + l*64;
    const float* ln1gL = ln1g + l*64; const float* ln1bL = ln1b + l*64;
    const float* fb1L = fb1 + l*2048; const float* fb2L = fb2 + l*64;
    const float* ln2gL = ln2g + l*64; const float* ln2bL = ln2b + l*64;

    // save layer input for the l==1 residual
    float xres[4];
    #pragma unroll
    for (int kk2 = 0; kk2 < 4; ++kk2){
      int o = tid + kk2*256;
      xres[kk2] = xb[(o>>6)*68 + (o&63)];
    }

    // ================= PREFETCH WAVE 1: QKV(12) + gattn-out(4) + MHA-in(12)
    short8 gb[3][4], ob4[4], mb[3][4];
    #pragma unroll
    for (int mat = 0; mat < 3; ++mat){
      int base = lbase + mat*512;
      gb[mat][0] = frS[base + (wvi*2+0)*64 + lane];
      gb[mat][1] = frS[FRAG_TOT + base + (wvi*2+0)*64 + lane];
      gb[mat][2] = frS[base + (wvi*2+1)*64 + lane];
      gb[mat][3] = frS[FRAG_TOT + base + (wvi*2+1)*64 + lane];
    }
    {
      int base = lbase + 1536;   // gow
      ob4[0] = frS[base + (wvi*2+0)*64 + lane];
      ob4[1] = frS[FRAG_TOT + base + (wvi*2+0)*64 + lane];
      ob4[2] = frS[base + (wvi*2+1)*64 + lane];
      ob4[3] = frS[FRAG_TOT + base + (wvi*2+1)*64 + lane];
    }
    #pragma unroll
    for (int sel = 0; sel < 3; ++sel){
      int base = lbase + OFF_INW + (sel*4 + wvi)*128;
      mb[sel][0] = frS[base + lane];
      mb[sel][1] = frS[FRAG_TOT + base + lane];
      mb[sel][2] = frS[base + 64 + lane];
      mb[sel][3] = frS[FRAG_TOT + base + 64 + lane];
    }

    // ---- gattn QKV ----
    packA68(xb, fragA, tid);
    __syncthreads();
    {
      short8 axh0 = fragA[lane], axh1 = fragA[64+lane];
      short8 axl0 = fragA[128+lane], axl1 = fragA[192+lane];
      #pragma unroll
      for (int mat = 0; mat < 3; ++mat){
        floatx4 c = {0.f,0.f,0.f,0.f};
        c = mm3(axh0, axl0, gb[mat][0], gb[mat][1], c);
        c = mm3(axh1, axl1, gb[mat][2], gb[mat][3], c);
        int d = wvi*16 + nidx;
        float bb = (mat == 0 ? gqbL : mat == 1 ? gkbL : gvbL)[d];
        float* dst = (mat == 0 ? q_ : mat == 1 ? k_ : v_);
        #pragma unroll
        for (int r = 0; r < 4; ++r) dst[(quad*4+r)*68 + d] = c[r] + bb;
      }
    }
    __syncthreads();
    // ---- merged scores+softmax (row per 4-lane group) ----
    {
      int row = tid >> 2;                 // h*16+qm
      int h = row >> 4, qm = row & 15;
      int km0 = (tid & 3) * 4;
      float s4[4];
      #pragma unroll
      for (int j = 0; j < 4; ++j){
        int km = km0 + j;
        float acc = dot16(q_ + qm*68 + h*16, k_ + km*68 + h*16);
        int dd = qm - km; if (dd < 0) dd = -dd;
        acc = acc * 0.25f + tbt[dd];
        if (pmv[km] == 0.f) acc = -1e9f;
        s4[j] = acc;
      }
      float mx = fmaxf(fmaxf(s4[0], s4[1]), fmaxf(s4[2], s4[3]));
      mx = fmaxf(mx, __shfl_xor(mx, 1, 64));
      mx = fmaxf(mx, __shfl_xor(mx, 2, 64));
      float e4[4], se = 0.f;
      #pragma unroll
      for (int j = 0; j < 4; ++j){ e4[j] = __expf(s4[j]-mx); se += e4[j]; }
      se += __shfl_xor(se, 1, 64);
      se += __shfl_xor(se, 2, 64);
      float inv = fast_rcp(se);
      #pragma unroll
      for (int j = 0; j < 4; ++j) ss[row*16 + km0 + j] = e4[j]*inv;
    }
    __syncthreads();
    for (int o = tid; o < 1024; o += 256){
      int m = o >> 6, d = o & 63, h = d >> 4;
      float acc = 0.f;
      #pragma unroll
      for (int km = 0; km < 16; ++km) acc += ss[h*256 + m*16 + km] * v_[km*68 + d];
      ao[m*68 + d] = acc;
    }
    __syncthreads();
    packA68(ao, fragA, tid);
    __syncthreads();
    {
      short8 axh0 = fragA[lane], axh1 = fragA[64+lane];
      short8 axl0 = fragA[128+lane], axl1 = fragA[192+lane];
      floatx4 c = {0.f,0.f,0.f,0.f};
      c = mm3(axh0, axl0, ob4[0], ob4[1], c);
      c = mm3(axh1, axl1, ob4[2], ob4[3], c);
      int d = wvi*16 + nidx;
      float bb = gobL[d];
      #pragma unroll
      for (int r = 0; r < 4; ++r){
        int tok = quad*4 + r;
        xb[tok*68 + d] += (c[r] + bb) * pmv[tok] + pe_t[tok*64 + d];
      }
    }
    __syncthreads();

    // ================= PREFETCH WAVE 2: MHA-out(4) + FF f1/f2 initial (8)
    short8 mob[4], f1c[4], f2c[4];
    {
      int base = lbase + OFF_OUTW;
      mob[0] = frS[base + (wvi*2+0)*64 + lane];
      mob[1] = frS[FRAG_TOT + base + (wvi*2+0)*64 + lane];
      mob[2] = frS[base + (wvi*2+1)*64 + lane];
      mob[3] = frS[FRAG_TOT + base + (wvi*2+1)*64 + lane];
    }
    {
      int f1base = lbase + OFF_FW1, f2base = lbase + OFF_FW2;
      #pragma unroll
      for (int t2 = 0; t2 < 2; ++t2){
        int sb = f1base + ((wvi*32+t2)*2)*64 + lane;
        f1c[t2*2+0] = frS[sb];
        f1c[t2*2+1] = frS[sb + 64];
      }
      #pragma unroll
      for (int ntd = 0; ntd < 4; ++ntd)
        f2c[ntd] = frS[f2base + (ntd*64 + wvi*16)*64 + lane];
    }

    // ---- MHA QKV (frags prefetched) ----
    packA68(xb, fragA, tid);
    __syncthreads();
    {
      short8 axh0 = fragA[lane], axh1 = fragA[64+lane];
      short8 axl0 = fragA[128+lane], axl1 = fragA[192+lane];
      #pragma unroll
      for (int sel = 0; sel < 3; ++sel){
        floatx4 c = {0.f,0.f,0.f,0.f};
        c = mm3(axh0, axl0, mb[sel][0], mb[sel][1], c);
        c = mm3(axh1, axl1, mb[sel][2], mb[sel][3], c);
        int d = wvi*16 + nidx;
        float bb = inbL[(sel*4 + wvi)*16 + nidx];
        float* dst = (sel == 0 ? q_ : sel == 1 ? k_ : v_);
        #pragma unroll
        for (int r = 0; r < 4; ++r) dst[(quad*4+r)*68 + d] = c[r] + bb;
      }
    }
    __syncthreads();
    {
      int row = tid >> 2;
      int h = row >> 4, qm = row & 15;
      int km0 = (tid & 3) * 4;
      float s4[4];
      #pragma unroll
      for (int j = 0; j < 4; ++j)
        s4[j] = 0.25f * dot16(q_ + qm*68 + h*16, k_ + (km0+j)*68 + h*16);
      float mx = fmaxf(fmaxf(s4[0], s4[1]), fmaxf(s4[2], s4[3]));
      mx = fmaxf(mx, __shfl_xor(mx, 1, 64));
      mx = fmaxf(mx, __shfl_xor(mx, 2, 64));
      float e4[4], se = 0.f;
      #pragma unroll
      for (int j = 0; j < 4; ++j){ e4[j] = __expf(s4[j]-mx); se += e4[j]; }
      se += __shfl_xor(se, 1, 64);
      se += __shfl_xor(se, 2, 64);
      float inv = fast_rcp(se);
      #pragma unroll
      for (int j = 0; j < 4; ++j) ss[row*16 + km0 + j] = e4[j]*inv;
    }
    __syncthreads();
    for (int o = tid; o < 1024; o += 256){
      int m = o >> 6, d = o & 63, h = d >> 4;
      float acc = 0.f;
      #pragma unroll
      for (int km = 0; km < 16; ++km) acc += ss[h*256 + m*16 + km] * v_[km*68 + d];
      ao[m*68 + d] = acc;
    }
    __syncthreads();
    packA68(ao, fragA, tid);
    __syncthreads();
    {
      short8 axh0 = fragA[lane], axh1 = fragA[64+lane];
      short8 axl0 = fragA[128+lane], axl1 = fragA[192+lane];
      floatx4 c = {0.f,0.f,0.f,0.f};
      c = mm3(axh0, axl0, mob[0], mob[1], c);
      c = mm3(axh1, axl1, mob[2], mob[3], c);
      int d = wvi*16 + nidx;
      float bb = outbL[d];
      #pragma unroll
      for (int r = 0; r < 4; ++r) xb[(quad*4+r)*68 + d] += c[r] + bb;
    }
    __syncthreads();

    // ---- LN1 (64 threads, 4 lanes/row) -> xb2 ----
    if (tid < 64){
      int row = tid >> 2, seg = tid & 3;
      const float* rp = xb + row*68 + seg*16;
      float s = 0.f;
      #pragma unroll
      for (int j = 0; j < 16; ++j) s += rp[j];
      s += __shfl_xor(s, 1, 64); s += __shfl_xor(s, 2, 64);
      float mu = s * (1.f/64.f);
      float v = 0.f;
      #pragma unroll
      for (int j = 0; j < 16; ++j){ float t = rp[j]-mu; v += t*t; }
      v += __shfl_xor(v, 1, 64); v += __shfl_xor(v, 2, 64);
      if (seg == 0){ mur[row] = mu; rvr[row] = rsqrtf(v*(1.f/64.f) + 1e-5f); }
    }
    __syncthreads();
    for (int o = tid; o < 1024; o += 256){
      int m = o >> 6, d = o & 63;
      xb2[m*68 + d] = (xb[m*68 + d] - mur[m]) * rvr[m] * ln1gL[d] + ln1bL[d];
    }
    __syncthreads();
    packA68(xb2, fragA, tid);
    __syncthreads();

    // ---- FF (2048 hidden): 1-term bf16; f1 & f2 both prefetched 1 iter ahead
    {
      const int w = wvi;
      const int f1base = lbase + OFF_FW1, f2base = lbase + OFF_FW2;
      short8 axh0 = fragA[lane], axh1 = fragA[64 + lane];
      floatx4 y0 = {0.f,0.f,0.f,0.f}, y1 = y0, y2 = y0, y3 = y0;
      float* hw = hbuf + w*576;

      short8 f1n[4], f2n[4];
      for (int it = 0; it < 16; ++it){
        int ntA = w*32 + it*2;
        floatx4 hA = {0.f,0.f,0.f,0.f}, hB = hA;
        hA = MFMA16(axh0, f1c[0], hA); hA = MFMA16(axh1, f1c[1], hA);
        hB = MFMA16(axh0, f1c[2], hB); hB = MFMA16(axh1, f1c[3], hB);
        float bbA = fb1L[ntA*16 + nidx], bbB = fb1L[ntA*16 + 16 + nidx];
        #pragma unroll
        for (int r = 0; r < 4; ++r){
          hw[(quad*4+r)*36 + nidx]      = fmaxf(hA[r] + bbA, 0.f);
          hw[(quad*4+r)*36 + 16 + nidx] = fmaxf(hB[r] + bbB, 0.f);
        }
        if (it < 15){
          int ntN = ntA + 2, kstN = w*16 + it + 1;
          #pragma unroll
          for (int t2 = 0; t2 < 2; ++t2){
            int sb = f1base + ((ntN+t2)*2)*64 + lane;
            f1n[t2*2+0] = frS[sb];
            f1n[t2*2+1] = frS[sb + 64];
          }
          #pragma unroll
          for (int ntd = 0; ntd < 4; ++ntd)
            f2n[ntd] = frS[f2base + (ntd*64 + kstN)*64 + lane];
        }
        short8 ah = cvt8s(hw + (lane & 15)*36 + quad*8);
        y0 = MFMA16(ah, f2c[0], y0);
        y1 = MFMA16(ah, f2c[1], y1);
        y2 = MFMA16(ah, f2c[2], y2);
        y3 = MFMA16(ah, f2c[3], y3);
        #pragma unroll
        for (int j = 0; j < 4; ++j){ f1c[j] = f1n[j]; f2c[j] = f2n[j]; }
      }
      #pragma unroll
      for (int r = 0; r < 4; ++r){
        int row = (quad*4 + r)*68;
        part[w*1088 + row + nidx]      = y0[r];
        part[w*1088 + row + 16 + nidx] = y1[r];
        part[w*1088 + row + 32 + nidx] = y2[r];
        part[w*1088 + row + 48 + nidx] = y3[r];
      }
    }
    __syncthreads();
    for (int o = tid; o < 1024; o += 256){
      int tok = o >> 6, d = o & 63;
      float s = xb2[tok*68 + d] + fb2L[d];
      #pragma unroll
      for (int ww = 0; ww < 4; ++ww) s += part[ww*1088 + tok*68 + d];
      xb[tok*68 + d] = s;
    }
    __syncthreads();
    // ---- LN2 (64 threads) + layer-1 residual ----
    if (tid < 64){
      int row = tid >> 2, seg = tid & 3;
      const float* rp = xb + row*68 + seg*16;
      float s = 0.f;
      #pragma unroll
      for (int j = 0; j < 16; ++j) s += rp[j];
      s += __shfl_xor(s, 1, 64); s += __shfl_xor(s, 2, 64);
      float mu = s * (1.f/64.f);
      float v = 0.f;
      #pragma unroll
      for (int j = 0; j < 16; ++j){ float t = rp[j]-mu; v += t*t; }
      v += __shfl_xor(v, 1, 64); v += __shfl_xor(v, 2, 64);
      if (seg == 0){ mur[row] = mu; rvr[row] = rsqrtf(v*(1.f/64.f) + 1e-5f); }
    }
    __syncthreads();
    #pragma unroll
    for (int kk2 = 0; kk2 < 4; ++kk2){
      int o = tid + kk2*256;
      int tok = o >> 6, d = o & 63;
      float vv = (xb[tok*68 + d] - mur[tok]) * rvr[tok] * ln2gL[d] + ln2bL[d];
      if (l == 0) xb[tok*68 + d] = vv;                 // becomes layer-1 input
      else        xout[bn*1024 + o] = vv + xres[kk2];  // layer residual
    }
    __syncthreads();
  }
}

// -------------------------------------------------------------------------
// Classifier head. One block per b. (small; fp32)
// -------------------------------------------------------------------------
__global__ __launch_bounds__(256) void final_kernel(
    const float* __restrict__ xc, const float* __restrict__ pm,
    const float* __restrict__ q_embed,
    const float* __restrict__ cin_w, const float* __restrict__ cin_b,
    const float* __restrict__ cout_w, const float* __restrict__ cout_b,
    const float* __restrict__ logit_w, const float* __restrict__ logit_b,
    float* __restrict__ out)
{
  const int b = blockIdx.x;
  const int tid = threadIdx.x;
  __shared__ __align__(16) float xs[M_ * D_];
  __shared__ float kpmv[M_];
  __shared__ __align__(16) float qv[5 * D_], kv[M_ * D_], vv[M_ * D_];
  __shared__ float sv[H_ * 5 * M_];
  __shared__ __align__(16) float ao[5 * D_], zv[5 * D_];

  for (int o = tid; o < M_ * D_; o += 256) {
    int m = o >> 6, d = o & 63;
    float acc = 0.f;
    #pragma unroll
    for (int n = 0; n < N_; ++n) acc += xc[(((b * N_ + n) * M_ + m) * D_) + d];
    xs[o] = acc * (1.f / 32.f);
  }
  if (tid < M_) {
    float any = 0.f;
    #pragma unroll
    for (int n = 0; n < N_; ++n) any += (pm[(b * N_ + n) * M_ + tid] > 0.f) ? 1.f : 0.f;
    kpmv[tid] = (any > 0.f) ? 0.f : 1.f;
  }
  __syncthreads();

  for (int o = tid; o < 5 * D_; o += 256) {
    int qi = o >> 6, d = o & 63;
    qv[o] = cin_b[d] + dot64(q_embed + qi * D_, cin_w + d * D_);
  }
  for (int o = tid; o < 2 * M_ * D_; o += 256) {
    int sel = o >> 10, r = o & 1023, m = r >> 6, d = r & 63;
    float acc = cin_b[D_ + sel * D_ + d] + dot64(xs + m * D_, cin_w + (D_ + sel * D_ + d) * D_);
    ((sel == 0) ? kv : vv)[r] = acc;
  }
  __syncthreads();

  for (int o = tid; o < H_ * 5 * M_; o += 256) {
    int h = o / 80, r = o % 80, qi = r >> 4, km = r & 15;
    float acc = 0.25f * dot16(qv + qi * D_ + h * DH_, kv + km * D_ + h * DH_);
    if (kpmv[km] != 0.f) acc = -1e9f;
    sv[o] = acc;
  }
  __syncthreads();
  if (tid < H_ * 5) {
    int h = tid / 5, qi = tid % 5;
    float* row = sv + h * 80 + qi * M_;
    float mx = -1e30f;
    #pragma unroll
    for (int km = 0; km < M_; ++km) mx = fmaxf(mx, row[km]);
    float se = 0.f;
    #pragma unroll
    for (int km = 0; km < M_; ++km) { float e = __expf(row[km] - mx); row[km] = e; se += e; }
    float inv = 1.f / se;
    #pragma unroll
    for (int km = 0; km < M_; ++km) row[km] *= inv;
  }
  __syncthreads();
  for (int o = tid; o < 5 * D_; o += 256) {
    int qi = o >> 6, d = o & 63, h = d >> 4;
    float acc = 0.f;
    #pragma unroll
    for (int km = 0; km < M_; ++km) acc += sv[h * 80 + qi * M_ + km] * vv[km * D_ + d];
    ao[o] = acc;
  }
  __syncthreads();
  for (int o = tid; o < 5 * D_; o += 256) {
    int qi = o >> 6, d = o & 63;
    zv[o] = cout_b[d] + dot64(ao + qi * D_, cout_w + d * D_);
  }
  __syncthreads();
  if (tid < 5) {
    float acc = logit_b[0] + dot64(zv + tid * D_, logit_w);
    out[b * 5 + tid] = acc;
  }
}

// -------------------------------------------------------------------------
extern "C" void kernel_launch(void* const* d_in, const int* in_sizes, int n_in,
                              void* d_out, int out_size, void* d_ws, size_t ws_size,
                              hipStream_t stream) {
  const float* x       = (const float*)d_in[0];
  const int*   mask    = (const int*)  d_in[1];
  const float* ttcn_w1 = (const float*)d_in[2];
  const float* ttcn_b1 = (const float*)d_in[3];
  const float* ttcn_w2 = (const float*)d_in[4];
  const float* ttcn_b2 = (const float*)d_in[5];
  const float* ttcn_w3 = (const float*)d_in[6];
  const float* ttcn_b3 = (const float*)d_in[7];   // unused: cancels in softmax
  const float* t_bias  = (const float*)d_in[8];
  const float* ga_qw   = (const float*)d_in[9];
  const float* ga_qb   = (const float*)d_in[10];
  const float* ga_kw   = (const float*)d_in[11];
  const float* ga_kb   = (const float*)d_in[12];
  const float* ga_vw   = (const float*)d_in[13];
  const float* ga_vb   = (const float*)d_in[14];
  const float* ga_ow   = (const float*)d_in[15];
  const float* ga_ob   = (const float*)d_in[16];
  const float* tf_in_w = (const float*)d_in[17];
  const float* tf_in_b = (const float*)d_in[18];
  const float* tf_out_w= (const float*)d_in[19];
  const float* tf_out_b= (const float*)d_in[20];
  const float* tf_ln1g = (const float*)d_in[21];
  const float* tf_ln1b = (const float*)d_in[22];
  const float* tf_ln2g = (const float*)d_in[23];
  const float* tf_ln2b = (const float*)d_in[24];
  const float* tf_fw1  = (const float*)d_in[25];
  const float* tf_fb1  = (const float*)d_in[26];
  const float* tf_fw2  = (const float*)d_in[27];
  const float* tf_fb2  = (const float*)d_in[28];
  const float* q_embed = (const float*)d_in[29];
  const float* cls_in_w  = (const float*)d_in[30];
  const float* cls_in_b  = (const float*)d_in[31];
  const float* cls_out_w = (const float*)d_in[32];
  const float* cls_out_b = (const float*)d_in[33];
  const float* logit_w = (const float*)d_in[34];
  const float* logit_b = (const float*)d_in[35];
  (void)ttcn_b3;

  float* wsf  = (float*)d_ws;
  float* xp   = wsf;                        // 262144 f
  float* pmb  = wsf + P_TOT * D_;           // 4096 f
  float* xbuf = pmb + P_TOT;                // 262144 f
  uint4* fr   = (uint4*)(xbuf + P_TOT * D_);// 2*FRAG_TOT uint4
  const short8* frS = (const short8*)fr;

  prep_kernel<<<325, 256, 0, stream>>>(ttcn_w1, ttcn_w2, ttcn_w3,
      ga_qw, ga_kw, ga_vw, ga_ow, tf_in_w, tf_out_w, tf_fw1, tf_fw2, fr);

  ttcn_kernel<<<P_TOT, 256, 0, stream>>>(x, mask, ttcn_b1, ttcn_b2, t_bias,
      frS + 0, frS + 256, frS + 768,
      xp, pmb);

  layer12_kernel<<<BN_, 256, 0, stream>>>(xp, pmb, frS,
      ga_qb, ga_kb, ga_vb, ga_ob, tf_in_b, tf_out_b, tf_ln1g, tf_ln1b,
      tf_fb1, tf_fb2, tf_ln2g, tf_ln2b, xbuf);

  final_kernel<<<B_, 256, 0, stream>>>(xbuf, pmb, q_embed,
                                       cls_in_w, cls_in_b, cls_out_w, cls_out_b,
                                       logit_w, logit_b, (float*)d_out);
}